// Round 1
// baseline (1553.253 us; speedup 1.0000x reference)
//
#include <hip/hip_runtime.h>

typedef unsigned short u16;
typedef __bf16 bf16x8 __attribute__((ext_vector_type(8)));
typedef float f32x4 __attribute__((ext_vector_type(4)));
typedef unsigned short u16x8 __attribute__((ext_vector_type(8)));

constexpr int NN  = 10000;   // nodes
constexpr int NE  = 160000;  // edges
constexpr int NG  = 32;      // graphs
constexpr int HD  = 128;     // hidden
constexpr int ECH = 32000;   // edge chunk rows
constexpr int NCH = 5;       // chunks (5*32000 = 160000)

// ---- workspace layout (bytes, all 256-aligned) ----
constexpr size_t WT_MSG1 = 0;                                  // [2][256][256] bf16
constexpr size_t WT_MSG2 = WT_MSG1 + 2ull*256*256*2;           // 262144
constexpr size_t WT_UPD1 = WT_MSG2 + 2ull*256*256*2;           // 524288  [2][256][384]
constexpr size_t WT_UPD2 = WT_UPD1 + 2ull*256*384*2;           // 917504  [2][128][256]
constexpr size_t WT_NODE = WT_UPD2 + 2ull*128*256*2;           // 1048576 [256][128]
constexpr size_t OFF_H   = WT_NODE + 256ull*128*2;             // 1114112  h f32 [2][NN][128]
constexpr size_t OFF_HB  = OFF_H  + 2ull*NN*128*4;             // h_bf [2][NN][128]
constexpr size_t OFF_AGG = OFF_HB + 2ull*NN*128*2;             // agg f32 [2][NN][256]
constexpr size_t OFF_BIG = OFF_AGG + 2ull*NN*256*4;            // big overlay region
constexpr size_t OFF_G   = OFF_BIG + 2ull*ECH*256*2;           // g f32 [2][NG][128]
// overlays inside BIG:
//   X1  bf16 [2][ECH][256]              (msg phase)
//   ui  bf16 [2][NN][384] at +0, U1 bf16 [2][NN][256] at +15360000   (update phase)
//   nx  f32  [2][NN][256] at +0         (readout phase)
constexpr size_t OFF_UI = OFF_BIG;
constexpr size_t OFF_U1 = OFF_BIG + 2ull*NN*384*2;
constexpr size_t OFF_NX = OFF_BIG;

__device__ inline u16 f2b(float f) {
  unsigned int u = __float_as_uint(f);
  unsigned int r = u + 0x7fffu + ((u >> 16) & 1u);
  return (u16)(r >> 16);
}

// ---------------- weight prep: transpose + bf16 cast ----------------
__global__ __launch_bounds__(256) void k_prep(
    const float* msgW1, const float* msgW2, const float* updW1,
    const float* updW2, const float* nodeW,
    u16* t1, u16* t2, u16* t3, u16* t4, u16* t5) {
  int idx = blockIdx.x * 256 + threadIdx.x;
  if (idx < 131072) {  // msgW1/msgW2: [l][k=256][n=256] -> [l][n][k]
    int l = idx >> 16, r = idx & 65535, n = r >> 8, k = r & 255;
    t1[idx] = f2b(msgW1[(l << 16) + (k << 8) + n]);
    t2[idx] = f2b(msgW2[(l << 16) + (k << 8) + n]);
  }
  if (idx < 196608) {  // updW1: [l][k=384][n=256] -> [l][n=256][k=384]
    int l = idx / 98304, r = idx % 98304, n = r / 384, k = r % 384;
    t3[idx] = f2b(updW1[l * 98304 + k * 256 + n]);
  }
  if (idx < 65536) {   // updW2: [l][k=256][n=128] -> [l][n=128][k=256]
    int l = idx >> 15, r = idx & 32767, n = r >> 8, k = r & 255;
    t4[idx] = f2b(updW2[l * 32768 + (k << 7) + n]);
  }
  if (idx < 32768) {   // nodeW: [k=128][n=256] -> [n=256][k=128]
    int n = idx >> 7, k = idx & 127;
    t5[idx] = f2b(nodeW[(k << 8) + n]);
  }
}

// ---------------- embedding: h = x @ W_emb + b_emb ----------------
__global__ __launch_bounds__(256) void k_embed(
    const float* x1, const float* x2, const float* W, const float* b,
    float* h, u16* h_bf) {
  int br = blockIdx.z;
  const float* x = br ? x2 : x1;
  float* hB = h + (size_t)br * NN * HD;
  u16* hbB = h_bf + (size_t)br * NN * HD;
  __shared__ float sW[64 * 128];
  __shared__ float sx[32 * 64];
  int tid = threadIdx.x;
  for (int i = tid; i < 64 * 128; i += 256) sW[i] = W[i];
  int r0 = blockIdx.x * 32;
  for (int i = tid; i < 32 * 64; i += 256) {
    int r = i >> 6, k = i & 63;
    sx[i] = (r0 + r < NN) ? x[(size_t)(r0 + r) * 64 + k] : 0.f;
  }
  __syncthreads();
  int c = tid & 127;
  int rbase = (tid >> 7) * 16;
  for (int r = rbase; r < rbase + 16; r++) {
    float acc = b[c];
#pragma unroll
    for (int k = 0; k < 64; k++) acc += sx[r * 64 + k] * sW[k * 128 + c];
    int gr = r0 + r;
    if (gr < NN) {
      hB[(size_t)gr * HD + c] = acc;
      hbB[(size_t)gr * HD + c] = f2b(acc);
    }
  }
}

// ---------------- generic MFMA GEMM ----------------
// modes: 0 MSG1 (gather rows from h_bf via src/tgt, relu -> bf16)
//        1 MSG2 (plain A, epilogue atomicAdd into agg[tgt])
//        2 UPD1 (plain A, relu -> bf16)
//        3 UPD2 (plain A, residual: h += v, write h f32 + h_bf bf16)
//        4 NX   (plain A, f32 store)
struct GemmP {
  const u16* A;   size_t sA;     // branch stride (elements)
  const int* ei0; const int* ei1;
  int edge_base;
  const u16* Wt;                 // [N][K] bf16 (shared across branches)
  const float* bias;
  u16* outb;  size_t s_outb;
  float* outf; size_t s_outf;
  u16* outb2; size_t s_outb2;
  int M, N, K;
  int mode;
};

__global__ __launch_bounds__(256) void k_gemm(GemmP p) {
  const int br = blockIdx.z;
  const int tid = threadIdx.x;
  const int lane = tid & 63, wave = tid >> 6;
  const int wm = (wave & 1) * 64, wn = (wave >> 1) * 64;
  const int q = lane >> 4, lr = lane & 15;
  const int m0 = blockIdx.x * 128, n0 = blockIdx.y * 128;
  __shared__ alignas(16) u16 lA[128 * 32];
  __shared__ alignas(16) u16 lB[128 * 32];

  f32x4 acc[4][4];
#pragma unroll
  for (int i = 0; i < 4; i++)
#pragma unroll
    for (int j = 0; j < 4; j++) acc[i][j] = (f32x4){0.f, 0.f, 0.f, 0.f};

  const u16* Abr = p.A + (size_t)br * p.sA;
  const int* ei = br ? p.ei1 : p.ei0;
  const int* tgt = ei;
  const int* src = ei + NE;
  const bool gather = (p.mode == 0);

  for (int k0 = 0; k0 < p.K; k0 += 32) {
    // stage A tile [128][32]
#pragma unroll
    for (int c = tid; c < 512; c += 256) {
      int r = c >> 2, kc = (c & 3) << 3;
      int gr = m0 + r;
      u16x8 v = {0, 0, 0, 0, 0, 0, 0, 0};
      if (gr < p.M) {
        int kk = k0 + kc;
        const u16* rp;
        if (gather) {
          int e = p.edge_base + gr;
          int node = (kk < 128) ? src[e] : tgt[e];
          rp = Abr + (size_t)node * 128 + (kk & 127);
        } else {
          rp = Abr + (size_t)gr * p.K + kk;
        }
        v = *(const u16x8*)rp;
      }
      *(u16x8*)&lA[r * 32 + kc] = v;
    }
    // stage B tile [128][32] from Wt[n][k]
#pragma unroll
    for (int c = tid; c < 512; c += 256) {
      int r = c >> 2, kc = (c & 3) << 3;
      *(u16x8*)&lB[r * 32 + kc] = *(const u16x8*)(p.Wt + (size_t)(n0 + r) * p.K + k0 + kc);
    }
    __syncthreads();
    bf16x8 af[4], bfr[4];
#pragma unroll
    for (int i = 0; i < 4; i++) af[i] = *(const bf16x8*)&lA[(wm + i * 16 + lr) * 32 + q * 8];
#pragma unroll
    for (int i = 0; i < 4; i++) bfr[i] = *(const bf16x8*)&lB[(wn + i * 16 + lr) * 32 + q * 8];
#pragma unroll
    for (int mi = 0; mi < 4; mi++)
#pragma unroll
      for (int ni = 0; ni < 4; ni++)
        acc[mi][ni] = __builtin_amdgcn_mfma_f32_16x16x32_bf16(af[mi], bfr[ni], acc[mi][ni], 0, 0, 0);
    __syncthreads();
  }

  // epilogue: C/D layout col=lane&15, row=(lane>>4)*4+reg
  if (p.mode == 0 || p.mode == 2) {
    u16* ob = p.outb + (size_t)br * p.s_outb;
#pragma unroll
    for (int mi = 0; mi < 4; mi++)
#pragma unroll
      for (int rg = 0; rg < 4; rg++) {
        int row = m0 + wm + mi * 16 + q * 4 + rg;
        if (row >= p.M) continue;
#pragma unroll
        for (int ni = 0; ni < 4; ni++) {
          int col = n0 + wn + ni * 16 + lr;
          float v = acc[mi][ni][rg] + p.bias[col];
          if (v < 0.f) v = 0.f;
          ob[(size_t)row * p.N + col] = f2b(v);
        }
      }
  } else if (p.mode == 1) {
    float* agg = p.outf + (size_t)br * p.s_outf;
#pragma unroll
    for (int mi = 0; mi < 4; mi++)
#pragma unroll
      for (int rg = 0; rg < 4; rg++) {
        int row = m0 + wm + mi * 16 + q * 4 + rg;
        if (row >= p.M) continue;
        int t = tgt[p.edge_base + row];
#pragma unroll
        for (int ni = 0; ni < 4; ni++) {
          int col = n0 + wn + ni * 16 + lr;
          float v = acc[mi][ni][rg] + p.bias[col];
          atomicAdd(agg + (size_t)t * 256 + col, v);
        }
      }
  } else if (p.mode == 3) {
    float* hf = p.outf + (size_t)br * p.s_outf;
    u16* hb = p.outb2 + (size_t)br * p.s_outb2;
#pragma unroll
    for (int mi = 0; mi < 4; mi++)
#pragma unroll
      for (int rg = 0; rg < 4; rg++) {
        int row = m0 + wm + mi * 16 + q * 4 + rg;
        if (row >= p.M) continue;
#pragma unroll
        for (int ni = 0; ni < 4; ni++) {
          int col = n0 + wn + ni * 16 + lr;
          size_t o = (size_t)row * p.N + col;
          float nh = hf[o] + acc[mi][ni][rg] + p.bias[col];
          hf[o] = nh;
          hb[o] = f2b(nh);
        }
      }
  } else {  // mode 4: f32 store
    float* of = p.outf + (size_t)br * p.s_outf;
#pragma unroll
    for (int mi = 0; mi < 4; mi++)
#pragma unroll
      for (int rg = 0; rg < 4; rg++) {
        int row = m0 + wm + mi * 16 + q * 4 + rg;
        if (row >= p.M) continue;
#pragma unroll
        for (int ni = 0; ni < 4; ni++) {
          int col = n0 + wn + ni * 16 + lr;
          of[(size_t)row * p.N + col] = acc[mi][ni][rg] + p.bias[col];
        }
      }
  }
}

// ---------------- concat [agg | h] -> bf16 ui ----------------
__global__ __launch_bounds__(256) void k_concat(const float* agg, const u16* h_bf, u16* ui) {
  int br = blockIdx.z;
  int idx = blockIdx.x * 256 + threadIdx.x;  // [0, NN*384)
  int n = idx / 384, k = idx % 384;
  u16 v;
  if (k < 256) v = f2b(agg[(size_t)br * NN * 256 + (size_t)n * 256 + k]);
  else         v = h_bf[(size_t)br * NN * 128 + (size_t)n * 128 + (k - 256)];
  ui[(size_t)br * NN * 384 + idx] = v;
}

// ---------------- gated pooling ----------------
__global__ __launch_bounds__(256) void k_gate(const float* nx, const int* b0, const int* b1, float* g) {
  int br = blockIdx.z;
  const int* batch = br ? b1 : b0;
  int idx = blockIdx.x * 256 + threadIdx.x;  // [0, NN*128)
  int n = idx >> 7, j = idx & 127;
  const float* nxb = nx + (size_t)br * NN * 256;
  float gt = nxb[(size_t)n * 256 + j];
  float vl = nxb[(size_t)n * 256 + 128 + j];
  float s = 1.f / (1.f + __expf(-gt));
  atomicAdd(g + (size_t)br * NG * 128 + (size_t)batch[n] * 128 + j, vl * s);
}

// ---------------- final graph GEMM ----------------
__global__ __launch_bounds__(128) void k_final(const float* g, const float* W, const float* b, float* out) {
  int br = blockIdx.z, gi = blockIdx.x, j = threadIdx.x;
  __shared__ float sg[128];
  sg[j] = g[(size_t)br * NG * 128 + (size_t)gi * 128 + j];
  __syncthreads();
  float acc = b[j];
#pragma unroll
  for (int k = 0; k < 128; k++) acc += sg[k] * W[k * 128 + j];
  out[(size_t)br * NG * 128 + (size_t)gi * 128 + j] = acc;
}

extern "C" void kernel_launch(void* const* d_in, const int* in_sizes, int n_in,
                              void* d_out, int out_size, void* d_ws, size_t ws_size,
                              hipStream_t stream) {
  const float* x1     = (const float*)d_in[0];
  const int*   ei1    = (const int*)d_in[1];
  const int*   bat1   = (const int*)d_in[2];
  const float* x2     = (const float*)d_in[3];
  const int*   ei2    = (const int*)d_in[4];
  const int*   bat2   = (const int*)d_in[5];
  const float* W_emb  = (const float*)d_in[6];
  const float* b_emb  = (const float*)d_in[7];
  const float* msg_W1 = (const float*)d_in[8];
  const float* msg_b1 = (const float*)d_in[9];
  const float* msg_W2 = (const float*)d_in[10];
  const float* msg_b2 = (const float*)d_in[11];
  const float* upd_W1 = (const float*)d_in[12];
  const float* upd_b1 = (const float*)d_in[13];
  const float* upd_W2 = (const float*)d_in[14];
  const float* upd_b2 = (const float*)d_in[15];
  const float* node_W = (const float*)d_in[16];
  const float* node_b = (const float*)d_in[17];
  const float* graph_W = (const float*)d_in[18];
  const float* graph_b = (const float*)d_in[19];
  float* out = (float*)d_out;

  char* ws = (char*)d_ws;
  u16* wt_msg1 = (u16*)(ws + WT_MSG1);
  u16* wt_msg2 = (u16*)(ws + WT_MSG2);
  u16* wt_upd1 = (u16*)(ws + WT_UPD1);
  u16* wt_upd2 = (u16*)(ws + WT_UPD2);
  u16* wt_node = (u16*)(ws + WT_NODE);
  float* h   = (float*)(ws + OFF_H);
  u16*   hb  = (u16*)(ws + OFF_HB);
  float* agg = (float*)(ws + OFF_AGG);
  u16*   X1  = (u16*)(ws + OFF_BIG);
  u16*   ui  = (u16*)(ws + OFF_UI);
  u16*   U1  = (u16*)(ws + OFF_U1);
  float* nx  = (float*)(ws + OFF_NX);
  float* g   = (float*)(ws + OFF_G);

  // weight prep
  k_prep<<<768, 256, 0, stream>>>(msg_W1, msg_W2, upd_W1, upd_W2, node_W,
                                  wt_msg1, wt_msg2, wt_upd1, wt_upd2, wt_node);
  // embedding
  k_embed<<<dim3(313, 1, 2), 256, 0, stream>>>(x1, x2, W_emb, b_emb, h, hb);

  for (int l = 0; l < 2; l++) {
    hipMemsetAsync(agg, 0, 2ull * NN * 256 * 4, stream);
    for (int ch = 0; ch < NCH; ch++) {
      GemmP p1{};
      p1.A = hb; p1.sA = (size_t)NN * 128;
      p1.ei0 = ei1; p1.ei1 = ei2; p1.edge_base = ch * ECH;
      p1.Wt = wt_msg1 + (size_t)l * 65536; p1.bias = msg_b1 + l * 256;
      p1.outb = X1; p1.s_outb = (size_t)ECH * 256;
      p1.M = ECH; p1.N = 256; p1.K = 256; p1.mode = 0;
      k_gemm<<<dim3(ECH / 128, 2, 2), 256, 0, stream>>>(p1);

      GemmP p2{};
      p2.A = X1; p2.sA = (size_t)ECH * 256;
      p2.ei0 = ei1; p2.ei1 = ei2; p2.edge_base = ch * ECH;
      p2.Wt = wt_msg2 + (size_t)l * 65536; p2.bias = msg_b2 + l * 256;
      p2.outf = agg; p2.s_outf = (size_t)NN * 256;
      p2.M = ECH; p2.N = 256; p2.K = 256; p2.mode = 1;
      k_gemm<<<dim3(ECH / 128, 2, 2), 256, 0, stream>>>(p2);
    }
    // concat [agg | h] -> ui (bf16)
    k_concat<<<dim3((NN * 384) / 256, 1, 2), 256, 0, stream>>>(agg, hb, ui);

    GemmP p3{};
    p3.A = ui; p3.sA = (size_t)NN * 384;
    p3.Wt = wt_upd1 + (size_t)l * 98304; p3.bias = upd_b1 + l * 256;
    p3.outb = U1; p3.s_outb = (size_t)NN * 256;
    p3.M = NN; p3.N = 256; p3.K = 384; p3.mode = 2;
    k_gemm<<<dim3(79, 2, 2), 256, 0, stream>>>(p3);

    GemmP p4{};
    p4.A = U1; p4.sA = (size_t)NN * 256;
    p4.Wt = wt_upd2 + (size_t)l * 32768; p4.bias = upd_b2 + l * 128;
    p4.outf = h; p4.s_outf = (size_t)NN * 128;
    p4.outb2 = hb; p4.s_outb2 = (size_t)NN * 128;
    p4.M = NN; p4.N = 128; p4.K = 256; p4.mode = 3;
    k_gemm<<<dim3(79, 1, 2), 256, 0, stream>>>(p4);
  }

  // readout
  GemmP p5{};
  p5.A = hb; p5.sA = (size_t)NN * 128;
  p5.Wt = wt_node; p5.bias = node_b;
  p5.outf = nx; p5.s_outf = (size_t)NN * 256;
  p5.M = NN; p5.N = 256; p5.K = 128; p5.mode = 4;
  k_gemm<<<dim3(79, 2, 2), 256, 0, stream>>>(p5);

  hipMemsetAsync(g, 0, 2ull * NG * 128 * 4, stream);
  k_gate<<<dim3((NN * 128) / 256, 1, 2), 256, 0, stream>>>(nx, bat1, bat2, g);
  k_final<<<dim3(NG, 1, 2), 128, 0, stream>>>(g, graph_W, graph_b, out);
}

// Round 2
// 498.358 us; speedup vs baseline: 3.1167x; 3.1167x over previous
//
#include <hip/hip_runtime.h>

typedef unsigned short u16;
typedef __bf16 bf16x8 __attribute__((ext_vector_type(8)));
typedef float f32x4 __attribute__((ext_vector_type(4)));
typedef unsigned short u16x8 __attribute__((ext_vector_type(8)));
typedef unsigned short u16x4 __attribute__((ext_vector_type(4)));

constexpr int NN  = 10000;   // nodes
constexpr int NE  = 160000;  // edges
constexpr int NG  = 32;      // graphs
constexpr int HD  = 128;     // hidden

// ---- workspace layout (bytes) ----
constexpr size_t WT_PQ   = 0;                         // [2][512][128] bf16 (msgW1 split/transposed)
constexpr size_t WT_MSG2 = WT_PQ   + 2ull*512*128*2;  // [2][256][256]
constexpr size_t WT_UPD1 = WT_MSG2 + 2ull*256*256*2;  // [2][256][384]
constexpr size_t WT_UPD2 = WT_UPD1 + 2ull*256*384*2;  // [2][128][256]
constexpr size_t WT_NODE = WT_UPD2 + 2ull*128*256*2;  // [256][128]
constexpr size_t OFF_DEG = WT_NODE + 256ull*128*2;    // int [2][NN]
constexpr size_t OFF_ST  = OFF_DEG + 2ull*NN*4;       // int [2][NN+1] starts
constexpr size_t OFF_CUR = OFF_ST  + 2ull*(NN+8)*4;   // int [2][NN] cursors
constexpr size_t OFF_SRC = OFF_CUR + 2ull*NN*4;       // int [2][NE] src sorted by tgt
constexpr size_t OFF_H   = OFF_SRC + 2ull*NE*4;       // f32 [2][NN][128]
constexpr size_t OFF_HB  = OFF_H   + 2ull*NN*128*4;   // bf16 [2][NN][128]
constexpr size_t OFF_PQ  = OFF_HB  + 2ull*NN*128*2;   // bf16 [2][NN][512]  (overlay: nx f32 [2][NN][256])
constexpr size_t OFF_S   = OFF_PQ  + 2ull*NN*512*2;   // bf16 [2][NN][256]  (overlay: U1 bf16 same size)
constexpr size_t OFF_UI  = OFF_S   + 2ull*NN*256*2;   // bf16 [2][NN][384]
constexpr size_t OFF_G   = OFF_UI  + 2ull*NN*384*2;   // f32 [2][NG][128]
constexpr size_t OFF_NX  = OFF_PQ;
constexpr size_t OFF_U1  = OFF_S;

__device__ inline u16 f2b(float f) {
  unsigned int u = __float_as_uint(f);
  unsigned int r = u + 0x7fffu + ((u >> 16) & 1u);
  return (u16)(r >> 16);
}
__device__ inline float b2f(u16 u) { return __uint_as_float(((unsigned int)u) << 16); }

// ---------------- weight prep: transpose + bf16 cast ----------------
__global__ __launch_bounds__(256) void k_prep(
    const float* msgW1, const float* msgW2, const float* updW1,
    const float* updW2, const float* nodeW,
    u16* tpq, u16* t2, u16* t3, u16* t4, u16* t5) {
  int idx = blockIdx.x * 256 + threadIdx.x;
  if (idx < 131072) {
    // wt_pq: [l][n=512][k=128]; n<256 -> W1[k][n] (src half), n>=256 -> W1[128+k][n-256] (tgt half)
    int l = idx >> 16, r = idx & 65535, n = r >> 7, k = r & 127;
    int row = (n < 256) ? k : (128 + k);
    tpq[idx] = f2b(msgW1[l * 65536 + row * 256 + (n & 255)]);
    // wt_msg2: [l][n=256][k=256] from [l][k][n]
    int n2 = (idx & 65535) >> 8, k2 = idx & 255;
    t2[idx] = f2b(msgW2[(idx & ~65535) + (k2 << 8) + n2]);
  }
  if (idx < 196608) {  // updW1: [l][k=384][n=256] -> [l][n=256][k=384]
    int l = idx / 98304, r = idx % 98304, n = r / 384, k = r % 384;
    t3[idx] = f2b(updW1[l * 98304 + k * 256 + n]);
  }
  if (idx < 65536) {   // updW2: [l][k=256][n=128] -> [l][n=128][k=256]
    int l = idx >> 15, r = idx & 32767, n = r >> 8, k = r & 255;
    t4[idx] = f2b(updW2[l * 32768 + (k << 7) + n]);
  }
  if (idx < 32768) {   // nodeW: [k=128][n=256] -> [n=256][k=128]
    int n = idx >> 7, k = idx & 127;
    t5[idx] = f2b(nodeW[(k << 8) + n]);
  }
}

// ---------------- counting sort of edges by tgt ----------------
__global__ __launch_bounds__(256) void k_deg(const int* ei0, const int* ei1, int* deg) {
  int br = blockIdx.z;
  int e = blockIdx.x * 256 + threadIdx.x;
  if (e >= NE) return;
  const int* tgt = br ? ei1 : ei0;
  atomicAdd(deg + br * NN + tgt[e], 1);
}

__global__ __launch_bounds__(256) void k_scan(const int* deg, int* starts, int* cursor) {
  int br = blockIdx.z;
  const int* d = deg + br * NN;
  int* st = starts + br * (NN + 8);
  int* cu = cursor + br * NN;
  __shared__ int part[257];
  int t = threadIdx.x;
  int c0 = t * 40;
  int s = 0;
  for (int i = 0; i < 40; i++) if (c0 + i < NN) s += d[c0 + i];
  part[t] = s;
  __syncthreads();
  if (t == 0) {
    int run = 0;
    for (int i = 0; i < 256; i++) { int v = part[i]; part[i] = run; run += v; }
    part[256] = run;
  }
  __syncthreads();
  int run = part[t];
  for (int i = 0; i < 40; i++) {
    int n = c0 + i;
    if (n < NN) { st[n] = run; cu[n] = run; run += d[n]; }
  }
  if (t == 255) st[NN] = part[256];
}

__global__ __launch_bounds__(256) void k_scatter(const int* ei0, const int* ei1,
                                                 int* cursor, int* srcs) {
  int br = blockIdx.z;
  int e = blockIdx.x * 256 + threadIdx.x;
  if (e >= NE) return;
  const int* ei = br ? ei1 : ei0;
  int t = ei[e], s = ei[NE + e];
  int pos = atomicAdd(cursor + br * NN + t, 1);
  srcs[br * NE + pos] = s;
}

// ---------------- embedding: h = x @ W_emb + b_emb ----------------
__global__ __launch_bounds__(256) void k_embed(
    const float* x1, const float* x2, const float* W, const float* b,
    float* h, u16* h_bf) {
  int br = blockIdx.z;
  const float* x = br ? x2 : x1;
  float* hB = h + (size_t)br * NN * HD;
  u16* hbB = h_bf + (size_t)br * NN * HD;
  __shared__ float sW[64 * 128];
  __shared__ float sx[32 * 64];
  int tid = threadIdx.x;
  for (int i = tid; i < 64 * 128; i += 256) sW[i] = W[i];
  int r0 = blockIdx.x * 32;
  for (int i = tid; i < 32 * 64; i += 256) {
    int r = i >> 6, k = i & 63;
    sx[i] = (r0 + r < NN) ? x[(size_t)(r0 + r) * 64 + k] : 0.f;
  }
  __syncthreads();
  int c = tid & 127;
  int rbase = (tid >> 7) * 16;
  for (int r = rbase; r < rbase + 16; r++) {
    float acc = b[c];
#pragma unroll
    for (int k = 0; k < 64; k++) acc += sx[r * 64 + k] * sW[k * 128 + c];
    int gr = r0 + r;
    if (gr < NN) {
      hB[(size_t)gr * HD + c] = acc;
      hbB[(size_t)gr * HD + c] = f2b(acc);
    }
  }
}

// ---------------- edge phase: S[n] = sum_e relu(P[src_e] + Q[n] + b1) ----------------
// PQ layout: [n][512] = [P(256) | Q(256)]. One wave per node; lane owns 4 cols.
__global__ __launch_bounds__(256) void k_edge(const u16* PQ, const int* starts,
                                              const int* srcs, const float* b1, u16* S) {
  int br = blockIdx.z;
  int node = blockIdx.x * 4 + (threadIdx.x >> 6);
  int lane = threadIdx.x & 63;
  int c0 = lane * 4;
  const u16* PQb = PQ + (size_t)br * NN * 512;
  const int* st = starts + br * (NN + 8);
  const int* sr = srcs + br * NE;
  u16x4 qr = *(const u16x4*)(PQb + (size_t)node * 512 + 256 + c0);
  float qv[4], acc[4] = {0.f, 0.f, 0.f, 0.f};
#pragma unroll
  for (int j = 0; j < 4; j++) qv[j] = b2f(qr[j]) + b1[c0 + j];
  int e0 = st[node], e1 = st[node + 1];
  int e = e0;
  for (; e + 1 < e1; e += 2) {
    int s0 = sr[e], s1 = sr[e + 1];
    u16x4 p0 = *(const u16x4*)(PQb + (size_t)s0 * 512 + c0);
    u16x4 p1 = *(const u16x4*)(PQb + (size_t)s1 * 512 + c0);
#pragma unroll
    for (int j = 0; j < 4; j++) {
      float v0 = b2f(p0[j]) + qv[j];
      float v1 = b2f(p1[j]) + qv[j];
      acc[j] += (v0 > 0.f ? v0 : 0.f) + (v1 > 0.f ? v1 : 0.f);
    }
  }
  if (e < e1) {
    int s0 = sr[e];
    u16x4 p0 = *(const u16x4*)(PQb + (size_t)s0 * 512 + c0);
#pragma unroll
    for (int j = 0; j < 4; j++) {
      float v0 = b2f(p0[j]) + qv[j];
      acc[j] += (v0 > 0.f ? v0 : 0.f);
    }
  }
  u16x4 o;
#pragma unroll
  for (int j = 0; j < 4; j++) o[j] = f2b(acc[j]);
  *(u16x4*)(S + (size_t)br * NN * 256 + (size_t)node * 256 + c0) = o;
}

// ---------------- generic MFMA GEMM ----------------
// modes: 2 relu -> bf16 store        (UPD1)
//        3 residual: h += v, write h f32 + hb bf16   (UPD2)
//        4 f32 store                  (NX)
//        5 plain bf16 store, no bias  (PQ)
//        6 bf16 store, acc + deg[row]*bias[col]  (AGG -> ui)
struct GemmP {
  const u16* A;   size_t sA;
  const u16* Wt;                 // [N][K] bf16
  const float* bias;
  const int* deg;
  u16* outb;  size_t s_outb;
  float* outf; size_t s_outf;
  u16* outb2; size_t s_outb2;
  int M, N, K, ldo;
  int mode;
};

#define LSTR 40  // padded LDS row stride (u16 units) to break bank conflicts

__global__ __launch_bounds__(256) void k_gemm(GemmP p) {
  const int br = blockIdx.z;
  const int tid = threadIdx.x;
  const int lane = tid & 63, wave = tid >> 6;
  const int wm = (wave & 1) * 64, wn = (wave >> 1) * 64;
  const int q = lane >> 4, lr = lane & 15;
  const int m0 = blockIdx.x * 128, n0 = blockIdx.y * 128;
  __shared__ alignas(16) u16 lA[128 * LSTR];
  __shared__ alignas(16) u16 lB[128 * LSTR];

  f32x4 acc[4][4];
#pragma unroll
  for (int i = 0; i < 4; i++)
#pragma unroll
    for (int j = 0; j < 4; j++) acc[i][j] = (f32x4){0.f, 0.f, 0.f, 0.f};

  const u16* Abr = p.A + (size_t)br * p.sA;

  for (int k0 = 0; k0 < p.K; k0 += 32) {
#pragma unroll
    for (int c = tid; c < 512; c += 256) {
      int r = c >> 2, kc = (c & 3) << 3;
      int gr = m0 + r;
      u16x8 v = {0, 0, 0, 0, 0, 0, 0, 0};
      if (gr < p.M) v = *(const u16x8*)(Abr + (size_t)gr * p.K + k0 + kc);
      *(u16x8*)&lA[r * LSTR + kc] = v;
    }
#pragma unroll
    for (int c = tid; c < 512; c += 256) {
      int r = c >> 2, kc = (c & 3) << 3;
      *(u16x8*)&lB[r * LSTR + kc] = *(const u16x8*)(p.Wt + (size_t)(n0 + r) * p.K + k0 + kc);
    }
    __syncthreads();
    bf16x8 af[4], bfr[4];
#pragma unroll
    for (int i = 0; i < 4; i++) af[i] = *(const bf16x8*)&lA[(wm + i * 16 + lr) * LSTR + q * 8];
#pragma unroll
    for (int i = 0; i < 4; i++) bfr[i] = *(const bf16x8*)&lB[(wn + i * 16 + lr) * LSTR + q * 8];
#pragma unroll
    for (int mi = 0; mi < 4; mi++)
#pragma unroll
      for (int ni = 0; ni < 4; ni++)
        acc[mi][ni] = __builtin_amdgcn_mfma_f32_16x16x32_bf16(af[mi], bfr[ni], acc[mi][ni], 0, 0, 0);
    __syncthreads();
  }

  // C/D layout: col=lane&15, row=(lane>>4)*4+reg
  if (p.mode == 2) {
    u16* ob = p.outb + (size_t)br * p.s_outb;
#pragma unroll
    for (int mi = 0; mi < 4; mi++)
#pragma unroll
      for (int rg = 0; rg < 4; rg++) {
        int row = m0 + wm + mi * 16 + q * 4 + rg;
        if (row >= p.M) continue;
#pragma unroll
        for (int ni = 0; ni < 4; ni++) {
          int col = n0 + wn + ni * 16 + lr;
          float v = acc[mi][ni][rg] + p.bias[col];
          if (v < 0.f) v = 0.f;
          ob[(size_t)row * p.ldo + col] = f2b(v);
        }
      }
  } else if (p.mode == 3) {
    float* hf = p.outf + (size_t)br * p.s_outf;
    u16* hb = p.outb2 + (size_t)br * p.s_outb2;
#pragma unroll
    for (int mi = 0; mi < 4; mi++)
#pragma unroll
      for (int rg = 0; rg < 4; rg++) {
        int row = m0 + wm + mi * 16 + q * 4 + rg;
        if (row >= p.M) continue;
#pragma unroll
        for (int ni = 0; ni < 4; ni++) {
          int col = n0 + wn + ni * 16 + lr;
          size_t o = (size_t)row * p.ldo + col;
          float nh = hf[o] + acc[mi][ni][rg] + p.bias[col];
          hf[o] = nh;
          hb[o] = f2b(nh);
        }
      }
  } else if (p.mode == 4) {
    float* of = p.outf + (size_t)br * p.s_outf;
#pragma unroll
    for (int mi = 0; mi < 4; mi++)
#pragma unroll
      for (int rg = 0; rg < 4; rg++) {
        int row = m0 + wm + mi * 16 + q * 4 + rg;
        if (row >= p.M) continue;
#pragma unroll
        for (int ni = 0; ni < 4; ni++) {
          int col = n0 + wn + ni * 16 + lr;
          of[(size_t)row * p.ldo + col] = acc[mi][ni][rg] + p.bias[col];
        }
      }
  } else if (p.mode == 5) {
    u16* ob = p.outb + (size_t)br * p.s_outb;
#pragma unroll
    for (int mi = 0; mi < 4; mi++)
#pragma unroll
      for (int rg = 0; rg < 4; rg++) {
        int row = m0 + wm + mi * 16 + q * 4 + rg;
        if (row >= p.M) continue;
#pragma unroll
        for (int ni = 0; ni < 4; ni++) {
          int col = n0 + wn + ni * 16 + lr;
          ob[(size_t)row * p.ldo + col] = f2b(acc[mi][ni][rg]);
        }
      }
  } else {  // mode 6
    u16* ob = p.outb + (size_t)br * p.s_outb;
    const int* dg = p.deg + br * NN;
#pragma unroll
    for (int mi = 0; mi < 4; mi++)
#pragma unroll
      for (int rg = 0; rg < 4; rg++) {
        int row = m0 + wm + mi * 16 + q * 4 + rg;
        if (row >= p.M) continue;
        float d = (float)dg[row];
#pragma unroll
        for (int ni = 0; ni < 4; ni++) {
          int col = n0 + wn + ni * 16 + lr;
          ob[(size_t)row * p.ldo + col] = f2b(acc[mi][ni][rg] + d * p.bias[col]);
        }
      }
  }
}

// ---------------- copy h (bf16) into ui[:, 256:384] ----------------
__global__ __launch_bounds__(256) void k_copyh(const u16* hb, u16* ui) {
  int br = blockIdx.z;
  int idx = blockIdx.x * 256 + threadIdx.x;  // [0, NN*128)
  int n = idx >> 7, j = idx & 127;
  ui[(size_t)br * NN * 384 + (size_t)n * 384 + 256 + j] =
      hb[(size_t)br * NN * 128 + idx];
}

// ---------------- gated pooling: one block per (graph, branch) ----------------
__global__ __launch_bounds__(256) void k_gate(const float* nx, const int* b0v,
                                              const int* b1v, float* g) {
  int br = blockIdx.z, gr = blockIdx.x;
  const int* batch = br ? b1v : b0v;
  int lo = 0, hi = NN;
  while (lo < hi) { int mid = (lo + hi) >> 1; if (batch[mid] < gr) lo = mid + 1; else hi = mid; }
  int n0 = lo;
  lo = 0; hi = NN;
  while (lo < hi) { int mid = (lo + hi) >> 1; if (batch[mid] < gr + 1) lo = mid + 1; else hi = mid; }
  int n1 = lo;
  int col = threadIdx.x & 127, half = threadIdx.x >> 7;
  const float* nxb = nx + (size_t)br * NN * 256;
  float acc = 0.f;
  for (int n = n0 + half; n < n1; n += 2) {
    float gt = nxb[(size_t)n * 256 + col];
    float vl = nxb[(size_t)n * 256 + 128 + col];
    acc += vl / (1.f + __expf(-gt));
  }
  __shared__ float red[256];
  red[threadIdx.x] = acc;
  __syncthreads();
  if (half == 0)
    g[((size_t)br * NG + gr) * 128 + col] = red[col] + red[128 + col];
}

// ---------------- final graph GEMM ----------------
__global__ __launch_bounds__(128) void k_final(const float* g, const float* W,
                                               const float* b, float* out) {
  int br = blockIdx.z, gi = blockIdx.x, j = threadIdx.x;
  __shared__ float sg[128];
  sg[j] = g[(size_t)br * NG * 128 + (size_t)gi * 128 + j];
  __syncthreads();
  float acc = b[j];
#pragma unroll
  for (int k = 0; k < 128; k++) acc += sg[k] * W[k * 128 + j];
  out[(size_t)br * NG * 128 + (size_t)gi * 128 + j] = acc;
}

extern "C" void kernel_launch(void* const* d_in, const int* in_sizes, int n_in,
                              void* d_out, int out_size, void* d_ws, size_t ws_size,
                              hipStream_t stream) {
  const float* x1     = (const float*)d_in[0];
  const int*   ei1    = (const int*)d_in[1];
  const int*   bat1   = (const int*)d_in[2];
  const float* x2     = (const float*)d_in[3];
  const int*   ei2    = (const int*)d_in[4];
  const int*   bat2   = (const int*)d_in[5];
  const float* W_emb  = (const float*)d_in[6];
  const float* b_emb  = (const float*)d_in[7];
  const float* msg_W1 = (const float*)d_in[8];
  const float* msg_b1 = (const float*)d_in[9];
  const float* msg_W2 = (const float*)d_in[10];
  const float* msg_b2 = (const float*)d_in[11];
  const float* upd_W1 = (const float*)d_in[12];
  const float* upd_b1 = (const float*)d_in[13];
  const float* upd_W2 = (const float*)d_in[14];
  const float* upd_b2 = (const float*)d_in[15];
  const float* node_W = (const float*)d_in[16];
  const float* node_b = (const float*)d_in[17];
  const float* graph_W = (const float*)d_in[18];
  const float* graph_b = (const float*)d_in[19];
  float* out = (float*)d_out;

  char* ws = (char*)d_ws;
  u16* wt_pq   = (u16*)(ws + WT_PQ);
  u16* wt_msg2 = (u16*)(ws + WT_MSG2);
  u16* wt_upd1 = (u16*)(ws + WT_UPD1);
  u16* wt_upd2 = (u16*)(ws + WT_UPD2);
  u16* wt_node = (u16*)(ws + WT_NODE);
  int* deg    = (int*)(ws + OFF_DEG);
  int* starts = (int*)(ws + OFF_ST);
  int* cursor = (int*)(ws + OFF_CUR);
  int* srcs   = (int*)(ws + OFF_SRC);
  float* h  = (float*)(ws + OFF_H);
  u16*   hb = (u16*)(ws + OFF_HB);
  u16*   PQ = (u16*)(ws + OFF_PQ);
  u16*   S  = (u16*)(ws + OFF_S);
  u16*   ui = (u16*)(ws + OFF_UI);
  u16*   U1 = (u16*)(ws + OFF_U1);
  float* nx = (float*)(ws + OFF_NX);
  float* g  = (float*)(ws + OFF_G);

  // prep: weights + edge sort + embedding
  k_prep<<<768, 256, 0, stream>>>(msg_W1, msg_W2, upd_W1, upd_W2, node_W,
                                  wt_pq, wt_msg2, wt_upd1, wt_upd2, wt_node);
  hipMemsetAsync(deg, 0, 2ull * NN * 4, stream);
  k_deg<<<dim3(625, 1, 2), 256, 0, stream>>>(ei1, ei2, deg);
  k_scan<<<dim3(1, 1, 2), 256, 0, stream>>>(deg, starts, cursor);
  k_scatter<<<dim3(625, 1, 2), 256, 0, stream>>>(ei1, ei2, cursor, srcs);
  k_embed<<<dim3(313, 1, 2), 256, 0, stream>>>(x1, x2, W_emb, b_emb, h, hb);

  for (int l = 0; l < 2; l++) {
    // PQ = h @ [W1_top | W1_bot]  -> [NN, 512] bf16
    GemmP pq{};
    pq.A = hb; pq.sA = (size_t)NN * 128;
    pq.Wt = wt_pq + (size_t)l * 512 * 128;
    pq.outb = PQ; pq.s_outb = (size_t)NN * 512;
    pq.M = NN; pq.N = 512; pq.K = 128; pq.ldo = 512; pq.mode = 5;
    k_gemm<<<dim3(79, 4, 2), 256, 0, stream>>>(pq);

    // S[n] = sum_{e: tgt=n} relu(P[src_e] + Q[n] + b1)
    k_edge<<<dim3(2500, 1, 2), 256, 0, stream>>>(PQ, starts, srcs, msg_b1 + l * 256, S);

    // ui[:, :256] = S @ W2 + deg*b2   (bf16, row stride 384)
    GemmP ag{};
    ag.A = S; ag.sA = (size_t)NN * 256;
    ag.Wt = wt_msg2 + (size_t)l * 65536; ag.bias = msg_b2 + l * 256; ag.deg = deg;
    ag.outb = ui; ag.s_outb = (size_t)NN * 384;
    ag.M = NN; ag.N = 256; ag.K = 256; ag.ldo = 384; ag.mode = 6;
    k_gemm<<<dim3(79, 2, 2), 256, 0, stream>>>(ag);

    // ui[:, 256:384] = h (bf16)
    k_copyh<<<dim3(5000, 1, 2), 256, 0, stream>>>(hb, ui);

    // U1 = relu(ui @ updW1 + ub1)
    GemmP p3{};
    p3.A = ui; p3.sA = (size_t)NN * 384;
    p3.Wt = wt_upd1 + (size_t)l * 98304; p3.bias = upd_b1 + l * 256;
    p3.outb = U1; p3.s_outb = (size_t)NN * 256;
    p3.M = NN; p3.N = 256; p3.K = 384; p3.ldo = 256; p3.mode = 2;
    k_gemm<<<dim3(79, 2, 2), 256, 0, stream>>>(p3);

    // h += U1 @ updW2 + ub2
    GemmP p4{};
    p4.A = U1; p4.sA = (size_t)NN * 256;
    p4.Wt = wt_upd2 + (size_t)l * 32768; p4.bias = upd_b2 + l * 128;
    p4.outf = h; p4.s_outf = (size_t)NN * 128;
    p4.outb2 = hb; p4.s_outb2 = (size_t)NN * 128;
    p4.M = NN; p4.N = 128; p4.K = 256; p4.ldo = 128; p4.mode = 3;
    k_gemm<<<dim3(79, 1, 2), 256, 0, stream>>>(p4);
  }

  // readout: nx = h @ nodeW + node_b (f32)
  GemmP p5{};
  p5.A = hb; p5.sA = (size_t)NN * 128;
  p5.Wt = wt_node; p5.bias = node_b;
  p5.outf = nx; p5.s_outf = (size_t)NN * 256;
  p5.M = NN; p5.N = 256; p5.K = 128; p5.ldo = 256; p5.mode = 4;
  k_gemm<<<dim3(79, 2, 2), 256, 0, stream>>>(p5);

  k_gate<<<dim3(NG, 1, 2), 256, 0, stream>>>(nx, bat1, bat2, g);
  k_final<<<dim3(NG, 1, 2), 128, 0, stream>>>(g, graph_W, graph_b, out);
}

// Round 3
// 421.726 us; speedup vs baseline: 3.6831x; 1.1817x over previous
//
#include <hip/hip_runtime.h>

typedef unsigned short u16;
typedef __bf16 bf16x8 __attribute__((ext_vector_type(8)));
typedef float f32x4 __attribute__((ext_vector_type(4)));
typedef unsigned short u16x8 __attribute__((ext_vector_type(8)));
typedef unsigned short u16x4 __attribute__((ext_vector_type(4)));

constexpr int NN  = 10000;   // nodes
constexpr int NE  = 160000;  // edges
constexpr int NG  = 32;      // graphs
constexpr int HD  = 128;     // hidden

// ---- workspace layout (bytes) ----
constexpr size_t WT_PQ   = 0;                  // [2][512][128] bf16 (msgW1 split/transposed)
constexpr size_t WT_M2R  = 262144;             // [2][256][256] bf16 (msgW2 row-major cast)
constexpr size_t WT_UPD1 = 524288;             // [2][256][384] bf16 (updW1 transposed; A for Wc gemm)
constexpr size_t WT_U1C  = 917504;             // [2][256][384] bf16 (combined UPD1' weight)
constexpr size_t WT_UPD2 = 1310720;            // [2][128][256]
constexpr size_t WT_NODE = 1441792;            // [256][128]
constexpr size_t OFF_C2  = 1507328;            // f32 [2][256]
constexpr size_t OFF_DEG = 1509376;            // int [2][NN]
constexpr size_t OFF_ST  = 1589376;            // int [2][NN+8]
constexpr size_t OFF_CUR = 1669440;            // int [2][NN]
constexpr size_t OFF_SRC = 1749440;            // int [2][NE]
constexpr size_t OFF_H   = 3029440;            // f32 [2][NN][128]
constexpr size_t OFF_HB  = 13269440;           // bf16 [2][NN][128]
constexpr size_t OFF_PQ  = 18389440;           // bf16 [2][NN][512]; overlays: U1 (first 10.24MB), nx f32 (full)
constexpr size_t OFF_UI  = 38869440;           // bf16 [2][NN][384]
constexpr size_t OFF_G   = 54229440;           // f32 [2][NG][128]
constexpr size_t OFF_U1  = OFF_PQ;             // bf16 [2][NN][256] (PQ dead by then)
constexpr size_t OFF_NX  = OFF_PQ;             // f32 [2][NN][256] (readout)

__device__ inline u16 f2b(float f) {
  unsigned int u = __float_as_uint(f);
  unsigned int r = u + 0x7fffu + ((u >> 16) & 1u);
  return (u16)(r >> 16);
}
__device__ inline float b2f(u16 u) { return __uint_as_float(((unsigned int)u) << 16); }

// ---------------- weight prep: transpose + bf16 cast ----------------
__global__ __launch_bounds__(256) void k_prep(
    const float* msgW1, const float* msgW2, const float* updW1,
    const float* updW2, const float* nodeW,
    u16* tpq, u16* t2r, u16* t3, u16* tu1c, u16* t4, u16* t5) {
  int idx = blockIdx.x * 256 + threadIdx.x;
  if (idx < 131072) {
    // wt_pq: [l][n=512][k=128]; n<256 -> W1[k][n] (src half), n>=256 -> W1[128+k][n-256]
    int l = idx >> 16, r = idx & 65535, n = r >> 7, k = r & 127;
    int row = (n < 256) ? k : (128 + k);
    tpq[idx] = f2b(msgW1[l * 65536 + row * 256 + (n & 255)]);
    // wt_m2r: straight cast of msgW2 [l][k=256][n=256]
    t2r[idx] = f2b(msgW2[idx]);
  }
  if (idx < 196608) {  // updW1: [l][k=384][n=256] -> [l][n=256][k=384]
    int l = idx / 98304, r = idx % 98304, n = r / 384, k = r % 384;
    t3[idx] = f2b(updW1[l * 98304 + k * 256 + n]);
  }
  if (idx < 65536) {   // u1c h-part: [l][n=256][256+k], k<128 <- updW1[l][256+k][n]
    int l = idx >> 15, r = idx & 32767, n = r >> 7, k = r & 127;
    tu1c[l * 98304 + n * 384 + 256 + k] = f2b(updW1[l * 98304 + (256 + k) * 256 + n]);
    // updW2: [l][k=256][n=128] -> [l][n=128][k=256]
    int n2 = (idx & 32767) >> 8, k2 = idx & 255;
    t4[idx] = f2b(updW2[(idx >> 15) * 32768 + (k2 << 7) + n2]);
  }
  if (idx < 32768) {   // nodeW: [k=128][n=256] -> [n=256][k=128]
    int n = idx >> 7, k = idx & 127;
    t5[idx] = f2b(nodeW[(k << 8) + n]);
  }
}

// ---------------- c2[l][n] = sum_c msg_b2[l][c] * updW1[l][c][n] ----------------
__global__ __launch_bounds__(128) void k_c2(const float* msgb2, const float* updW1, float* c2) {
  int idx = blockIdx.x * 128 + threadIdx.x;  // 512
  int l = idx >> 8, n = idx & 255;
  const float* b2 = msgb2 + l * 256;
  const float* U1 = updW1 + l * 98304 + n;
  float a = 0.f;
  for (int c = 0; c < 256; c++) a += b2[c] * U1[c * 256];
  c2[idx] = a;
}

// ---------------- counting sort of edges by tgt ----------------
__global__ __launch_bounds__(256) void k_deg(const int* ei0, const int* ei1, int* deg) {
  int br = blockIdx.z;
  int e = blockIdx.x * 256 + threadIdx.x;
  if (e >= NE) return;
  const int* tgt = br ? ei1 : ei0;
  atomicAdd(deg + br * NN + tgt[e], 1);
}

__global__ __launch_bounds__(256) void k_scan(const int* deg, int* starts, int* cursor) {
  int br = blockIdx.z;
  const int* d = deg + br * NN;
  int* st = starts + br * (NN + 8);
  int* cu = cursor + br * NN;
  __shared__ int part[257];
  int t = threadIdx.x;
  int c0 = t * 40;
  int s = 0;
  for (int i = 0; i < 40; i++) if (c0 + i < NN) s += d[c0 + i];
  part[t] = s;
  __syncthreads();
  if (t == 0) {
    int run = 0;
    for (int i = 0; i < 256; i++) { int v = part[i]; part[i] = run; run += v; }
    part[256] = run;
  }
  __syncthreads();
  int run = part[t];
  for (int i = 0; i < 40; i++) {
    int n = c0 + i;
    if (n < NN) { st[n] = run; cu[n] = run; run += d[n]; }
  }
  if (t == 255) st[NN] = part[256];
}

__global__ __launch_bounds__(256) void k_scatter(const int* ei0, const int* ei1,
                                                 int* cursor, int* srcs) {
  int br = blockIdx.z;
  int e = blockIdx.x * 256 + threadIdx.x;
  if (e >= NE) return;
  const int* ei = br ? ei1 : ei0;
  int t = ei[e], s = ei[NE + e];
  int pos = atomicAdd(cursor + br * NN + t, 1);
  srcs[br * NE + pos] = s;
}

// ---------------- embedding: h = x @ W_emb + b_emb (also seeds ui h-half) ---------
__global__ __launch_bounds__(256) void k_embed(
    const float* x1, const float* x2, const float* W, const float* b,
    float* h, u16* h_bf, u16* ui) {
  int br = blockIdx.z;
  const float* x = br ? x2 : x1;
  float* hB = h + (size_t)br * NN * HD;
  u16* hbB = h_bf + (size_t)br * NN * HD;
  u16* uiB = ui + (size_t)br * NN * 384;
  __shared__ float sW[64 * 128];
  __shared__ float sx[32 * 64];
  int tid = threadIdx.x;
  for (int i = tid; i < 64 * 128; i += 256) sW[i] = W[i];
  int r0 = blockIdx.x * 32;
  for (int i = tid; i < 32 * 64; i += 256) {
    int r = i >> 6, k = i & 63;
    sx[i] = (r0 + r < NN) ? x[(size_t)(r0 + r) * 64 + k] : 0.f;
  }
  __syncthreads();
  int c = tid & 127;
  int rbase = (tid >> 7) * 16;
  for (int r = rbase; r < rbase + 16; r++) {
    float acc = b[c];
#pragma unroll
    for (int k = 0; k < 64; k++) acc += sx[r * 64 + k] * sW[k * 128 + c];
    int gr = r0 + r;
    if (gr < NN) {
      u16 bv = f2b(acc);
      hB[(size_t)gr * HD + c] = acc;
      hbB[(size_t)gr * HD + c] = bv;
      uiB[(size_t)gr * 384 + 256 + c] = bv;
    }
  }
}

// ---------------- edge phase: ui[n][:256] = sum_e relu(P[src_e] + Q[n] + b1) ------
__global__ __launch_bounds__(256) void k_edge(const u16* PQ, const int* starts,
                                              const int* srcs, const float* b1, u16* ui) {
  int br = blockIdx.z;
  int node = blockIdx.x * 4 + (threadIdx.x >> 6);
  int lane = threadIdx.x & 63;
  int c0 = lane * 4;
  const u16* PQb = PQ + (size_t)br * NN * 512;
  const int* st = starts + br * (NN + 8);
  const int* sr = srcs + br * NE;
  u16x4 qr = *(const u16x4*)(PQb + (size_t)node * 512 + 256 + c0);
  float qv[4], acc[4] = {0.f, 0.f, 0.f, 0.f};
#pragma unroll
  for (int j = 0; j < 4; j++) qv[j] = b2f(qr[j]) + b1[c0 + j];
  int e0 = st[node], e1 = st[node + 1];
  int e = e0;
  for (; e + 3 < e1; e += 4) {
    int s0 = sr[e], s1 = sr[e + 1], s2 = sr[e + 2], s3 = sr[e + 3];
    u16x4 p0 = *(const u16x4*)(PQb + (size_t)s0 * 512 + c0);
    u16x4 p1 = *(const u16x4*)(PQb + (size_t)s1 * 512 + c0);
    u16x4 p2 = *(const u16x4*)(PQb + (size_t)s2 * 512 + c0);
    u16x4 p3 = *(const u16x4*)(PQb + (size_t)s3 * 512 + c0);
#pragma unroll
    for (int j = 0; j < 4; j++) {
      float v0 = b2f(p0[j]) + qv[j];
      float v1 = b2f(p1[j]) + qv[j];
      float v2 = b2f(p2[j]) + qv[j];
      float v3 = b2f(p3[j]) + qv[j];
      acc[j] += (v0 > 0.f ? v0 : 0.f) + (v1 > 0.f ? v1 : 0.f)
              + (v2 > 0.f ? v2 : 0.f) + (v3 > 0.f ? v3 : 0.f);
    }
  }
  for (; e < e1; e++) {
    int s0 = sr[e];
    u16x4 p0 = *(const u16x4*)(PQb + (size_t)s0 * 512 + c0);
#pragma unroll
    for (int j = 0; j < 4; j++) {
      float v0 = b2f(p0[j]) + qv[j];
      acc[j] += (v0 > 0.f ? v0 : 0.f);
    }
  }
  u16x4 o;
#pragma unroll
  for (int j = 0; j < 4; j++) o[j] = f2b(acc[j]);
  *(u16x4*)(ui + (size_t)br * NN * 384 + (size_t)node * 384 + c0) = o;
}

// ---------------- generic MFMA GEMM ----------------
// modes: 3 residual: h += v, write h f32 + hb bf16 + ui[:,256:384] bf16  (UPD2)
//        4 f32 store                          (NX)
//        5 plain bf16 store, no bias          (PQ, Wc)
//        7 relu(acc + bias + deg*bias2) bf16  (UPD1')
struct GemmP {
  const u16* A;   size_t sA;     // per-z stride (elements)
  int lda;                       // A row stride
  const u16* Wt;  size_t sW;     // [N][K] bf16, per-z stride
  const float* bias;
  const float* bias2;
  const int* deg;
  u16* outb;  size_t s_outb;     // bf16 out (mode 5/7); ui base (mode 3)
  float* outf; size_t s_outf;
  u16* outb2; size_t s_outb2;
  int M, N, K, ldo;
  int mode;
};

#define LSTR 40  // padded LDS row stride (u16) to break bank conflicts

__global__ __launch_bounds__(256) void k_gemm(GemmP p) {
  const int br = blockIdx.z;
  const int tid = threadIdx.x;
  const int lane = tid & 63, wave = tid >> 6;
  const int wm = (wave & 1) * 64, wn = (wave >> 1) * 64;
  const int q = lane >> 4, lr = lane & 15;
  const int m0 = blockIdx.x * 128, n0 = blockIdx.y * 128;
  __shared__ alignas(16) u16 lA[128 * LSTR];
  __shared__ alignas(16) u16 lB[128 * LSTR];

  f32x4 acc[4][4];
#pragma unroll
  for (int i = 0; i < 4; i++)
#pragma unroll
    for (int j = 0; j < 4; j++) acc[i][j] = (f32x4){0.f, 0.f, 0.f, 0.f};

  const u16* Abr = p.A + (size_t)br * p.sA;
  const u16* Wbr = p.Wt + (size_t)br * p.sW;

  for (int k0 = 0; k0 < p.K; k0 += 32) {
#pragma unroll
    for (int c = tid; c < 512; c += 256) {
      int r = c >> 2, kc = (c & 3) << 3;
      int gr = m0 + r;
      u16x8 v = {0, 0, 0, 0, 0, 0, 0, 0};
      if (gr < p.M) v = *(const u16x8*)(Abr + (size_t)gr * p.lda + k0 + kc);
      *(u16x8*)&lA[r * LSTR + kc] = v;
    }
#pragma unroll
    for (int c = tid; c < 512; c += 256) {
      int r = c >> 2, kc = (c & 3) << 3;
      *(u16x8*)&lB[r * LSTR + kc] = *(const u16x8*)(Wbr + (size_t)(n0 + r) * p.K + k0 + kc);
    }
    __syncthreads();
    bf16x8 af[4], bfr[4];
#pragma unroll
    for (int i = 0; i < 4; i++) af[i] = *(const bf16x8*)&lA[(wm + i * 16 + lr) * LSTR + q * 8];
#pragma unroll
    for (int i = 0; i < 4; i++) bfr[i] = *(const bf16x8*)&lB[(wn + i * 16 + lr) * LSTR + q * 8];
#pragma unroll
    for (int mi = 0; mi < 4; mi++)
#pragma unroll
      for (int ni = 0; ni < 4; ni++)
        acc[mi][ni] = __builtin_amdgcn_mfma_f32_16x16x32_bf16(af[mi], bfr[ni], acc[mi][ni], 0, 0, 0);
    __syncthreads();
  }

  // C/D layout: col=lane&15, row=(lane>>4)*4+reg
  if (p.mode == 3) {
    float* hf = p.outf + (size_t)br * p.s_outf;
    u16* hb = p.outb2 + (size_t)br * p.s_outb2;
    u16* ub = p.outb + (size_t)br * p.s_outb;
#pragma unroll
    for (int mi = 0; mi < 4; mi++)
#pragma unroll
      for (int rg = 0; rg < 4; rg++) {
        int row = m0 + wm + mi * 16 + q * 4 + rg;
        if (row >= p.M) continue;
#pragma unroll
        for (int ni = 0; ni < 4; ni++) {
          int col = n0 + wn + ni * 16 + lr;
          size_t o = (size_t)row * p.ldo + col;
          float nh = hf[o] + acc[mi][ni][rg] + p.bias[col];
          u16 bv = f2b(nh);
          hf[o] = nh;
          hb[o] = bv;
          ub[(size_t)row * 384 + 256 + col] = bv;
        }
      }
  } else if (p.mode == 4) {
    float* of = p.outf + (size_t)br * p.s_outf;
#pragma unroll
    for (int mi = 0; mi < 4; mi++)
#pragma unroll
      for (int rg = 0; rg < 4; rg++) {
        int row = m0 + wm + mi * 16 + q * 4 + rg;
        if (row >= p.M) continue;
#pragma unroll
        for (int ni = 0; ni < 4; ni++) {
          int col = n0 + wn + ni * 16 + lr;
          of[(size_t)row * p.ldo + col] = acc[mi][ni][rg] + p.bias[col];
        }
      }
  } else if (p.mode == 5) {
    u16* ob = p.outb + (size_t)br * p.s_outb;
#pragma unroll
    for (int mi = 0; mi < 4; mi++)
#pragma unroll
      for (int rg = 0; rg < 4; rg++) {
        int row = m0 + wm + mi * 16 + q * 4 + rg;
        if (row >= p.M) continue;
#pragma unroll
        for (int ni = 0; ni < 4; ni++) {
          int col = n0 + wn + ni * 16 + lr;
          ob[(size_t)row * p.ldo + col] = f2b(acc[mi][ni][rg]);
        }
      }
  } else {  // mode 7: relu(acc + bias + deg*bias2)
    u16* ob = p.outb + (size_t)br * p.s_outb;
    const int* dg = p.deg + br * NN;
#pragma unroll
    for (int mi = 0; mi < 4; mi++)
#pragma unroll
      for (int rg = 0; rg < 4; rg++) {
        int row = m0 + wm + mi * 16 + q * 4 + rg;
        if (row >= p.M) continue;
        float d = (float)dg[row];
#pragma unroll
        for (int ni = 0; ni < 4; ni++) {
          int col = n0 + wn + ni * 16 + lr;
          float v = acc[mi][ni][rg] + p.bias[col] + d * p.bias2[col];
          if (v < 0.f) v = 0.f;
          ob[(size_t)row * p.ldo + col] = f2b(v);
        }
      }
  }
}

// ---------------- gated pooling: chunked nodes, few atomics ----------------
__global__ __launch_bounds__(256) void k_gate(const float* nx, const int* b0v,
                                              const int* b1v, float* g) {
  int br = blockIdx.z;
  const int* batch = br ? b1v : b0v;
  int n0 = blockIdx.x * 128;
  int col = threadIdx.x & 127, half = threadIdx.x >> 7;
  __shared__ int sbat[128];
  if (threadIdx.x < 128) {
    int n = n0 + threadIdx.x;
    sbat[threadIdx.x] = (n < NN) ? batch[n] : -1;
  }
  __syncthreads();
  const float* nxb = nx + (size_t)br * NN * 256;
  float* gb = g + (size_t)br * NG * 128;
  float acc = 0.f;
  int cur = -1;
  for (int r = half * 64; r < half * 64 + 64; r++) {
    int n = n0 + r;
    if (n >= NN) break;
    int bt = sbat[r];
    if (bt != cur) {
      if (cur >= 0) atomicAdd(gb + (size_t)cur * 128 + col, acc);
      cur = bt;
      acc = 0.f;
    }
    float gt = nxb[(size_t)n * 256 + col];
    float vl = nxb[(size_t)n * 256 + 128 + col];
    acc += vl / (1.f + __expf(-gt));
  }
  if (cur >= 0) atomicAdd(gb + (size_t)cur * 128 + col, acc);
}

// ---------------- final graph GEMM ----------------
__global__ __launch_bounds__(128) void k_final(const float* g, const float* W,
                                               const float* b, float* out) {
  int br = blockIdx.z, gi = blockIdx.x, j = threadIdx.x;
  __shared__ float sg[128];
  sg[j] = g[(size_t)br * NG * 128 + (size_t)gi * 128 + j];
  __syncthreads();
  float acc = b[j];
#pragma unroll
  for (int k = 0; k < 128; k++) acc += sg[k] * W[k * 128 + j];
  out[(size_t)br * NG * 128 + (size_t)gi * 128 + j] = acc;
}

extern "C" void kernel_launch(void* const* d_in, const int* in_sizes, int n_in,
                              void* d_out, int out_size, void* d_ws, size_t ws_size,
                              hipStream_t stream) {
  const float* x1     = (const float*)d_in[0];
  const int*   ei1    = (const int*)d_in[1];
  const int*   bat1   = (const int*)d_in[2];
  const float* x2     = (const float*)d_in[3];
  const int*   ei2    = (const int*)d_in[4];
  const int*   bat2   = (const int*)d_in[5];
  const float* W_emb  = (const float*)d_in[6];
  const float* b_emb  = (const float*)d_in[7];
  const float* msg_W1 = (const float*)d_in[8];
  const float* msg_b1 = (const float*)d_in[9];
  const float* msg_W2 = (const float*)d_in[10];
  const float* msg_b2 = (const float*)d_in[11];
  const float* upd_W1 = (const float*)d_in[12];
  const float* upd_b1 = (const float*)d_in[13];
  const float* upd_W2 = (const float*)d_in[14];
  const float* upd_b2 = (const float*)d_in[15];
  const float* node_W = (const float*)d_in[16];
  const float* node_b = (const float*)d_in[17];
  const float* graph_W = (const float*)d_in[18];
  const float* graph_b = (const float*)d_in[19];
  float* out = (float*)d_out;

  char* ws = (char*)d_ws;
  u16* wt_pq   = (u16*)(ws + WT_PQ);
  u16* wt_m2r  = (u16*)(ws + WT_M2R);
  u16* wt_upd1 = (u16*)(ws + WT_UPD1);
  u16* wt_u1c  = (u16*)(ws + WT_U1C);
  u16* wt_upd2 = (u16*)(ws + WT_UPD2);
  u16* wt_node = (u16*)(ws + WT_NODE);
  float* c2    = (float*)(ws + OFF_C2);
  int* deg    = (int*)(ws + OFF_DEG);
  int* starts = (int*)(ws + OFF_ST);
  int* cursor = (int*)(ws + OFF_CUR);
  int* srcs   = (int*)(ws + OFF_SRC);
  float* h  = (float*)(ws + OFF_H);
  u16*   hb = (u16*)(ws + OFF_HB);
  u16*   PQ = (u16*)(ws + OFF_PQ);
  u16*   ui = (u16*)(ws + OFF_UI);
  u16*   U1 = (u16*)(ws + OFF_U1);
  float* nx = (float*)(ws + OFF_NX);
  float* g  = (float*)(ws + OFF_G);

  // ---- prep ----
  k_prep<<<768, 256, 0, stream>>>(msg_W1, msg_W2, upd_W1, upd_W2, node_W,
                                  wt_pq, wt_m2r, wt_upd1, wt_u1c, wt_upd2, wt_node);
  k_c2<<<4, 128, 0, stream>>>(msg_b2, upd_W1, c2);
  // Wc = W2 @ W1u_top -> wt_u1c[:, :256] (z = layer)
  {
    GemmP pc{};
    pc.A = wt_upd1; pc.sA = 98304; pc.lda = 384;
    pc.Wt = wt_m2r; pc.sW = 65536;
    pc.outb = wt_u1c; pc.s_outb = 98304;
    pc.M = 256; pc.N = 256; pc.K = 256; pc.ldo = 384; pc.mode = 5;
    k_gemm<<<dim3(2, 2, 2), 256, 0, stream>>>(pc);
  }
  hipMemsetAsync(deg, 0, 2ull * NN * 4, stream);
  k_deg<<<dim3(625, 1, 2), 256, 0, stream>>>(ei1, ei2, deg);
  k_scan<<<dim3(1, 1, 2), 256, 0, stream>>>(deg, starts, cursor);
  k_scatter<<<dim3(625, 1, 2), 256, 0, stream>>>(ei1, ei2, cursor, srcs);
  k_embed<<<dim3(313, 1, 2), 256, 0, stream>>>(x1, x2, W_emb, b_emb, h, hb, ui);

  for (int l = 0; l < 2; l++) {
    // PQ = h @ [W1_top | W1_bot]  -> [NN, 512] bf16
    GemmP pq{};
    pq.A = hb; pq.sA = (size_t)NN * 128; pq.lda = 128;
    pq.Wt = wt_pq + (size_t)l * 65536; pq.sW = 0;
    pq.outb = PQ; pq.s_outb = (size_t)NN * 512;
    pq.M = NN; pq.N = 512; pq.K = 128; pq.ldo = 512; pq.mode = 5;
    k_gemm<<<dim3(79, 4, 2), 256, 0, stream>>>(pq);

    // ui[:, :256] = S[n] = sum_{e: tgt=n} relu(P[src_e] + Q[n] + b1)
    k_edge<<<dim3(2500, 1, 2), 256, 0, stream>>>(PQ, starts, srcs, msg_b1 + l * 256, ui);

    // U1 = relu([S|h] @ [Wc ; W1u_bot] + b1u + deg*c2)
    GemmP p3{};
    p3.A = ui; p3.sA = (size_t)NN * 384; p3.lda = 384;
    p3.Wt = wt_u1c + (size_t)l * 98304; p3.sW = 0;
    p3.bias = upd_b1 + l * 256; p3.bias2 = c2 + l * 256; p3.deg = deg;
    p3.outb = U1; p3.s_outb = (size_t)NN * 256;
    p3.M = NN; p3.N = 256; p3.K = 384; p3.ldo = 256; p3.mode = 7;
    k_gemm<<<dim3(79, 2, 2), 256, 0, stream>>>(p3);

    // h += U1 @ updW2 + ub2 ; refresh hb and ui[:,256:384]
    GemmP p4{};
    p4.A = U1; p4.sA = (size_t)NN * 256; p4.lda = 256;
    p4.Wt = wt_upd2 + (size_t)l * 32768; p4.sW = 0;
    p4.bias = upd_b2 + l * 128;
    p4.outf = h; p4.s_outf = (size_t)NN * 128;
    p4.outb2 = hb; p4.s_outb2 = (size_t)NN * 128;
    p4.outb = ui; p4.s_outb = (size_t)NN * 384;
    p4.M = NN; p4.N = 128; p4.K = 256; p4.ldo = 128; p4.mode = 3;
    k_gemm<<<dim3(79, 1, 2), 256, 0, stream>>>(p4);
  }

  // readout: nx = h @ nodeW + node_b (f32)  [nx overlays PQ/U1 region]
  GemmP p5{};
  p5.A = hb; p5.sA = (size_t)NN * 128; p5.lda = 128;
  p5.Wt = wt_node; p5.sW = 0;
  p5.bias = node_b;
  p5.outf = nx; p5.s_outf = (size_t)NN * 256;
  p5.M = NN; p5.N = 256; p5.K = 128; p5.ldo = 256; p5.mode = 4;
  k_gemm<<<dim3(79, 2, 2), 256, 0, stream>>>(p5);

  hipMemsetAsync(g, 0, 2ull * NG * 128 * 4, stream);
  k_gate<<<dim3(79, 1, 2), 256, 0, stream>>>(nx, bat1, bat2, g);
  k_final<<<dim3(NG, 1, 2), 128, 0, stream>>>(g, graph_W, graph_b, out);
}

// Round 4
// 384.393 us; speedup vs baseline: 4.0408x; 1.0971x over previous
//
#include <hip/hip_runtime.h>

typedef unsigned short u16;
typedef __bf16 bf16x8 __attribute__((ext_vector_type(8)));
typedef float f32x4 __attribute__((ext_vector_type(4)));
typedef unsigned short u16x8 __attribute__((ext_vector_type(8)));

constexpr int NN  = 10000;   // nodes
constexpr int NE  = 160000;  // edges
constexpr int NG  = 32;      // graphs
constexpr int HD  = 128;     // hidden

// ---- workspace layout (bytes) ----
constexpr size_t WT_PQ   = 0;                  // [2][512][128] bf16 (msgW1 split/transposed)
constexpr size_t WT_M2R  = 262144;             // [2][256][256] bf16 (msgW2 row-major cast)
constexpr size_t WT_UPD1 = 524288;             // [2][256][384] bf16 (updW1 transposed)
constexpr size_t WT_U1C  = 917504;             // [2][256][384] bf16 (combined UPD1' weight)
constexpr size_t WT_UPD2 = 1310720;            // [2][128][256]
constexpr size_t WT_NODE = 1441792;            // [256][128]
constexpr size_t OFF_C2  = 1507328;            // f32 [2][256]
constexpr size_t OFF_DEG = 1509376;            // int [2][NN]
constexpr size_t OFF_ST  = 1589376;            // int [2][NN+8]
constexpr size_t OFF_CUR = 1669440;            // int [2][NN]
constexpr size_t OFF_SRC = 1749440;            // int [2][NE]
constexpr size_t OFF_H   = 3029440;            // f32 [2][NN][128]
constexpr size_t OFF_HB  = 13269440;           // bf16 [2][NN][128]
constexpr size_t OFF_PQ  = 18389440;           // bf16 [2][NN][512]
constexpr size_t OFF_UI  = 38869440;           // bf16 [2][NN][384]
constexpr size_t OFF_G   = 54229440;           // f32 [2][NG][128]

__device__ inline u16 f2b(float f) {
  unsigned int u = __float_as_uint(f);
  unsigned int r = u + 0x7fffu + ((u >> 16) & 1u);
  return (u16)(r >> 16);
}
__device__ inline float b2f(u16 u) { return __uint_as_float(((unsigned int)u) << 16); }

// ---------------- weight prep (+ c2, + zero deg/g) ----------------
__global__ __launch_bounds__(256) void k_prep(
    const float* msgW1, const float* msgW2, const float* updW1,
    const float* updW2, const float* nodeW, const float* msgb2,
    u16* tpq, u16* t2r, u16* t3, u16* tu1c, u16* t4, u16* t5,
    float* c2, int* deg, float* g) {
  int idx = blockIdx.x * 256 + threadIdx.x;
  if (idx < 131072) {
    // wt_pq: [l][n=512][k=128]; n<256 -> W1[k][n] (src half), n>=256 -> W1[128+k][n-256]
    int l = idx >> 16, r = idx & 65535, n = r >> 7, k = r & 127;
    int row = (n < 256) ? k : (128 + k);
    tpq[idx] = f2b(msgW1[l * 65536 + row * 256 + (n & 255)]);
    // wt_m2r: straight cast of msgW2 [l][k=256][n=256]
    t2r[idx] = f2b(msgW2[idx]);
  }
  if (idx < 196608) {  // updW1: [l][k=384][n=256] -> [l][n=256][k=384]
    int l = idx / 98304, r = idx % 98304, n = r / 384, k = r % 384;
    t3[idx] = f2b(updW1[l * 98304 + k * 256 + n]);
  }
  if (idx < 65536) {   // u1c h-part: [l][n=256][256+k], k<128 <- updW1[l][256+k][n]
    int l = idx >> 15, r = idx & 32767, n = r >> 7, k = r & 127;
    tu1c[l * 98304 + n * 384 + 256 + k] = f2b(updW1[l * 98304 + (256 + k) * 256 + n]);
    // updW2: [l][k=256][n=128] -> [l][n=128][k=256]
    int n2 = (idx & 32767) >> 8, k2 = idx & 255;
    t4[idx] = f2b(updW2[(idx >> 15) * 32768 + (k2 << 7) + n2]);
  }
  if (idx < 32768) {   // nodeW: [k=128][n=256] -> [n=256][k=128]
    int n = idx >> 7, k = idx & 127;
    t5[idx] = f2b(nodeW[(k << 8) + n]);
  }
  if (idx < 512) {     // c2[l][n] = sum_c msg_b2[l][c] * updW1[l][c][n]
    int l = idx >> 8, n = idx & 255;
    const float* b2 = msgb2 + l * 256;
    const float* U1 = updW1 + l * 98304 + n;
    float a = 0.f;
    for (int c = 0; c < 256; c++) a += b2[c] * U1[c * 256];
    c2[idx] = a;
  }
  if (idx < 2 * NN) deg[idx] = 0;
  if (idx < 2 * NG * 128) g[idx] = 0.f;
}

// ---------------- counting sort of edges by tgt ----------------
__global__ __launch_bounds__(256) void k_deg(const int* ei0, const int* ei1, int* deg) {
  int br = blockIdx.z;
  int e = blockIdx.x * 256 + threadIdx.x;
  if (e >= NE) return;
  const int* tgt = br ? ei1 : ei0;
  atomicAdd(deg + br * NN + tgt[e], 1);
}

__global__ __launch_bounds__(256) void k_scan(const int* deg, int* starts, int* cursor) {
  int br = blockIdx.z;
  const int* d = deg + br * NN;
  int* st = starts + br * (NN + 8);
  int* cu = cursor + br * NN;
  __shared__ int part[257];
  int t = threadIdx.x;
  int c0 = t * 40;
  int s = 0;
  for (int i = 0; i < 40; i++) if (c0 + i < NN) s += d[c0 + i];
  part[t] = s;
  __syncthreads();
  if (t == 0) {
    int run = 0;
    for (int i = 0; i < 256; i++) { int v = part[i]; part[i] = run; run += v; }
    part[256] = run;
  }
  __syncthreads();
  int run = part[t];
  for (int i = 0; i < 40; i++) {
    int n = c0 + i;
    if (n < NN) { st[n] = run; cu[n] = run; run += d[n]; }
  }
  if (t == 255) st[NN] = part[256];
}

__global__ __launch_bounds__(256) void k_scatter(const int* ei0, const int* ei1,
                                                 int* cursor, int* srcs) {
  int br = blockIdx.z;
  int e = blockIdx.x * 256 + threadIdx.x;
  if (e >= NE) return;
  const int* ei = br ? ei1 : ei0;
  int t = ei[e], s = ei[NE + e];
  int pos = atomicAdd(cursor + br * NN + t, 1);
  srcs[br * NE + pos] = s;
}

// ---------------- embedding: h = x @ W_emb + b_emb (also seeds ui h-half) ---------
__global__ __launch_bounds__(256) void k_embed(
    const float* x1, const float* x2, const float* W, const float* b,
    float* h, u16* h_bf, u16* ui) {
  int br = blockIdx.z;
  const float* x = br ? x2 : x1;
  float* hB = h + (size_t)br * NN * HD;
  u16* hbB = h_bf + (size_t)br * NN * HD;
  u16* uiB = ui + (size_t)br * NN * 384;
  __shared__ float sW[64 * 128];
  __shared__ float sx[32 * 64];
  int tid = threadIdx.x;
  for (int i = tid; i < 64 * 128; i += 256) sW[i] = W[i];
  int r0 = blockIdx.x * 32;
  for (int i = tid; i < 32 * 64; i += 256) {
    int r = i >> 6, k = i & 63;
    sx[i] = (r0 + r < NN) ? x[(size_t)(r0 + r) * 64 + k] : 0.f;
  }
  __syncthreads();
  int c = tid & 127;
  int rbase = (tid >> 7) * 16;
  for (int r = rbase; r < rbase + 16; r++) {
    float acc = b[c];
#pragma unroll
    for (int k = 0; k < 64; k++) acc += sx[r * 64 + k] * sW[k * 128 + c];
    int gr = r0 + r;
    if (gr < NN) {
      u16 bv = f2b(acc);
      hB[(size_t)gr * HD + c] = acc;
      hbB[(size_t)gr * HD + c] = bv;
      uiB[(size_t)gr * 384 + 256 + c] = bv;
    }
  }
}

// ---------------- edge phase: ui[n][:256] = sum_e relu(P[src_e] + Q[n] + b1) ------
// Half-wave per edge: 32 lanes x u16x8 = one 512B P row per issue.
__global__ __launch_bounds__(256) void k_edge(const u16* PQ, const int* starts,
                                              const int* srcs, const float* b1, u16* ui) {
  int br = blockIdx.z;
  int node = blockIdx.x * 4 + (threadIdx.x >> 6);
  int lane = threadIdx.x & 63;
  int half = lane >> 5;
  int c0 = (lane & 31) * 8;
  const u16* PQb = PQ + (size_t)br * NN * 512;
  const int* st = starts + br * (NN + 8);
  const int* sr = srcs + br * NE;
  u16x8 qr = *(const u16x8*)(PQb + (size_t)node * 512 + 256 + c0);
  float qv[8], acc[8];
#pragma unroll
  for (int j = 0; j < 8; j++) { qv[j] = b2f(qr[j]) + b1[c0 + j]; acc[j] = 0.f; }
  int e0 = st[node], e1 = st[node + 1];
  int e = e0 + half;
  for (; e + 2 < e1; e += 4) {
    int s0 = sr[e], s1 = sr[e + 2];
    u16x8 p0 = *(const u16x8*)(PQb + (size_t)s0 * 512 + c0);
    u16x8 p1 = *(const u16x8*)(PQb + (size_t)s1 * 512 + c0);
#pragma unroll
    for (int j = 0; j < 8; j++) {
      float v0 = b2f(p0[j]) + qv[j];
      float v1 = b2f(p1[j]) + qv[j];
      acc[j] += (v0 > 0.f ? v0 : 0.f) + (v1 > 0.f ? v1 : 0.f);
    }
  }
  for (; e < e1; e += 2) {
    int s0 = sr[e];
    u16x8 p0 = *(const u16x8*)(PQb + (size_t)s0 * 512 + c0);
#pragma unroll
    for (int j = 0; j < 8; j++) {
      float v0 = b2f(p0[j]) + qv[j];
      acc[j] += (v0 > 0.f ? v0 : 0.f);
    }
  }
#pragma unroll
  for (int j = 0; j < 8; j++) acc[j] += __shfl_xor(acc[j], 32);
  if (half == 0) {
    u16x8 o;
#pragma unroll
    for (int j = 0; j < 8; j++) o[j] = f2b(acc[j]);
    *(u16x8*)(ui + (size_t)br * NN * 384 + (size_t)node * 384 + c0) = o;
  }
}

// ---------------- plain MFMA GEMM (bf16 store, no bias): PQ + Wc prep ----------
struct GemmP {
  const u16* A;   size_t sA;     // per-z stride (elements)
  int lda;
  const u16* Wt;  size_t sW;     // [N][K] bf16, per-z stride
  u16* outb;  size_t s_outb;
  int M, N, K, ldo;
};

#define LSTR 40

__global__ __launch_bounds__(256) void k_gemm(GemmP p) {
  const int br = blockIdx.z;
  const int tid = threadIdx.x;
  const int lane = tid & 63, wave = tid >> 6;
  const int wm = (wave & 1) * 64, wn = (wave >> 1) * 64;
  const int q = lane >> 4, lr = lane & 15;
  const int m0 = blockIdx.x * 128, n0 = blockIdx.y * 128;
  __shared__ alignas(16) u16 lA[128 * LSTR];
  __shared__ alignas(16) u16 lB[128 * LSTR];

  f32x4 acc[4][4];
#pragma unroll
  for (int i = 0; i < 4; i++)
#pragma unroll
    for (int j = 0; j < 4; j++) acc[i][j] = (f32x4){0.f, 0.f, 0.f, 0.f};

  const u16* Abr = p.A + (size_t)br * p.sA;
  const u16* Wbr = p.Wt + (size_t)br * p.sW;

  for (int k0 = 0; k0 < p.K; k0 += 32) {
#pragma unroll
    for (int c = tid; c < 512; c += 256) {
      int r = c >> 2, kc = (c & 3) << 3;
      int gr = m0 + r;
      u16x8 v = {0, 0, 0, 0, 0, 0, 0, 0};
      if (gr < p.M) v = *(const u16x8*)(Abr + (size_t)gr * p.lda + k0 + kc);
      *(u16x8*)&lA[r * LSTR + kc] = v;
    }
#pragma unroll
    for (int c = tid; c < 512; c += 256) {
      int r = c >> 2, kc = (c & 3) << 3;
      *(u16x8*)&lB[r * LSTR + kc] = *(const u16x8*)(Wbr + (size_t)(n0 + r) * p.K + k0 + kc);
    }
    __syncthreads();
    bf16x8 af[4], bfr[4];
#pragma unroll
    for (int i = 0; i < 4; i++) af[i] = *(const bf16x8*)&lA[(wm + i * 16 + lr) * LSTR + q * 8];
#pragma unroll
    for (int i = 0; i < 4; i++) bfr[i] = *(const bf16x8*)&lB[(wn + i * 16 + lr) * LSTR + q * 8];
#pragma unroll
    for (int mi = 0; mi < 4; mi++)
#pragma unroll
      for (int ni = 0; ni < 4; ni++)
        acc[mi][ni] = __builtin_amdgcn_mfma_f32_16x16x32_bf16(af[mi], bfr[ni], acc[mi][ni], 0, 0, 0);
    __syncthreads();
  }

  u16* ob = p.outb + (size_t)br * p.s_outb;
#pragma unroll
  for (int mi = 0; mi < 4; mi++)
#pragma unroll
    for (int rg = 0; rg < 4; rg++) {
      int row = m0 + wm + mi * 16 + q * 4 + rg;
      if (row >= p.M) continue;
#pragma unroll
      for (int ni = 0; ni < 4; ni++) {
        int col = n0 + wn + ni * 16 + lr;
        ob[(size_t)row * p.ldo + col] = f2b(acc[mi][ni][rg]);
      }
    }
}

// ---------------- fused update MLP: U1=relu(ui@W1c+b+deg*c2); h+=U1@W2+b2 ---------
// Phase1: 128x256 strip in regs -> bf16 in LDS. Phase2: MFMA vs W2 (global B-frags).
__global__ __launch_bounds__(256, 2) void k_upd(
    const u16* ui_all, const u16* w1c, const float* b1u, const float* c2l,
    const int* deg_all, const u16* w2, const float* b2u,
    float* h_all, u16* hb_all) {
  const int br = blockIdx.z;
  const int tid = threadIdx.x;
  const int lane = tid & 63, wave = tid >> 6;
  const int q = lane >> 4, lr = lane & 15;
  const int m0 = blockIdx.x * 128;

  __shared__ alignas(16) u16 sm[128 * 264];  // phase1: lA(5120)+lB(10240); then lU
  u16* lA = sm;
  u16* lB = sm + 5120;

  const u16* ui = ui_all + (size_t)br * NN * 384;
  const int* deg = deg_all + br * NN;
  float* h = h_all + (size_t)br * NN * 128;
  u16* hb = hb_all + (size_t)br * NN * 128;
  u16* uiw = (u16*)ui_all + (size_t)br * NN * 384;

  // ---- phase 1: wave computes 64 rows x 128 cols of U1 ----
  const int wm = (wave & 1) * 64, wn = (wave >> 1) * 128;
  f32x4 acc[4][8];
#pragma unroll
  for (int i = 0; i < 4; i++)
#pragma unroll
    for (int j = 0; j < 8; j++) acc[i][j] = (f32x4){0.f, 0.f, 0.f, 0.f};

  for (int k0 = 0; k0 < 384; k0 += 32) {
#pragma unroll
    for (int c = tid; c < 512; c += 256) {
      int r = c >> 2, kc = (c & 3) << 3;
      int gr = m0 + r;
      u16x8 v = {0, 0, 0, 0, 0, 0, 0, 0};
      if (gr < NN) v = *(const u16x8*)(ui + (size_t)gr * 384 + k0 + kc);
      *(u16x8*)&lA[r * LSTR + kc] = v;
    }
#pragma unroll
    for (int c = tid; c < 1024; c += 256) {
      int r = c >> 2, kc = (c & 3) << 3;
      *(u16x8*)&lB[r * LSTR + kc] = *(const u16x8*)(w1c + (size_t)r * 384 + k0 + kc);
    }
    __syncthreads();
    bf16x8 af[4], bfr[8];
#pragma unroll
    for (int i = 0; i < 4; i++) af[i] = *(const bf16x8*)&lA[(wm + i * 16 + lr) * LSTR + q * 8];
#pragma unroll
    for (int i = 0; i < 8; i++) bfr[i] = *(const bf16x8*)&lB[(wn + i * 16 + lr) * LSTR + q * 8];
#pragma unroll
    for (int mi = 0; mi < 4; mi++)
#pragma unroll
      for (int ni = 0; ni < 8; ni++)
        acc[mi][ni] = __builtin_amdgcn_mfma_f32_16x16x32_bf16(af[mi], bfr[ni], acc[mi][ni], 0, 0, 0);
    __syncthreads();
  }

  // relu + bias + deg*c2 -> bf16 into lU (stride 264)
  u16* lU = sm;
#pragma unroll
  for (int mi = 0; mi < 4; mi++)
#pragma unroll
    for (int rg = 0; rg < 4; rg++) {
      int row = wm + mi * 16 + q * 4 + rg;
      int gr = m0 + row;
      float d = (gr < NN) ? (float)deg[gr] : 0.f;
#pragma unroll
      for (int ni = 0; ni < 8; ni++) {
        int col = wn + ni * 16 + lr;
        float v = acc[mi][ni][rg] + b1u[col] + d * c2l[col];
        if (v < 0.f) v = 0.f;
        lU[row * 264 + col] = f2b(v);
      }
    }
  __syncthreads();

  // ---- phase 2: 128x128 = lU(128x256) @ W2^T, B-frags from global ----
  const int wm2 = (wave & 1) * 64, wn2 = (wave >> 1) * 64;
  f32x4 facc[4][4];
#pragma unroll
  for (int i = 0; i < 4; i++)
#pragma unroll
    for (int j = 0; j < 4; j++) facc[i][j] = (f32x4){0.f, 0.f, 0.f, 0.f};

  for (int k0 = 0; k0 < 256; k0 += 32) {
    bf16x8 af[4], bfr[4];
#pragma unroll
    for (int i = 0; i < 4; i++)
      af[i] = *(const bf16x8*)&lU[(wm2 + i * 16 + lr) * 264 + k0 + q * 8];
#pragma unroll
    for (int i = 0; i < 4; i++)
      bfr[i] = *(const bf16x8*)(w2 + (size_t)(wn2 + i * 16 + lr) * 256 + k0 + q * 8);
#pragma unroll
    for (int mi = 0; mi < 4; mi++)
#pragma unroll
      for (int ni = 0; ni < 4; ni++)
        facc[mi][ni] = __builtin_amdgcn_mfma_f32_16x16x32_bf16(af[mi], bfr[ni], facc[mi][ni], 0, 0, 0);
  }

  // residual epilogue
#pragma unroll
  for (int mi = 0; mi < 4; mi++)
#pragma unroll
    for (int rg = 0; rg < 4; rg++) {
      int row = m0 + wm2 + mi * 16 + q * 4 + rg;
      if (row >= NN) continue;
#pragma unroll
      for (int ni = 0; ni < 4; ni++) {
        int col = wn2 + ni * 16 + lr;
        size_t o = (size_t)row * 128 + col;
        float nh = h[o] + facc[mi][ni][rg] + b2u[col];
        u16 bv = f2b(nh);
        h[o] = nh;
        hb[o] = bv;
        uiw[(size_t)row * 384 + 256 + col] = bv;
      }
    }
}

// ---------------- fused readout: nx = hb@nodeW + b; gate; pool into g ------------
// Wave computes 64 rows x (64 gate cols + 64 paired val cols).
__global__ __launch_bounds__(256, 2) void k_nxg(
    const u16* hb_all, const u16* wnode, const float* nb,
    const int* b0v, const int* b1v, float* g) {
  const int br = blockIdx.z;
  const int tid = threadIdx.x;
  const int lane = tid & 63, wave = tid >> 6;
  const int q = lane >> 4, lr = lane & 15;
  const int m0 = blockIdx.x * 128;
  const int wm = (wave & 1) * 64, wg = (wave >> 1) * 64;

  __shared__ alignas(16) u16 lA[128 * LSTR];
  __shared__ alignas(16) u16 lB[256 * LSTR];
  __shared__ int sbat[128];

  const u16* hb = hb_all + (size_t)br * NN * 128;
  const int* batch = br ? b1v : b0v;
  if (tid < 128) {
    int n = m0 + tid;
    sbat[tid] = (n < NN) ? batch[n] : -1;
  }

  f32x4 acc[4][8];
#pragma unroll
  for (int i = 0; i < 4; i++)
#pragma unroll
    for (int j = 0; j < 8; j++) acc[i][j] = (f32x4){0.f, 0.f, 0.f, 0.f};

  for (int k0 = 0; k0 < 128; k0 += 32) {
#pragma unroll
    for (int c = tid; c < 512; c += 256) {
      int r = c >> 2, kc = (c & 3) << 3;
      int gr = m0 + r;
      u16x8 v = {0, 0, 0, 0, 0, 0, 0, 0};
      if (gr < NN) v = *(const u16x8*)(hb + (size_t)gr * 128 + k0 + kc);
      *(u16x8*)&lA[r * LSTR + kc] = v;
    }
#pragma unroll
    for (int c = tid; c < 1024; c += 256) {
      int r = c >> 2, kc = (c & 3) << 3;
      *(u16x8*)&lB[r * LSTR + kc] = *(const u16x8*)(wnode + (size_t)r * 128 + k0 + kc);
    }
    __syncthreads();
    bf16x8 af[4], bfr[8];
#pragma unroll
    for (int i = 0; i < 4; i++) af[i] = *(const bf16x8*)&lA[(wm + i * 16 + lr) * LSTR + q * 8];
#pragma unroll
    for (int i = 0; i < 8; i++) {
      int nrow = (i < 4) ? (wg + i * 16 + lr) : (128 + wg + (i - 4) * 16 + lr);
      bfr[i] = *(const bf16x8*)&lB[nrow * LSTR + q * 8];
    }
#pragma unroll
    for (int mi = 0; mi < 4; mi++)
#pragma unroll
      for (int ni = 0; ni < 8; ni++)
        acc[mi][ni] = __builtin_amdgcn_mfma_f32_16x16x32_bf16(af[mi], bfr[ni], acc[mi][ni], 0, 0, 0);
    __syncthreads();
  }

  // gate + run-length pooled accumulation (batch sorted)
  float* gb = g + (size_t)br * NG * 128;
  float racc[4] = {0.f, 0.f, 0.f, 0.f};
  int cur = -1;
#pragma unroll
  for (int mi = 0; mi < 4; mi++)
#pragma unroll
    for (int rg = 0; rg < 4; rg++) {
      int lrow = wm + mi * 16 + q * 4 + rg;
      int bt = sbat[lrow];
      if (bt != cur) {
        if (cur >= 0) {
#pragma unroll
          for (int ni = 0; ni < 4; ni++)
            atomicAdd(gb + (size_t)cur * 128 + wg + ni * 16 + lr, racc[ni]);
        }
        cur = bt;
#pragma unroll
        for (int ni = 0; ni < 4; ni++) racc[ni] = 0.f;
      }
      if (bt >= 0) {
#pragma unroll
        for (int ni = 0; ni < 4; ni++) {
          int gcol = wg + ni * 16 + lr;
          float gt = acc[mi][ni][rg] + nb[gcol];
          float vl = acc[mi][ni + 4][rg] + nb[128 + gcol];
          racc[ni] += vl / (1.f + __expf(-gt));
        }
      }
    }
  if (cur >= 0) {
#pragma unroll
    for (int ni = 0; ni < 4; ni++)
      atomicAdd(gb + (size_t)cur * 128 + wg + ni * 16 + lr, racc[ni]);
  }
}

// ---------------- final graph GEMM ----------------
__global__ __launch_bounds__(128) void k_final(const float* g, const float* W,
                                               const float* b, float* out) {
  int br = blockIdx.z, gi = blockIdx.x, j = threadIdx.x;
  __shared__ float sg[128];
  sg[j] = g[(size_t)br * NG * 128 + (size_t)gi * 128 + j];
  __syncthreads();
  float acc = b[j];
#pragma unroll
  for (int k = 0; k < 128; k++) acc += sg[k] * W[k * 128 + j];
  out[(size_t)br * NG * 128 + (size_t)gi * 128 + j] = acc;
}

extern "C" void kernel_launch(void* const* d_in, const int* in_sizes, int n_in,
                              void* d_out, int out_size, void* d_ws, size_t ws_size,
                              hipStream_t stream) {
  const float* x1     = (const float*)d_in[0];
  const int*   ei1    = (const int*)d_in[1];
  const int*   bat1   = (const int*)d_in[2];
  const float* x2     = (const float*)d_in[3];
  const int*   ei2    = (const int*)d_in[4];
  const int*   bat2   = (const int*)d_in[5];
  const float* W_emb  = (const float*)d_in[6];
  const float* b_emb  = (const float*)d_in[7];
  const float* msg_W1 = (const float*)d_in[8];
  const float* msg_b1 = (const float*)d_in[9];
  const float* msg_W2 = (const float*)d_in[10];
  const float* msg_b2 = (const float*)d_in[11];
  const float* upd_W1 = (const float*)d_in[12];
  const float* upd_b1 = (const float*)d_in[13];
  const float* upd_W2 = (const float*)d_in[14];
  const float* upd_b2 = (const float*)d_in[15];
  const float* node_W = (const float*)d_in[16];
  const float* node_b = (const float*)d_in[17];
  const float* graph_W = (const float*)d_in[18];
  const float* graph_b = (const float*)d_in[19];
  float* out = (float*)d_out;

  char* ws = (char*)d_ws;
  u16* wt_pq   = (u16*)(ws + WT_PQ);
  u16* wt_m2r  = (u16*)(ws + WT_M2R);
  u16* wt_upd1 = (u16*)(ws + WT_UPD1);
  u16* wt_u1c  = (u16*)(ws + WT_U1C);
  u16* wt_upd2 = (u16*)(ws + WT_UPD2);
  u16* wt_node = (u16*)(ws + WT_NODE);
  float* c2    = (float*)(ws + OFF_C2);
  int* deg    = (int*)(ws + OFF_DEG);
  int* starts = (int*)(ws + OFF_ST);
  int* cursor = (int*)(ws + OFF_CUR);
  int* srcs   = (int*)(ws + OFF_SRC);
  float* h  = (float*)(ws + OFF_H);
  u16*   hb = (u16*)(ws + OFF_HB);
  u16*   PQ = (u16*)(ws + OFF_PQ);
  u16*   ui = (u16*)(ws + OFF_UI);
  float* g  = (float*)(ws + OFF_G);

  // ---- prep (weights + c2 + zero deg/g) ----
  k_prep<<<768, 256, 0, stream>>>(msg_W1, msg_W2, upd_W1, upd_W2, node_W, msg_b2,
                                  wt_pq, wt_m2r, wt_upd1, wt_u1c, wt_upd2, wt_node,
                                  c2, deg, g);
  // Wc = W2 @ W1u_top -> wt_u1c[:, :256] (z = layer)
  {
    GemmP pc{};
    pc.A = wt_upd1; pc.sA = 98304; pc.lda = 384;
    pc.Wt = wt_m2r; pc.sW = 65536;
    pc.outb = wt_u1c; pc.s_outb = 98304;
    pc.M = 256; pc.N = 256; pc.K = 256; pc.ldo = 384;
    k_gemm<<<dim3(2, 2, 2), 256, 0, stream>>>(pc);
  }
  k_deg<<<dim3(625, 1, 2), 256, 0, stream>>>(ei1, ei2, deg);
  k_scan<<<dim3(1, 1, 2), 256, 0, stream>>>(deg, starts, cursor);
  k_scatter<<<dim3(625, 1, 2), 256, 0, stream>>>(ei1, ei2, cursor, srcs);
  k_embed<<<dim3(313, 1, 2), 256, 0, stream>>>(x1, x2, W_emb, b_emb, h, hb, ui);

  for (int l = 0; l < 2; l++) {
    // PQ = h @ [W1_top | W1_bot]  -> [NN, 512] bf16
    GemmP pq{};
    pq.A = hb; pq.sA = (size_t)NN * 128; pq.lda = 128;
    pq.Wt = wt_pq + (size_t)l * 65536; pq.sW = 0;
    pq.outb = PQ; pq.s_outb = (size_t)NN * 512;
    pq.M = NN; pq.N = 512; pq.K = 128; pq.ldo = 512;
    k_gemm<<<dim3(79, 4, 2), 256, 0, stream>>>(pq);

    // ui[:, :256] = S[n] = sum_{e: tgt=n} relu(P[src_e] + Q[n] + b1)
    k_edge<<<dim3(2500, 1, 2), 256, 0, stream>>>(PQ, starts, srcs, msg_b1 + l * 256, ui);

    // fused: U1 = relu([S|h]@W1c + b1u + deg*c2);  h += U1@W2 + b2
    k_upd<<<dim3(79, 1, 2), 256, 0, stream>>>(
        ui, wt_u1c + (size_t)l * 98304, upd_b1 + l * 256, c2 + l * 256,
        deg, wt_upd2 + (size_t)l * 32768, upd_b2 + l * 128, h, hb);
  }

  // fused readout: gate(h@nodeW+b) pooled into g
  k_nxg<<<dim3(79, 1, 2), 256, 0, stream>>>(hb, wt_node, node_b, bat1, bat2, g);
  k_final<<<dim3(NG, 1, 2), 128, 0, stream>>>(g, graph_W, graph_b, out);
}

// Round 5
// 372.075 us; speedup vs baseline: 4.1746x; 1.0331x over previous
//
#include <hip/hip_runtime.h>

typedef unsigned short u16;
typedef __bf16 bf16x8 __attribute__((ext_vector_type(8)));
typedef float f32x4 __attribute__((ext_vector_type(4)));
typedef unsigned short u16x8 __attribute__((ext_vector_type(8)));

constexpr int NN  = 10000;   // nodes
constexpr int NE  = 160000;  // edges
constexpr int NG  = 32;      // graphs
constexpr int HD  = 128;     // hidden

// ---- workspace layout (bytes) ----
constexpr size_t WT_PQ   = 0;                  // [2][512][128] bf16 (msgW1 split/transposed)
constexpr size_t WT_M2R  = 262144;             // [2][256][256] bf16 (msgW2 row-major cast)
constexpr size_t WT_UPD1 = 524288;             // [2][256][384] bf16 (updW1 transposed)
constexpr size_t WT_U1C  = 917504;             // [2][256][384] bf16 (combined UPD1' weight)
constexpr size_t WT_UPD2 = 1310720;            // [2][128][256]
constexpr size_t WT_NODE = 1441792;            // [256][128]
constexpr size_t OFF_C2  = 1507328;            // f32 [2][256]
constexpr size_t OFF_DEG = 1509376;            // int [2][NN]
constexpr size_t OFF_ST  = 1589376;            // int [2][NN+8]
constexpr size_t OFF_CUR = 1669440;            // int [2][NN]
constexpr size_t OFF_SRC = 1749440;            // int [2][NE]
constexpr size_t OFF_H   = 3029440;            // f32 [2][NN][128]
constexpr size_t OFF_HB  = 13269440;           // bf16 [2][NN][128]
constexpr size_t OFF_PQ  = 18389440;           // bf16 [2][NN][512]
constexpr size_t OFF_UI  = 38869440;           // bf16 [2][NN][384]
constexpr size_t OFF_G   = 54229440;           // f32 [2][NG][128]

__device__ inline u16 f2b(float f) {
  unsigned int u = __float_as_uint(f);
  unsigned int r = u + 0x7fffu + ((u >> 16) & 1u);
  return (u16)(r >> 16);
}
__device__ inline float b2f(u16 u) { return __uint_as_float(((unsigned int)u) << 16); }

// ---------------- weight prep (+ c2, + zero deg/g) ----------------
__global__ __launch_bounds__(256) void k_prep(
    const float* msgW1, const float* msgW2, const float* updW1,
    const float* updW2, const float* nodeW, const float* msgb2,
    u16* tpq, u16* t2r, u16* t3, u16* tu1c, u16* t4, u16* t5,
    float* c2, int* deg, float* g) {
  int idx = blockIdx.x * 256 + threadIdx.x;
  if (idx < 131072) {
    // wt_pq: [l][n=512][k=128]; n<256 -> W1[k][n] (src half), n>=256 -> W1[128+k][n-256]
    int l = idx >> 16, r = idx & 65535, n = r >> 7, k = r & 127;
    int row = (n < 256) ? k : (128 + k);
    tpq[idx] = f2b(msgW1[l * 65536 + row * 256 + (n & 255)]);
    // wt_m2r: straight cast of msgW2 [l][k=256][n=256]
    t2r[idx] = f2b(msgW2[idx]);
  }
  if (idx < 196608) {  // updW1: [l][k=384][n=256] -> [l][n=256][k=384]
    int l = idx / 98304, r = idx % 98304, n = r / 384, k = r % 384;
    t3[idx] = f2b(updW1[l * 98304 + k * 256 + n]);
  }
  if (idx < 65536) {   // u1c h-part: [l][n=256][256+k], k<128 <- updW1[l][256+k][n]
    int l = idx >> 15, r = idx & 32767, n = r >> 7, k = r & 127;
    tu1c[l * 98304 + n * 384 + 256 + k] = f2b(updW1[l * 98304 + (256 + k) * 256 + n]);
    // updW2: [l][k=256][n=128] -> [l][n=128][k=256]
    int n2 = (idx & 32767) >> 8, k2 = idx & 255;
    t4[idx] = f2b(updW2[(idx >> 15) * 32768 + (k2 << 7) + n2]);
  }
  if (idx < 32768) {   // nodeW: [k=128][n=256] -> [n=256][k=128]
    int n = idx >> 7, k = idx & 127;
    t5[idx] = f2b(nodeW[(k << 8) + n]);
  }
  if (idx < 512) {     // c2[l][n] = sum_c msg_b2[l][c] * updW1[l][c][n]
    int l = idx >> 8, n = idx & 255;
    const float* b2 = msgb2 + l * 256;
    const float* U1 = updW1 + l * 98304 + n;
    float a = 0.f;
    for (int c = 0; c < 256; c++) a += b2[c] * U1[c * 256];
    c2[idx] = a;
  }
  if (idx < 2 * NN) deg[idx] = 0;
  if (idx < 2 * NG * 128) g[idx] = 0.f;
}

// ---------------- counting sort of edges by tgt ----------------
__global__ __launch_bounds__(256) void k_deg(const int* ei0, const int* ei1, int* deg) {
  int br = blockIdx.z;
  int e = blockIdx.x * 256 + threadIdx.x;
  if (e >= NE) return;
  const int* tgt = br ? ei1 : ei0;
  atomicAdd(deg + br * NN + tgt[e], 1);
}

__global__ __launch_bounds__(256) void k_scan(const int* deg, int* starts, int* cursor) {
  int br = blockIdx.z;
  const int* d = deg + br * NN;
  int* st = starts + br * (NN + 8);
  int* cu = cursor + br * NN;
  __shared__ int part[257];
  int t = threadIdx.x;
  int c0 = t * 40;
  int s = 0;
  for (int i = 0; i < 40; i++) if (c0 + i < NN) s += d[c0 + i];
  part[t] = s;
  __syncthreads();
  if (t == 0) {
    int run = 0;
    for (int i = 0; i < 256; i++) { int v = part[i]; part[i] = run; run += v; }
    part[256] = run;
  }
  __syncthreads();
  int run = part[t];
  for (int i = 0; i < 40; i++) {
    int n = c0 + i;
    if (n < NN) { st[n] = run; cu[n] = run; run += d[n]; }
  }
  if (t == 255) st[NN] = part[256];
}

__global__ __launch_bounds__(256) void k_scatter(const int* ei0, const int* ei1,
                                                 int* cursor, int* srcs) {
  int br = blockIdx.z;
  int e = blockIdx.x * 256 + threadIdx.x;
  if (e >= NE) return;
  const int* ei = br ? ei1 : ei0;
  int t = ei[e], s = ei[NE + e];
  int pos = atomicAdd(cursor + br * NN + t, 1);
  srcs[br * NE + pos] = s;
}

// ---------------- embedding: h = x @ W_emb + b_emb (also seeds ui h-half) ---------
__global__ __launch_bounds__(256) void k_embed(
    const float* x1, const float* x2, const float* W, const float* b,
    float* h, u16* h_bf, u16* ui) {
  int br = blockIdx.z;
  const float* x = br ? x2 : x1;
  float* hB = h + (size_t)br * NN * HD;
  u16* hbB = h_bf + (size_t)br * NN * HD;
  u16* uiB = ui + (size_t)br * NN * 384;
  __shared__ float sW[64 * 128];
  __shared__ float sx[32 * 64];
  int tid = threadIdx.x;
  for (int i = tid; i < 64 * 128; i += 256) sW[i] = W[i];
  int r0 = blockIdx.x * 32;
  for (int i = tid; i < 32 * 64; i += 256) {
    int r = i >> 6, k = i & 63;
    sx[i] = (r0 + r < NN) ? x[(size_t)(r0 + r) * 64 + k] : 0.f;
  }
  __syncthreads();
  int c = tid & 127;
  int rbase = (tid >> 7) * 16;
  for (int r = rbase; r < rbase + 16; r++) {
    float acc = b[c];
#pragma unroll
    for (int k = 0; k < 64; k++) acc += sx[r * 64 + k] * sW[k * 128 + c];
    int gr = r0 + r;
    if (gr < NN) {
      u16 bv = f2b(acc);
      hB[(size_t)gr * HD + c] = acc;
      hbB[(size_t)gr * HD + c] = bv;
      uiB[(size_t)gr * 384 + 256 + c] = bv;
    }
  }
}

// ---------------- edge phase: ui[n][:256] = sum_e relu(P[src_e] + Q[n] + b1) ------
// Half-wave per edge: 32 lanes x u16x8 = one 512B P row per issue.
__global__ __launch_bounds__(256) void k_edge(const u16* PQ, const int* starts,
                                              const int* srcs, const float* b1, u16* ui) {
  int br = blockIdx.z;
  int node = blockIdx.x * 4 + (threadIdx.x >> 6);
  int lane = threadIdx.x & 63;
  int half = lane >> 5;
  int c0 = (lane & 31) * 8;
  const u16* PQb = PQ + (size_t)br * NN * 512;
  const int* st = starts + br * (NN + 8);
  const int* sr = srcs + br * NE;
  u16x8 qr = *(const u16x8*)(PQb + (size_t)node * 512 + 256 + c0);
  float qv[8], acc[8];
#pragma unroll
  for (int j = 0; j < 8; j++) { qv[j] = b2f(qr[j]) + b1[c0 + j]; acc[j] = 0.f; }
  int e0 = st[node], e1 = st[node + 1];
  int e = e0 + half;
  for (; e + 2 < e1; e += 4) {
    int s0 = sr[e], s1 = sr[e + 2];
    u16x8 p0 = *(const u16x8*)(PQb + (size_t)s0 * 512 + c0);
    u16x8 p1 = *(const u16x8*)(PQb + (size_t)s1 * 512 + c0);
#pragma unroll
    for (int j = 0; j < 8; j++) {
      float v0 = b2f(p0[j]) + qv[j];
      float v1 = b2f(p1[j]) + qv[j];
      acc[j] += (v0 > 0.f ? v0 : 0.f) + (v1 > 0.f ? v1 : 0.f);
    }
  }
  for (; e < e1; e += 2) {
    int s0 = sr[e];
    u16x8 p0 = *(const u16x8*)(PQb + (size_t)s0 * 512 + c0);
#pragma unroll
    for (int j = 0; j < 8; j++) {
      float v0 = b2f(p0[j]) + qv[j];
      acc[j] += (v0 > 0.f ? v0 : 0.f);
    }
  }
#pragma unroll
  for (int j = 0; j < 8; j++) acc[j] += __shfl_xor(acc[j], 32);
  if (half == 0) {
    u16x8 o;
#pragma unroll
    for (int j = 0; j < 8; j++) o[j] = f2b(acc[j]);
    *(u16x8*)(ui + (size_t)br * NN * 384 + (size_t)node * 384 + c0) = o;
  }
}

// ---------------- plain MFMA GEMM (bf16 store, no bias): PQ + Wc prep ----------
struct GemmP {
  const u16* A;   size_t sA;     // per-z stride (elements)
  int lda;
  const u16* Wt;  size_t sW;     // [N][K] bf16, per-z stride
  u16* outb;  size_t s_outb;
  int M, N, K, ldo;
};

#define LSTR 40

__global__ __launch_bounds__(256) void k_gemm(GemmP p) {
  const int br = blockIdx.z;
  const int tid = threadIdx.x;
  const int lane = tid & 63, wave = tid >> 6;
  const int wm = (wave & 1) * 64, wn = (wave >> 1) * 64;
  const int q = lane >> 4, lr = lane & 15;
  const int m0 = blockIdx.x * 128, n0 = blockIdx.y * 128;
  __shared__ alignas(16) u16 lA[128 * LSTR];
  __shared__ alignas(16) u16 lB[128 * LSTR];

  f32x4 acc[4][4];
#pragma unroll
  for (int i = 0; i < 4; i++)
#pragma unroll
    for (int j = 0; j < 4; j++) acc[i][j] = (f32x4){0.f, 0.f, 0.f, 0.f};

  const u16* Abr = p.A + (size_t)br * p.sA;
  const u16* Wbr = p.Wt + (size_t)br * p.sW;

  for (int k0 = 0; k0 < p.K; k0 += 32) {
#pragma unroll
    for (int c = tid; c < 512; c += 256) {
      int r = c >> 2, kc = (c & 3) << 3;
      int gr = m0 + r;
      u16x8 v = {0, 0, 0, 0, 0, 0, 0, 0};
      if (gr < p.M) v = *(const u16x8*)(Abr + (size_t)gr * p.lda + k0 + kc);
      *(u16x8*)&lA[r * LSTR + kc] = v;
    }
#pragma unroll
    for (int c = tid; c < 512; c += 256) {
      int r = c >> 2, kc = (c & 3) << 3;
      *(u16x8*)&lB[r * LSTR + kc] = *(const u16x8*)(Wbr + (size_t)(n0 + r) * p.K + k0 + kc);
    }
    __syncthreads();
    bf16x8 af[4], bfr[4];
#pragma unroll
    for (int i = 0; i < 4; i++) af[i] = *(const bf16x8*)&lA[(wm + i * 16 + lr) * LSTR + q * 8];
#pragma unroll
    for (int i = 0; i < 4; i++) bfr[i] = *(const bf16x8*)&lB[(wn + i * 16 + lr) * LSTR + q * 8];
#pragma unroll
    for (int mi = 0; mi < 4; mi++)
#pragma unroll
      for (int ni = 0; ni < 4; ni++)
        acc[mi][ni] = __builtin_amdgcn_mfma_f32_16x16x32_bf16(af[mi], bfr[ni], acc[mi][ni], 0, 0, 0);
    __syncthreads();
  }

  u16* ob = p.outb + (size_t)br * p.s_outb;
#pragma unroll
  for (int mi = 0; mi < 4; mi++)
#pragma unroll
    for (int rg = 0; rg < 4; rg++) {
      int row = m0 + wm + mi * 16 + q * 4 + rg;
      if (row >= p.M) continue;
#pragma unroll
      for (int ni = 0; ni < 4; ni++) {
        int col = n0 + wn + ni * 16 + lr;
        ob[(size_t)row * p.ldo + col] = f2b(acc[mi][ni][rg]);
      }
    }
}

// ---------------- fused update MLP, M-tile 32, grid 313x2 -------------------------
// Phase1: 32x256 U1 strip (4 waves x 32x64), relu -> bf16 lU[32][272] (overlays staging).
// Phase2: 32x128 = lU @ W2^T (B-frags from L2-resident global), residual epilogue.
__global__ __launch_bounds__(256, 4) void k_upd(
    const u16* ui_all, const u16* w1c, const float* b1u, const float* c2l,
    const int* deg_all, const u16* w2, const float* b2u,
    float* h_all, u16* hb_all) {
  const int br = blockIdx.z;
  const int tid = threadIdx.x;
  const int lane = tid & 63, wave = tid >> 6;
  const int q = lane >> 4, lr = lane & 15;
  const int m0 = blockIdx.x * 32;

  __shared__ alignas(16) u16 sm[32 * LSTR + 256 * LSTR];  // 23040 B; lU overlays base
  u16* lA = sm;
  u16* lB = sm + 32 * LSTR;
  u16* lU = sm;  // 32*272 = 8704 u16, valid after phase1 final barrier

  const u16* ui = ui_all + (size_t)br * NN * 384;

  // ---- phase 1 ----
  const int wn = wave * 64;
  f32x4 acc[2][4];
#pragma unroll
  for (int i = 0; i < 2; i++)
#pragma unroll
    for (int j = 0; j < 4; j++) acc[i][j] = (f32x4){0.f, 0.f, 0.f, 0.f};

  for (int k0 = 0; k0 < 384; k0 += 32) {
    for (int c = tid; c < 1152; c += 256) {
      if (c < 128) {
        int r = c >> 2, kc = (c & 3) << 3;
        int gr = m0 + r;
        u16x8 v = {0, 0, 0, 0, 0, 0, 0, 0};
        if (gr < NN) v = *(const u16x8*)(ui + (size_t)gr * 384 + k0 + kc);
        *(u16x8*)&lA[r * LSTR + kc] = v;
      } else {
        int cc = c - 128;
        int r = cc >> 2, kc = (cc & 3) << 3;
        *(u16x8*)&lB[r * LSTR + kc] = *(const u16x8*)(w1c + (size_t)r * 384 + k0 + kc);
      }
    }
    __syncthreads();
    bf16x8 af[2], bfr[4];
#pragma unroll
    for (int i = 0; i < 2; i++) af[i] = *(const bf16x8*)&lA[(i * 16 + lr) * LSTR + q * 8];
#pragma unroll
    for (int i = 0; i < 4; i++) bfr[i] = *(const bf16x8*)&lB[(wn + i * 16 + lr) * LSTR + q * 8];
#pragma unroll
    for (int mi = 0; mi < 2; mi++)
#pragma unroll
      for (int ni = 0; ni < 4; ni++)
        acc[mi][ni] = __builtin_amdgcn_mfma_f32_16x16x32_bf16(af[mi], bfr[ni], acc[mi][ni], 0, 0, 0);
    __syncthreads();
  }

  // relu + bias + deg*c2 -> bf16 into lU[32][272]
  const int* deg = deg_all + br * NN;
#pragma unroll
  for (int mi = 0; mi < 2; mi++)
#pragma unroll
    for (int rg = 0; rg < 4; rg++) {
      int row = mi * 16 + q * 4 + rg;
      int gr = m0 + row;
      float d = (gr < NN) ? (float)deg[gr] : 0.f;
#pragma unroll
      for (int ni = 0; ni < 4; ni++) {
        int col = wn + ni * 16 + lr;
        float v = acc[mi][ni][rg] + b1u[col] + d * c2l[col];
        if (v < 0.f) v = 0.f;
        lU[row * 272 + col] = f2b(v);
      }
    }
  __syncthreads();

  // ---- phase 2 ----
  const int wn2 = wave * 32;
  f32x4 acc2[2][2];
#pragma unroll
  for (int i = 0; i < 2; i++)
#pragma unroll
    for (int j = 0; j < 2; j++) acc2[i][j] = (f32x4){0.f, 0.f, 0.f, 0.f};

  for (int k0 = 0; k0 < 256; k0 += 32) {
    bf16x8 af[2], bfr[2];
#pragma unroll
    for (int i = 0; i < 2; i++)
      af[i] = *(const bf16x8*)&lU[(i * 16 + lr) * 272 + k0 + q * 8];
#pragma unroll
    for (int i = 0; i < 2; i++)
      bfr[i] = *(const bf16x8*)(w2 + (size_t)(wn2 + i * 16 + lr) * 256 + k0 + q * 8);
#pragma unroll
    for (int mi = 0; mi < 2; mi++)
#pragma unroll
      for (int ni = 0; ni < 2; ni++)
        acc2[mi][ni] = __builtin_amdgcn_mfma_f32_16x16x32_bf16(af[mi], bfr[ni], acc2[mi][ni], 0, 0, 0);
  }

  // residual epilogue
  float* h = h_all + (size_t)br * NN * 128;
  u16* hb = hb_all + (size_t)br * NN * 128;
  u16* uiw = (u16*)ui_all + (size_t)br * NN * 384;
#pragma unroll
  for (int mi = 0; mi < 2; mi++)
#pragma unroll
    for (int rg = 0; rg < 4; rg++) {
      int row = m0 + mi * 16 + q * 4 + rg;
      if (row >= NN) continue;
#pragma unroll
      for (int ni = 0; ni < 2; ni++) {
        int col = wn2 + ni * 16 + lr;
        size_t o = (size_t)row * 128 + col;
        float nh = h[o] + acc2[mi][ni][rg] + b2u[col];
        u16 bv = f2b(nh);
        h[o] = nh;
        hb[o] = bv;
        uiw[(size_t)row * 384 + 256 + col] = bv;
      }
    }
}

// ---------------- fused readout, M-tile 64, grid 157x2 ----------------------------
// Wave computes 64 rows x (32 gate + 32 paired val cols); run-length pooled atomics.
__global__ __launch_bounds__(256, 4) void k_nxg(
    const u16* hb_all, const u16* wnode, const float* nb,
    const int* b0v, const int* b1v, float* g) {
  const int br = blockIdx.z;
  const int tid = threadIdx.x;
  const int lane = tid & 63, wave = tid >> 6;
  const int q = lane >> 4, lr = lane & 15;
  const int m0 = blockIdx.x * 64;
  const int wg = wave * 32;

  __shared__ alignas(16) u16 lA[64 * LSTR];
  __shared__ alignas(16) u16 lB[256 * LSTR];
  __shared__ int sbat[64];

  const u16* hb = hb_all + (size_t)br * NN * 128;
  const int* batch = br ? b1v : b0v;
  if (tid < 64) {
    int n = m0 + tid;
    sbat[tid] = (n < NN) ? batch[n] : -1;
  }

  f32x4 acc[4][4];  // ni 0-1 gate, 2-3 val
#pragma unroll
  for (int i = 0; i < 4; i++)
#pragma unroll
    for (int j = 0; j < 4; j++) acc[i][j] = (f32x4){0.f, 0.f, 0.f, 0.f};

  for (int k0 = 0; k0 < 128; k0 += 32) {
    for (int c = tid; c < 1280; c += 256) {
      if (c < 256) {
        int r = c >> 2, kc = (c & 3) << 3;
        int gr = m0 + r;
        u16x8 v = {0, 0, 0, 0, 0, 0, 0, 0};
        if (gr < NN) v = *(const u16x8*)(hb + (size_t)gr * 128 + k0 + kc);
        *(u16x8*)&lA[r * LSTR + kc] = v;
      } else {
        int cc = c - 256;
        int r = cc >> 2, kc = (cc & 3) << 3;
        *(u16x8*)&lB[r * LSTR + kc] = *(const u16x8*)(wnode + (size_t)r * 128 + k0 + kc);
      }
    }
    __syncthreads();
    bf16x8 af[4], bfr[4];
#pragma unroll
    for (int i = 0; i < 4; i++) af[i] = *(const bf16x8*)&lA[(i * 16 + lr) * LSTR + q * 8];
#pragma unroll
    for (int i = 0; i < 4; i++) {
      int nrow = (i < 2) ? (wg + i * 16 + lr) : (128 + wg + (i - 2) * 16 + lr);
      bfr[i] = *(const bf16x8*)&lB[nrow * LSTR + q * 8];
    }
#pragma unroll
    for (int mi = 0; mi < 4; mi++)
#pragma unroll
      for (int ni = 0; ni < 4; ni++)
        acc[mi][ni] = __builtin_amdgcn_mfma_f32_16x16x32_bf16(af[mi], bfr[ni], acc[mi][ni], 0, 0, 0);
    __syncthreads();
  }

  // gate + run-length pooled accumulation (batch sorted; rows ascend per lane)
  float* gb = g + (size_t)br * NG * 128;
  float racc[2] = {0.f, 0.f};
  int cur = -1;
#pragma unroll
  for (int mi = 0; mi < 4; mi++)
#pragma unroll
    for (int rg = 0; rg < 4; rg++) {
      int lrow = mi * 16 + q * 4 + rg;
      int bt = sbat[lrow];
      if (bt != cur) {
        if (cur >= 0) {
#pragma unroll
          for (int ni = 0; ni < 2; ni++)
            atomicAdd(gb + (size_t)cur * 128 + wg + ni * 16 + lr, racc[ni]);
        }
        cur = bt;
        racc[0] = 0.f; racc[1] = 0.f;
      }
      if (bt >= 0) {
#pragma unroll
        for (int ni = 0; ni < 2; ni++) {
          int gcol = wg + ni * 16 + lr;
          float gt = acc[mi][ni][rg] + nb[gcol];
          float vl = acc[mi][ni + 2][rg] + nb[128 + gcol];
          racc[ni] += vl / (1.f + __expf(-gt));
        }
      }
    }
  if (cur >= 0) {
#pragma unroll
    for (int ni = 0; ni < 2; ni++)
      atomicAdd(gb + (size_t)cur * 128 + wg + ni * 16 + lr, racc[ni]);
  }
}

// ---------------- final graph GEMM ----------------
__global__ __launch_bounds__(128) void k_final(const float* g, const float* W,
                                               const float* b, float* out) {
  int br = blockIdx.z, gi = blockIdx.x, j = threadIdx.x;
  __shared__ float sg[128];
  sg[j] = g[(size_t)br * NG * 128 + (size_t)gi * 128 + j];
  __syncthreads();
  float acc = b[j];
#pragma unroll
  for (int k = 0; k < 128; k++) acc += sg[k] * W[k * 128 + j];
  out[(size_t)br * NG * 128 + (size_t)gi * 128 + j] = acc;
}

extern "C" void kernel_launch(void* const* d_in, const int* in_sizes, int n_in,
                              void* d_out, int out_size, void* d_ws, size_t ws_size,
                              hipStream_t stream) {
  const float* x1     = (const float*)d_in[0];
  const int*   ei1    = (const int*)d_in[1];
  const int*   bat1   = (const int*)d_in[2];
  const float* x2     = (const float*)d_in[3];
  const int*   ei2    = (const int*)d_in[4];
  const int*   bat2   = (const int*)d_in[5];
  const float* W_emb  = (const float*)d_in[6];
  const float* b_emb  = (const float*)d_in[7];
  const float* msg_W1 = (const float*)d_in[8];
  const float* msg_b1 = (const float*)d_in[9];
  const float* msg_W2 = (const float*)d_in[10];
  const float* msg_b2 = (const float*)d_in[11];
  const float* upd_W1 = (const float*)d_in[12];
  const float* upd_b1 = (const float*)d_in[13];
  const float* upd_W2 = (const float*)d_in[14];
  const float* upd_b2 = (const float*)d_in[15];
  const float* node_W = (const float*)d_in[16];
  const float* node_b = (const float*)d_in[17];
  const float* graph_W = (const float*)d_in[18];
  const float* graph_b = (const float*)d_in[19];
  float* out = (float*)d_out;

  char* ws = (char*)d_ws;
  u16* wt_pq   = (u16*)(ws + WT_PQ);
  u16* wt_m2r  = (u16*)(ws + WT_M2R);
  u16* wt_upd1 = (u16*)(ws + WT_UPD1);
  u16* wt_u1c  = (u16*)(ws + WT_U1C);
  u16* wt_upd2 = (u16*)(ws + WT_UPD2);
  u16* wt_node = (u16*)(ws + WT_NODE);
  float* c2    = (float*)(ws + OFF_C2);
  int* deg    = (int*)(ws + OFF_DEG);
  int* starts = (int*)(ws + OFF_ST);
  int* cursor = (int*)(ws + OFF_CUR);
  int* srcs   = (int*)(ws + OFF_SRC);
  float* h  = (float*)(ws + OFF_H);
  u16*   hb = (u16*)(ws + OFF_HB);
  u16*   PQ = (u16*)(ws + OFF_PQ);
  u16*   ui = (u16*)(ws + OFF_UI);
  float* g  = (float*)(ws + OFF_G);

  // ---- prep (weights + c2 + zero deg/g) ----
  k_prep<<<768, 256, 0, stream>>>(msg_W1, msg_W2, upd_W1, upd_W2, node_W, msg_b2,
                                  wt_pq, wt_m2r, wt_upd1, wt_u1c, wt_upd2, wt_node,
                                  c2, deg, g);
  // Wc = W2 @ W1u_top -> wt_u1c[:, :256] (z = layer)
  {
    GemmP pc{};
    pc.A = wt_upd1; pc.sA = 98304; pc.lda = 384;
    pc.Wt = wt_m2r; pc.sW = 65536;
    pc.outb = wt_u1c; pc.s_outb = 98304;
    pc.M = 256; pc.N = 256; pc.K = 256; pc.ldo = 384;
    k_gemm<<<dim3(2, 2, 2), 256, 0, stream>>>(pc);
  }
  k_deg<<<dim3(625, 1, 2), 256, 0, stream>>>(ei1, ei2, deg);
  k_scan<<<dim3(1, 1, 2), 256, 0, stream>>>(deg, starts, cursor);
  k_scatter<<<dim3(625, 1, 2), 256, 0, stream>>>(ei1, ei2, cursor, srcs);
  k_embed<<<dim3(313, 1, 2), 256, 0, stream>>>(x1, x2, W_emb, b_emb, h, hb, ui);

  for (int l = 0; l < 2; l++) {
    // PQ = h @ [W1_top | W1_bot]  -> [NN, 512] bf16
    GemmP pq{};
    pq.A = hb; pq.sA = (size_t)NN * 128; pq.lda = 128;
    pq.Wt = wt_pq + (size_t)l * 65536; pq.sW = 0;
    pq.outb = PQ; pq.s_outb = (size_t)NN * 512;
    pq.M = NN; pq.N = 512; pq.K = 128; pq.ldo = 512;
    k_gemm<<<dim3(79, 4, 2), 256, 0, stream>>>(pq);

    // ui[:, :256] = S[n] = sum_{e: tgt=n} relu(P[src_e] + Q[n] + b1)
    k_edge<<<dim3(2500, 1, 2), 256, 0, stream>>>(PQ, starts, srcs, msg_b1 + l * 256, ui);

    // fused: U1 = relu([S|h]@W1c + b1u + deg*c2);  h += U1@W2 + b2
    k_upd<<<dim3(313, 1, 2), 256, 0, stream>>>(
        ui, wt_u1c + (size_t)l * 98304, upd_b1 + l * 256, c2 + l * 256,
        deg, wt_upd2 + (size_t)l * 32768, upd_b2 + l * 128, h, hb);
  }

  // fused readout: gate(h@nodeW+b) pooled into g
  k_nxg<<<dim3(157, 1, 2), 256, 0, stream>>>(hb, wt_node, node_b, bat1, bat2, g);
  k_final<<<dim3(NG, 1, 2), 128, 0, stream>>>(g, graph_W, graph_b, out);
}

// Round 6
// 362.789 us; speedup vs baseline: 4.2814x; 1.0256x over previous
//
#include <hip/hip_runtime.h>

typedef unsigned short u16;
typedef __bf16 bf16x8 __attribute__((ext_vector_type(8)));
typedef float f32x4 __attribute__((ext_vector_type(4)));
typedef unsigned short u16x8 __attribute__((ext_vector_type(8)));

constexpr int NN  = 10000;   // nodes
constexpr int NE  = 160000;  // edges
constexpr int NG  = 32;      // graphs
constexpr int HD  = 128;     // hidden

// ---- workspace layout (bytes) ----
constexpr size_t WT_PQ   = 0;                  // [2][512][128] bf16 (msgW1 split/transposed)
constexpr size_t WT_M2R  = 262144;             // [2][256][256] bf16 (msgW2 row-major cast)
constexpr size_t WT_UPD1 = 524288;             // [2][256][384] bf16 (updW1 transposed)
constexpr size_t WT_U1C  = 917504;             // [2][256][384] bf16 (combined UPD1' weight)
constexpr size_t WT_UPD2 = 1310720;            // [2][128][256]
constexpr size_t WT_NODE = 1441792;            // [256][128]
constexpr size_t OFF_C2  = 1507328;            // f32 [2][256]
constexpr size_t OFF_DEG = 1509376;            // int [2][NN]
constexpr size_t OFF_ST  = 1589376;            // int [2][NN+8]
constexpr size_t OFF_CUR = 1669440;            // int [2][NN]
constexpr size_t OFF_SRC = 1749440;            // int [2][NE]
constexpr size_t OFF_H   = 3029440;            // f32 [2][NN][128]
constexpr size_t OFF_HB  = 13269440;           // bf16 [2][NN][128]
constexpr size_t OFF_PQ  = 18389440;           // bf16 [2][NN][512]
constexpr size_t OFF_UI  = 38869440;           // bf16 [2][NN][384]
constexpr size_t OFF_G   = 54229440;           // f32 [2][NG][128]

#define LSTR 40

__device__ inline u16 f2b(float f) {
  unsigned int u = __float_as_uint(f);
  unsigned int r = u + 0x7fffu + ((u >> 16) & 1u);
  return (u16)(r >> 16);
}
__device__ inline float b2f(u16 u) { return __uint_as_float(((unsigned int)u) << 16); }

// ---------------- weight prep (+ c2, + zero deg/g) ----------------
__global__ __launch_bounds__(256) void k_prep(
    const float* msgW1, const float* msgW2, const float* updW1,
    const float* updW2, const float* nodeW, const float* msgb2,
    u16* tpq, u16* t2r, u16* t3, u16* tu1c, u16* t4, u16* t5,
    float* c2, int* deg, float* g) {
  int idx = blockIdx.x * 256 + threadIdx.x;
  if (idx < 131072) {
    // wt_pq: [l][n=512][k=128]; n<256 -> W1[k][n] (src half), n>=256 -> W1[128+k][n-256]
    int l = idx >> 16, r = idx & 65535, n = r >> 7, k = r & 127;
    int row = (n < 256) ? k : (128 + k);
    tpq[idx] = f2b(msgW1[l * 65536 + row * 256 + (n & 255)]);
    t2r[idx] = f2b(msgW2[idx]);
  }
  if (idx < 196608) {  // updW1: [l][k=384][n=256] -> [l][n=256][k=384]
    int l = idx / 98304, r = idx % 98304, n = r / 384, k = r % 384;
    t3[idx] = f2b(updW1[l * 98304 + k * 256 + n]);
  }
  if (idx < 65536) {   // u1c h-part: [l][n=256][256+k], k<128 <- updW1[l][256+k][n]
    int l = idx >> 15, r = idx & 32767, n = r >> 7, k = r & 127;
    tu1c[l * 98304 + n * 384 + 256 + k] = f2b(updW1[l * 98304 + (256 + k) * 256 + n]);
    // updW2: [l][k=256][n=128] -> [l][n=128][k=256]
    int n2 = (idx & 32767) >> 8, k2 = idx & 255;
    t4[idx] = f2b(updW2[(idx >> 15) * 32768 + (k2 << 7) + n2]);
  }
  if (idx < 32768) {   // nodeW: [k=128][n=256] -> [n=256][k=128]
    int n = idx >> 7, k = idx & 127;
    t5[idx] = f2b(nodeW[(k << 8) + n]);
  }
  if (idx < 512) {     // c2[l][n] = sum_c msg_b2[l][c] * updW1[l][c][n]
    int l = idx >> 8, n = idx & 255;
    const float* b2 = msgb2 + l * 256;
    const float* U1 = updW1 + l * 98304 + n;
    float a = 0.f;
    for (int c = 0; c < 256; c++) a += b2[c] * U1[c * 256];
    c2[idx] = a;
  }
  if (idx < 2 * NN) deg[idx] = 0;
  if (idx < 2 * NG * 128) g[idx] = 0.f;
}

// ---------------- counting sort of edges by tgt ----------------
__global__ __launch_bounds__(256) void k_deg(const int* ei0, const int* ei1, int* deg) {
  int br = blockIdx.z;
  int e = blockIdx.x * 256 + threadIdx.x;
  if (e >= NE) return;
  const int* tgt = br ? ei1 : ei0;
  atomicAdd(deg + br * NN + tgt[e], 1);
}

__global__ __launch_bounds__(256) void k_scan(const int* deg, int* starts, int* cursor) {
  int br = blockIdx.z;
  const int* d = deg + br * NN;
  int* st = starts + br * (NN + 8);
  int* cu = cursor + br * NN;
  __shared__ int part[257];
  int t = threadIdx.x;
  int c0 = t * 40;
  int s = 0;
  for (int i = 0; i < 40; i++) if (c0 + i < NN) s += d[c0 + i];
  part[t] = s;
  __syncthreads();
  if (t == 0) {
    int run = 0;
    for (int i = 0; i < 256; i++) { int v = part[i]; part[i] = run; run += v; }
    part[256] = run;
  }
  __syncthreads();
  int run = part[t];
  for (int i = 0; i < 40; i++) {
    int n = c0 + i;
    if (n < NN) { st[n] = run; cu[n] = run; run += d[n]; }
  }
  if (t == 255) st[NN] = part[256];
}

__global__ __launch_bounds__(256) void k_scatter(const int* ei0, const int* ei1,
                                                 int* cursor, int* srcs) {
  int br = blockIdx.z;
  int e = blockIdx.x * 256 + threadIdx.x;
  if (e >= NE) return;
  const int* ei = br ? ei1 : ei0;
  int t = ei[e], s = ei[NE + e];
  int pos = atomicAdd(cursor + br * NN + t, 1);
  srcs[br * NE + pos] = s;
}

// ---------------- shared phase: PQ strip from lhb (32x128 bf16, stride 136) -------
__device__ __forceinline__ void pq_from_lhb(
    const u16* lhb, const u16* wq, u16* PQ, int m0, int wave, int lane) {
  const int q = lane >> 4, lr = lane & 15;
  f32x4 a3[2][8];
#pragma unroll
  for (int i = 0; i < 2; i++)
#pragma unroll
    for (int j = 0; j < 8; j++) a3[i][j] = (f32x4){0.f, 0.f, 0.f, 0.f};
#pragma unroll
  for (int k0 = 0; k0 < 128; k0 += 32) {
    bf16x8 af[2], bfr[8];
#pragma unroll
    for (int i = 0; i < 2; i++)
      af[i] = *(const bf16x8*)&lhb[(i * 16 + lr) * 136 + k0 + q * 8];
#pragma unroll
    for (int i = 0; i < 8; i++)
      bfr[i] = *(const bf16x8*)(wq + (size_t)(wave * 128 + i * 16 + lr) * 128 + k0 + q * 8);
#pragma unroll
    for (int mi = 0; mi < 2; mi++)
#pragma unroll
      for (int ni = 0; ni < 8; ni++)
        a3[mi][ni] = __builtin_amdgcn_mfma_f32_16x16x32_bf16(af[mi], bfr[ni], a3[mi][ni], 0, 0, 0);
  }
#pragma unroll
  for (int mi = 0; mi < 2; mi++)
#pragma unroll
    for (int rg = 0; rg < 4; rg++) {
      int grow = m0 + mi * 16 + q * 4 + rg;
      if (grow >= NN) continue;
#pragma unroll
      for (int ni = 0; ni < 8; ni++) {
        int col = wave * 128 + ni * 16 + lr;
        PQ[(size_t)grow * 512 + col] = f2b(a3[mi][ni][rg]);
      }
    }
}

// ---------------- embedding: h = x @ W_emb + b_emb; + PQ(l=0) phase ---------------
__global__ __launch_bounds__(256) void k_embed(
    const float* x1, const float* x2, const float* W, const float* b,
    float* h, u16* h_bf, u16* ui, const u16* wpq0, u16* PQ_all) {
  int br = blockIdx.z;
  const float* x = br ? x2 : x1;
  float* hB = h + (size_t)br * NN * HD;
  u16* hbB = h_bf + (size_t)br * NN * HD;
  u16* uiB = ui + (size_t)br * NN * 384;
  __shared__ float sW[64 * 128];
  __shared__ float sx[32 * 64];
  __shared__ alignas(16) u16 lhb[32 * 136];
  int tid = threadIdx.x;
  for (int i = tid; i < 64 * 128; i += 256) sW[i] = W[i];
  int r0 = blockIdx.x * 32;
  for (int i = tid; i < 32 * 64; i += 256) {
    int r = i >> 6, k = i & 63;
    sx[i] = (r0 + r < NN) ? x[(size_t)(r0 + r) * 64 + k] : 0.f;
  }
  __syncthreads();
  int c = tid & 127;
  int rbase = (tid >> 7) * 16;
  for (int r = rbase; r < rbase + 16; r++) {
    float acc = b[c];
#pragma unroll
    for (int k = 0; k < 64; k++) acc += sx[r * 64 + k] * sW[k * 128 + c];
    int gr = r0 + r;
    u16 bv = f2b(acc);
    lhb[r * 136 + c] = bv;
    if (gr < NN) {
      hB[(size_t)gr * HD + c] = acc;
      hbB[(size_t)gr * HD + c] = bv;
      uiB[(size_t)gr * 384 + 256 + c] = bv;
    }
  }
  __syncthreads();
  pq_from_lhb(lhb, wpq0, PQ_all + (size_t)br * NN * 512, r0, tid >> 6, tid & 63);
}

// ---------------- edge phase: ui[n][:256] = sum_e relu(P[src_e] + Q[n] + b1) ------
// Half-wave owns a contiguous run of the node's edge list; 4 P-loads in flight.
__global__ __launch_bounds__(256) void k_edge(const u16* PQ, const int* starts,
                                              const int* srcs, const float* b1, u16* ui) {
  int br = blockIdx.z;
  int node = blockIdx.x * 4 + (threadIdx.x >> 6);
  int lane = threadIdx.x & 63;
  int half = lane >> 5;
  int c0 = (lane & 31) * 8;
  const u16* PQb = PQ + (size_t)br * NN * 512;
  const int* st = starts + br * (NN + 8);
  const int* sr = srcs + br * NE;
  u16x8 qr = *(const u16x8*)(PQb + (size_t)node * 512 + 256 + c0);
  float qv[8], acc[8];
#pragma unroll
  for (int j = 0; j < 8; j++) { qv[j] = b2f(qr[j]) + b1[c0 + j]; acc[j] = 0.f; }
  int e0 = st[node], e1 = st[node + 1];
  int mid = e0 + ((e1 - e0 + 1) >> 1);
  int e = half ? mid : e0;
  int ee = half ? e1 : mid;
  for (; e + 3 < ee; e += 4) {
    int s0 = sr[e], s1 = sr[e + 1], s2 = sr[e + 2], s3 = sr[e + 3];
    u16x8 p0 = *(const u16x8*)(PQb + (size_t)s0 * 512 + c0);
    u16x8 p1 = *(const u16x8*)(PQb + (size_t)s1 * 512 + c0);
    u16x8 p2 = *(const u16x8*)(PQb + (size_t)s2 * 512 + c0);
    u16x8 p3 = *(const u16x8*)(PQb + (size_t)s3 * 512 + c0);
#pragma unroll
    for (int j = 0; j < 8; j++) {
      float v0 = b2f(p0[j]) + qv[j];
      float v1 = b2f(p1[j]) + qv[j];
      float v2 = b2f(p2[j]) + qv[j];
      float v3 = b2f(p3[j]) + qv[j];
      acc[j] += (v0 > 0.f ? v0 : 0.f) + (v1 > 0.f ? v1 : 0.f)
              + (v2 > 0.f ? v2 : 0.f) + (v3 > 0.f ? v3 : 0.f);
    }
  }
  for (; e + 1 < ee; e += 2) {
    int s0 = sr[e], s1 = sr[e + 1];
    u16x8 p0 = *(const u16x8*)(PQb + (size_t)s0 * 512 + c0);
    u16x8 p1 = *(const u16x8*)(PQb + (size_t)s1 * 512 + c0);
#pragma unroll
    for (int j = 0; j < 8; j++) {
      float v0 = b2f(p0[j]) + qv[j];
      float v1 = b2f(p1[j]) + qv[j];
      acc[j] += (v0 > 0.f ? v0 : 0.f) + (v1 > 0.f ? v1 : 0.f);
    }
  }
  if (e < ee) {
    int s0 = sr[e];
    u16x8 p0 = *(const u16x8*)(PQb + (size_t)s0 * 512 + c0);
#pragma unroll
    for (int j = 0; j < 8; j++) {
      float v0 = b2f(p0[j]) + qv[j];
      acc[j] += (v0 > 0.f ? v0 : 0.f);
    }
  }
#pragma unroll
  for (int j = 0; j < 8; j++) acc[j] += __shfl_xor(acc[j], 32);
  if (half == 0) {
    u16x8 o;
#pragma unroll
    for (int j = 0; j < 8; j++) o[j] = f2b(acc[j]);
    *(u16x8*)(ui + (size_t)br * NN * 384 + (size_t)node * 384 + c0) = o;
  }
}

// ---------------- plain MFMA GEMM (bf16 store, no bias): Wc prep only ----------
struct GemmP {
  const u16* A;   size_t sA;
  int lda;
  const u16* Wt;  size_t sW;
  u16* outb;  size_t s_outb;
  int M, N, K, ldo;
};

__global__ __launch_bounds__(256) void k_gemm(GemmP p) {
  const int br = blockIdx.z;
  const int tid = threadIdx.x;
  const int lane = tid & 63, wave = tid >> 6;
  const int wm = (wave & 1) * 64, wn = (wave >> 1) * 64;
  const int q = lane >> 4, lr = lane & 15;
  const int m0 = blockIdx.x * 128, n0 = blockIdx.y * 128;
  __shared__ alignas(16) u16 lA[128 * LSTR];
  __shared__ alignas(16) u16 lB[128 * LSTR];

  f32x4 acc[4][4];
#pragma unroll
  for (int i = 0; i < 4; i++)
#pragma unroll
    for (int j = 0; j < 4; j++) acc[i][j] = (f32x4){0.f, 0.f, 0.f, 0.f};

  const u16* Abr = p.A + (size_t)br * p.sA;
  const u16* Wbr = p.Wt + (size_t)br * p.sW;

  for (int k0 = 0; k0 < p.K; k0 += 32) {
#pragma unroll
    for (int c = tid; c < 512; c += 256) {
      int r = c >> 2, kc = (c & 3) << 3;
      int gr = m0 + r;
      u16x8 v = {0, 0, 0, 0, 0, 0, 0, 0};
      if (gr < p.M) v = *(const u16x8*)(Abr + (size_t)gr * p.lda + k0 + kc);
      *(u16x8*)&lA[r * LSTR + kc] = v;
    }
#pragma unroll
    for (int c = tid; c < 512; c += 256) {
      int r = c >> 2, kc = (c & 3) << 3;
      *(u16x8*)&lB[r * LSTR + kc] = *(const u16x8*)(Wbr + (size_t)(n0 + r) * p.K + k0 + kc);
    }
    __syncthreads();
    bf16x8 af[4], bfr[4];
#pragma unroll
    for (int i = 0; i < 4; i++) af[i] = *(const bf16x8*)&lA[(wm + i * 16 + lr) * LSTR + q * 8];
#pragma unroll
    for (int i = 0; i < 4; i++) bfr[i] = *(const bf16x8*)&lB[(wn + i * 16 + lr) * LSTR + q * 8];
#pragma unroll
    for (int mi = 0; mi < 4; mi++)
#pragma unroll
      for (int ni = 0; ni < 4; ni++)
        acc[mi][ni] = __builtin_amdgcn_mfma_f32_16x16x32_bf16(af[mi], bfr[ni], acc[mi][ni], 0, 0, 0);
    __syncthreads();
  }

  u16* ob = p.outb + (size_t)br * p.s_outb;
#pragma unroll
  for (int mi = 0; mi < 4; mi++)
#pragma unroll
    for (int rg = 0; rg < 4; rg++) {
      int row = m0 + wm + mi * 16 + q * 4 + rg;
      if (row >= p.M) continue;
#pragma unroll
      for (int ni = 0; ni < 4; ni++) {
        int col = n0 + wn + ni * 16 + lr;
        ob[(size_t)row * p.ldo + col] = f2b(acc[mi][ni][rg]);
      }
    }
}

// ---------------- fused update MLP (M-tile 32) + phase3 (PQ-next or readout) ------
// P1: U1 strip = relu([S|h]@W1c + b1u + deg*c2) -> lU. P2: h += lU@W2^T + b2.
// P3 mode 0: PQ(next) = h_strip @ wt_pq(next).  mode 1: readout gate+pool.
__global__ __launch_bounds__(256, 3) void k_upd(
    const u16* ui_all, const u16* w1c, const float* b1u, const float* c2l,
    const int* deg_all, const u16* w2, const float* b2u,
    float* h_all, u16* hb_all, int mode,
    const u16* wpq_next, u16* PQ_all,
    const u16* wnode, const float* nb, const int* b0v, const int* b1v, float* g) {
  const int br = blockIdx.z;
  const int tid = threadIdx.x;
  const int lane = tid & 63, wave = tid >> 6;
  const int q = lane >> 4, lr = lane & 15;
  const int m0 = blockIdx.x * 32;

  __shared__ alignas(16) u16 sm[32 * LSTR + 256 * LSTR + 32 * 136];
  __shared__ int sbat[32];
  u16* lA = sm;
  u16* lB = sm + 32 * LSTR;
  u16* lU = sm;                       // 32*272, overlays staging after phase1
  u16* lhb = sm + 32 * LSTR + 256 * LSTR;  // 32*136

  if (mode == 1 && tid < 32) {
    const int* batch = br ? b1v : b0v;
    int n = m0 + tid;
    sbat[tid] = (n < NN) ? batch[n] : -1;
  }

  const u16* ui = ui_all + (size_t)br * NN * 384;

  // ---- phase 1 ----
  const int wn = wave * 64;
  f32x4 acc[2][4];
#pragma unroll
  for (int i = 0; i < 2; i++)
#pragma unroll
    for (int j = 0; j < 4; j++) acc[i][j] = (f32x4){0.f, 0.f, 0.f, 0.f};

  for (int k0 = 0; k0 < 384; k0 += 32) {
    for (int c = tid; c < 1152; c += 256) {
      if (c < 128) {
        int r = c >> 2, kc = (c & 3) << 3;
        int gr = m0 + r;
        u16x8 v = {0, 0, 0, 0, 0, 0, 0, 0};
        if (gr < NN) v = *(const u16x8*)(ui + (size_t)gr * 384 + k0 + kc);
        *(u16x8*)&lA[r * LSTR + kc] = v;
      } else {
        int cc = c - 128;
        int r = cc >> 2, kc = (cc & 3) << 3;
        *(u16x8*)&lB[r * LSTR + kc] = *(const u16x8*)(w1c + (size_t)r * 384 + k0 + kc);
      }
    }
    __syncthreads();
    bf16x8 af[2], bfr[4];
#pragma unroll
    for (int i = 0; i < 2; i++) af[i] = *(const bf16x8*)&lA[(i * 16 + lr) * LSTR + q * 8];
#pragma unroll
    for (int i = 0; i < 4; i++) bfr[i] = *(const bf16x8*)&lB[(wn + i * 16 + lr) * LSTR + q * 8];
#pragma unroll
    for (int mi = 0; mi < 2; mi++)
#pragma unroll
      for (int ni = 0; ni < 4; ni++)
        acc[mi][ni] = __builtin_amdgcn_mfma_f32_16x16x32_bf16(af[mi], bfr[ni], acc[mi][ni], 0, 0, 0);
    __syncthreads();
  }

  // relu + bias + deg*c2 -> bf16 into lU[32][272]
  const int* deg = deg_all + br * NN;
#pragma unroll
  for (int mi = 0; mi < 2; mi++)
#pragma unroll
    for (int rg = 0; rg < 4; rg++) {
      int row = mi * 16 + q * 4 + rg;
      int gr = m0 + row;
      float d = (gr < NN) ? (float)deg[gr] : 0.f;
#pragma unroll
      for (int ni = 0; ni < 4; ni++) {
        int col = wn + ni * 16 + lr;
        float v = acc[mi][ni][rg] + b1u[col] + d * c2l[col];
        if (v < 0.f) v = 0.f;
        lU[row * 272 + col] = f2b(v);
      }
    }
  __syncthreads();

  // ---- phase 2 ----
  const int wn2 = wave * 32;
  f32x4 acc2[2][2];
#pragma unroll
  for (int i = 0; i < 2; i++)
#pragma unroll
    for (int j = 0; j < 2; j++) acc2[i][j] = (f32x4){0.f, 0.f, 0.f, 0.f};

  for (int k0 = 0; k0 < 256; k0 += 32) {
    bf16x8 af[2], bfr[2];
#pragma unroll
    for (int i = 0; i < 2; i++)
      af[i] = *(const bf16x8*)&lU[(i * 16 + lr) * 272 + k0 + q * 8];
#pragma unroll
    for (int i = 0; i < 2; i++)
      bfr[i] = *(const bf16x8*)(w2 + (size_t)(wn2 + i * 16 + lr) * 256 + k0 + q * 8);
#pragma unroll
    for (int mi = 0; mi < 2; mi++)
#pragma unroll
      for (int ni = 0; ni < 2; ni++)
        acc2[mi][ni] = __builtin_amdgcn_mfma_f32_16x16x32_bf16(af[mi], bfr[ni], acc2[mi][ni], 0, 0, 0);
  }

  // residual epilogue (+ stage bf16 h into lhb)
  float* h = h_all + (size_t)br * NN * 128;
  u16* hb = hb_all + (size_t)br * NN * 128;
  u16* uiw = (u16*)ui_all + (size_t)br * NN * 384;
#pragma unroll
  for (int mi = 0; mi < 2; mi++)
#pragma unroll
    for (int rg = 0; rg < 4; rg++) {
      int lrow = mi * 16 + q * 4 + rg;
      int grow = m0 + lrow;
#pragma unroll
      for (int ni = 0; ni < 2; ni++) {
        int col = wn2 + ni * 16 + lr;
        if (grow < NN) {
          size_t o = (size_t)grow * 128 + col;
          float nh = h[o] + acc2[mi][ni][rg] + b2u[col];
          u16 bv = f2b(nh);
          h[o] = nh;
          hb[o] = bv;
          uiw[(size_t)grow * 384 + 256 + col] = bv;
          lhb[lrow * 136 + col] = bv;
        } else {
          lhb[lrow * 136 + col] = 0;
        }
      }
    }
  __syncthreads();

  // ---- phase 3 ----
  if (mode == 0) {
    pq_from_lhb(lhb, wpq_next, PQ_all + (size_t)br * NN * 512, m0, wave, lane);
  } else {
    const int wg = wave * 32;
    f32x4 a3[2][4];  // ni 0-1 gate cols, 2-3 val cols
#pragma unroll
    for (int i = 0; i < 2; i++)
#pragma unroll
      for (int j = 0; j < 4; j++) a3[i][j] = (f32x4){0.f, 0.f, 0.f, 0.f};
#pragma unroll
    for (int k0 = 0; k0 < 128; k0 += 32) {
      bf16x8 af[2], bfr[4];
#pragma unroll
      for (int i = 0; i < 2; i++)
        af[i] = *(const bf16x8*)&lhb[(i * 16 + lr) * 136 + k0 + q * 8];
#pragma unroll
      for (int i = 0; i < 4; i++) {
        int nrow = (i < 2) ? (wg + i * 16 + lr) : (128 + wg + (i - 2) * 16 + lr);
        bfr[i] = *(const bf16x8*)(wnode + (size_t)nrow * 128 + k0 + q * 8);
      }
#pragma unroll
      for (int mi = 0; mi < 2; mi++)
#pragma unroll
        for (int ni = 0; ni < 4; ni++)
          a3[mi][ni] = __builtin_amdgcn_mfma_f32_16x16x32_bf16(af[mi], bfr[ni], a3[mi][ni], 0, 0, 0);
    }
    float* gb = g + (size_t)br * NG * 128;
    float racc[2] = {0.f, 0.f};
    int cur = -1;
#pragma unroll
    for (int mi = 0; mi < 2; mi++)
#pragma unroll
      for (int rg = 0; rg < 4; rg++) {
        int lrow = mi * 16 + q * 4 + rg;
        int bt = sbat[lrow];
        if (bt != cur) {
          if (cur >= 0) {
#pragma unroll
            for (int ni = 0; ni < 2; ni++)
              atomicAdd(gb + (size_t)cur * 128 + wg + ni * 16 + lr, racc[ni]);
          }
          cur = bt;
          racc[0] = 0.f; racc[1] = 0.f;
        }
        if (bt >= 0) {
#pragma unroll
          for (int ni = 0; ni < 2; ni++) {
            int gcol = wg + ni * 16 + lr;
            float gt = a3[mi][ni][rg] + nb[gcol];
            float vl = a3[mi][ni + 2][rg] + nb[128 + gcol];
            racc[ni] += vl / (1.f + __expf(-gt));
          }
        }
      }
    if (cur >= 0) {
#pragma unroll
      for (int ni = 0; ni < 2; ni++)
        atomicAdd(gb + (size_t)cur * 128 + wg + ni * 16 + lr, racc[ni]);
    }
  }
}

// ---------------- final graph GEMM ----------------
__global__ __launch_bounds__(128) void k_final(const float* g, const float* W,
                                               const float* b, float* out) {
  int br = blockIdx.z, gi = blockIdx.x, j = threadIdx.x;
  __shared__ float sg[128];
  sg[j] = g[(size_t)br * NG * 128 + (size_t)gi * 128 + j];
  __syncthreads();
  float acc = b[j];
#pragma unroll
  for (int k = 0; k < 128; k++) acc += sg[k] * W[k * 128 + j];
  out[(size_t)br * NG * 128 + (size_t)gi * 128 + j] = acc;
}

extern "C" void kernel_launch(void* const* d_in, const int* in_sizes, int n_in,
                              void* d_out, int out_size, void* d_ws, size_t ws_size,
                              hipStream_t stream) {
  const float* x1     = (const float*)d_in[0];
  const int*   ei1    = (const int*)d_in[1];
  const int*   bat1   = (const int*)d_in[2];
  const float* x2     = (const float*)d_in[3];
  const int*   ei2    = (const int*)d_in[4];
  const int*   bat2   = (const int*)d_in[5];
  const float* W_emb  = (const float*)d_in[6];
  const float* b_emb  = (const float*)d_in[7];
  const float* msg_W1 = (const float*)d_in[8];
  const float* msg_b1 = (const float*)d_in[9];
  const float* msg_W2 = (const float*)d_in[10];
  const float* msg_b2 = (const float*)d_in[11];
  const float* upd_W1 = (const float*)d_in[12];
  const float* upd_b1 = (const float*)d_in[13];
  const float* upd_W2 = (const float*)d_in[14];
  const float* upd_b2 = (const float*)d_in[15];
  const float* node_W = (const float*)d_in[16];
  const float* node_b = (const float*)d_in[17];
  const float* graph_W = (const float*)d_in[18];
  const float* graph_b = (const float*)d_in[19];
  float* out = (float*)d_out;

  char* ws = (char*)d_ws;
  u16* wt_pq   = (u16*)(ws + WT_PQ);
  u16* wt_m2r  = (u16*)(ws + WT_M2R);
  u16* wt_upd1 = (u16*)(ws + WT_UPD1);
  u16* wt_u1c  = (u16*)(ws + WT_U1C);
  u16* wt_upd2 = (u16*)(ws + WT_UPD2);
  u16* wt_node = (u16*)(ws + WT_NODE);
  float* c2    = (float*)(ws + OFF_C2);
  int* deg    = (int*)(ws + OFF_DEG);
  int* starts = (int*)(ws + OFF_ST);
  int* cursor = (int*)(ws + OFF_CUR);
  int* srcs   = (int*)(ws + OFF_SRC);
  float* h  = (float*)(ws + OFF_H);
  u16*   hb = (u16*)(ws + OFF_HB);
  u16*   PQ = (u16*)(ws + OFF_PQ);
  u16*   ui = (u16*)(ws + OFF_UI);
  float* g  = (float*)(ws + OFF_G);

  // ---- prep (weights + c2 + zero deg/g) ----
  k_prep<<<768, 256, 0, stream>>>(msg_W1, msg_W2, upd_W1, upd_W2, node_W, msg_b2,
                                  wt_pq, wt_m2r, wt_upd1, wt_u1c, wt_upd2, wt_node,
                                  c2, deg, g);
  // Wc = W2 @ W1u_top -> wt_u1c[:, :256] (z = layer)
  {
    GemmP pc{};
    pc.A = wt_upd1; pc.sA = 98304; pc.lda = 384;
    pc.Wt = wt_m2r; pc.sW = 65536;
    pc.outb = wt_u1c; pc.s_outb = 98304;
    pc.M = 256; pc.N = 256; pc.K = 256; pc.ldo = 384;
    k_gemm<<<dim3(2, 2, 2), 256, 0, stream>>>(pc);
  }
  k_deg<<<dim3(625, 1, 2), 256, 0, stream>>>(ei1, ei2, deg);
  k_scan<<<dim3(1, 1, 2), 256, 0, stream>>>(deg, starts, cursor);
  k_scatter<<<dim3(625, 1, 2), 256, 0, stream>>>(ei1, ei2, cursor, srcs);
  // embed + PQ(l=0)
  k_embed<<<dim3(313, 1, 2), 256, 0, stream>>>(x1, x2, W_emb, b_emb, h, hb, ui,
                                               wt_pq, PQ);

  for (int l = 0; l < 2; l++) {
    // ui[:, :256] = S[n] = sum_{e: tgt=n} relu(P[src_e] + Q[n] + b1)
    k_edge<<<dim3(2500, 1, 2), 256, 0, stream>>>(PQ, starts, srcs, msg_b1 + l * 256, ui);

    // fused: U1 = relu([S|h]@W1c+..); h += U1@W2+b2; then PQ(l+1) or readout
    k_upd<<<dim3(313, 1, 2), 256, 0, stream>>>(
        ui, wt_u1c + (size_t)l * 98304, upd_b1 + l * 256, c2 + l * 256,
        deg, wt_upd2 + (size_t)l * 32768, upd_b2 + l * 128, h, hb,
        (l == 0) ? 0 : 1,
        wt_pq + 65536, PQ,
        wt_node, node_b, bat1, bat2, g);
  }

  k_final<<<dim3(NG, 1, 2), 128, 0, stream>>>(g, graph_W, graph_b, out);
}

// Round 7
// 350.964 us; speedup vs baseline: 4.4257x; 1.0337x over previous
//
#include <hip/hip_runtime.h>

typedef unsigned short u16;
typedef __bf16 bf16x8 __attribute__((ext_vector_type(8)));
typedef float f32x4 __attribute__((ext_vector_type(4)));
typedef unsigned short u16x8 __attribute__((ext_vector_type(8)));

constexpr int NN  = 10000;   // nodes
constexpr int NE  = 160000;  // edges
constexpr int NG  = 32;      // graphs
constexpr int HD  = 128;     // hidden

// ---- workspace layout (bytes) ----
constexpr size_t WT_PQ   = 0;                  // [2][512][128] bf16 (msgW1 split/transposed)
constexpr size_t WT_M2R  = 262144;             // [2][256][256] bf16 (msgW2 row-major cast)
constexpr size_t WT_UPD1 = 524288;             // [2][256][384] bf16 (updW1 transposed)
constexpr size_t WT_U1C  = 917504;             // [2][256][384] bf16 (combined UPD1' weight)
constexpr size_t WT_UPD2 = 1310720;            // [2][128][256]
constexpr size_t WT_NODE = 1441792;            // [256][128]
constexpr size_t OFF_C2  = 1507328;            // f32 [2][256]
constexpr size_t OFF_DEG = 1509376;            // int [2][NN]
constexpr size_t OFF_ST  = 1589376;            // int [2][NN+8]
constexpr size_t OFF_CUR = 1669440;            // int [2][NN]
constexpr size_t OFF_SRC = 1749440;            // int [2][NE]
constexpr size_t OFF_H   = 3029440;            // f32 [2][NN][128]
constexpr size_t OFF_HB  = 13269440;           // bf16 [2][NN][128]
constexpr size_t OFF_PQ  = 18389440;           // bf16 [2][NN][512]
constexpr size_t OFF_UI  = 38869440;           // bf16 [2][NN][384]
constexpr size_t OFF_G   = 54229440;           // f32 [2][NG][128]

#define LSTR 40

__device__ inline u16 f2b(float f) {
  unsigned int u = __float_as_uint(f);
  unsigned int r = u + 0x7fffu + ((u >> 16) & 1u);
  return (u16)(r >> 16);
}
__device__ inline float b2f(u16 u) { return __uint_as_float(((unsigned int)u) << 16); }

// ---------------- weight prep (+ c2, + zero deg/g) ----------------
__global__ __launch_bounds__(256) void k_prep(
    const float* msgW1, const float* msgW2, const float* updW1,
    const float* updW2, const float* nodeW, const float* msgb2,
    u16* tpq, u16* t2r, u16* t3, u16* tu1c, u16* t4, u16* t5,
    float* c2, int* deg, float* g) {
  int idx = blockIdx.x * 256 + threadIdx.x;
  if (idx < 131072) {
    // wt_pq: [l][n=512][k=128]; n<256 -> W1[k][n] (src half), n>=256 -> W1[128+k][n-256]
    int l = idx >> 16, r = idx & 65535, n = r >> 7, k = r & 127;
    int row = (n < 256) ? k : (128 + k);
    tpq[idx] = f2b(msgW1[l * 65536 + row * 256 + (n & 255)]);
    t2r[idx] = f2b(msgW2[idx]);
  }
  if (idx < 196608) {  // updW1: [l][k=384][n=256] -> [l][n=256][k=384]
    int l = idx / 98304, r = idx % 98304, n = r / 384, k = r % 384;
    t3[idx] = f2b(updW1[l * 98304 + k * 256 + n]);
  }
  if (idx < 65536) {   // u1c h-part: [l][n=256][256+k], k<128 <- updW1[l][256+k][n]
    int l = idx >> 15, r = idx & 32767, n = r >> 7, k = r & 127;
    tu1c[l * 98304 + n * 384 + 256 + k] = f2b(updW1[l * 98304 + (256 + k) * 256 + n]);
    // updW2: [l][k=256][n=128] -> [l][n=128][k=256]
    int n2 = (idx & 32767) >> 8, k2 = idx & 255;
    t4[idx] = f2b(updW2[(idx >> 15) * 32768 + (k2 << 7) + n2]);
  }
  if (idx < 32768) {   // nodeW: [k=128][n=256] -> [n=256][k=128]
    int n = idx >> 7, k = idx & 127;
    t5[idx] = f2b(nodeW[(k << 8) + n]);
  }
  if (idx < 512) {     // c2[l][n] = sum_c msg_b2[l][c] * updW1[l][c][n]
    int l = idx >> 8, n = idx & 255;
    const float* b2 = msgb2 + l * 256;
    const float* U1 = updW1 + l * 98304 + n;
    float a = 0.f;
    for (int c = 0; c < 256; c++) a += b2[c] * U1[c * 256];
    c2[idx] = a;
  }
  if (idx < 2 * NN) deg[idx] = 0;
  if (idx < 2 * NG * 128) g[idx] = 0.f;
}

// ---------------- counting sort of edges by tgt ----------------
__global__ __launch_bounds__(256) void k_deg(const int* ei0, const int* ei1, int* deg) {
  int br = blockIdx.z;
  int e = blockIdx.x * 256 + threadIdx.x;
  if (e >= NE) return;
  const int* tgt = br ? ei1 : ei0;
  atomicAdd(deg + br * NN + tgt[e], 1);
}

__global__ __launch_bounds__(256) void k_scan(const int* deg, int* starts, int* cursor) {
  int br = blockIdx.z;
  const int* d = deg + br * NN;
  int* st = starts + br * (NN + 8);
  int* cu = cursor + br * NN;
  __shared__ int part[257];
  int t = threadIdx.x;
  int c0 = t * 40;
  int s = 0;
  for (int i = 0; i < 40; i++) if (c0 + i < NN) s += d[c0 + i];
  part[t] = s;
  __syncthreads();
  if (t == 0) {
    int run = 0;
    for (int i = 0; i < 256; i++) { int v = part[i]; part[i] = run; run += v; }
    part[256] = run;
  }
  __syncthreads();
  int run = part[t];
  for (int i = 0; i < 40; i++) {
    int n = c0 + i;
    if (n < NN) { st[n] = run; cu[n] = run; run += d[n]; }
  }
  if (t == 255) st[NN] = part[256];
}

__global__ __launch_bounds__(256) void k_scatter(const int* ei0, const int* ei1,
                                                 int* cursor, int* srcs) {
  int br = blockIdx.z;
  int e = blockIdx.x * 256 + threadIdx.x;
  if (e >= NE) return;
  const int* ei = br ? ei1 : ei0;
  int t = ei[e], s = ei[NE + e];
  int pos = atomicAdd(cursor + br * NN + t, 1);
  srcs[br * NE + pos] = s;
}

// ---------------- shared phase: PQ strip from lhb (32x128 bf16, stride 136) -------
__device__ __forceinline__ void pq_from_lhb(
    const u16* lhb, const u16* wq, u16* PQ, int m0, int wave, int lane) {
  const int q = lane >> 4, lr = lane & 15;
  f32x4 a3[2][8];
#pragma unroll
  for (int i = 0; i < 2; i++)
#pragma unroll
    for (int j = 0; j < 8; j++) a3[i][j] = (f32x4){0.f, 0.f, 0.f, 0.f};
#pragma unroll
  for (int k0 = 0; k0 < 128; k0 += 32) {
    bf16x8 af[2], bfr[8];
#pragma unroll
    for (int i = 0; i < 2; i++)
      af[i] = *(const bf16x8*)&lhb[(i * 16 + lr) * 136 + k0 + q * 8];
#pragma unroll
    for (int i = 0; i < 8; i++)
      bfr[i] = *(const bf16x8*)(wq + (size_t)(wave * 128 + i * 16 + lr) * 128 + k0 + q * 8);
#pragma unroll
    for (int mi = 0; mi < 2; mi++)
#pragma unroll
      for (int ni = 0; ni < 8; ni++)
        a3[mi][ni] = __builtin_amdgcn_mfma_f32_16x16x32_bf16(af[mi], bfr[ni], a3[mi][ni], 0, 0, 0);
  }
#pragma unroll
  for (int mi = 0; mi < 2; mi++)
#pragma unroll
    for (int rg = 0; rg < 4; rg++) {
      int grow = m0 + mi * 16 + q * 4 + rg;
      if (grow >= NN) continue;
#pragma unroll
      for (int ni = 0; ni < 8; ni++) {
        int col = wave * 128 + ni * 16 + lr;
        PQ[(size_t)grow * 512 + col] = f2b(a3[mi][ni][rg]);
      }
    }
}

// ---------------- embedding: h = x @ W_emb + b_emb; + PQ(l=0) phase ---------------
__global__ __launch_bounds__(256) void k_embed(
    const float* x1, const float* x2, const float* W, const float* b,
    float* h, u16* h_bf, u16* ui, const u16* wpq0, u16* PQ_all) {
  int br = blockIdx.z;
  const float* x = br ? x2 : x1;
  float* hB = h + (size_t)br * NN * HD;
  u16* hbB = h_bf + (size_t)br * NN * HD;
  u16* uiB = ui + (size_t)br * NN * 384;
  __shared__ float sW[64 * 128];
  __shared__ float sx[32 * 64];
  __shared__ alignas(16) u16 lhb[32 * 136];
  int tid = threadIdx.x;
  for (int i = tid; i < 64 * 128; i += 256) sW[i] = W[i];
  int r0 = blockIdx.x * 32;
  for (int i = tid; i < 32 * 64; i += 256) {
    int r = i >> 6, k = i & 63;
    sx[i] = (r0 + r < NN) ? x[(size_t)(r0 + r) * 64 + k] : 0.f;
  }
  __syncthreads();
  int c = tid & 127;
  int rbase = (tid >> 7) * 16;
  for (int r = rbase; r < rbase + 16; r++) {
    float acc = b[c];
#pragma unroll
    for (int k = 0; k < 64; k++) acc += sx[r * 64 + k] * sW[k * 128 + c];
    int gr = r0 + r;
    u16 bv = f2b(acc);
    lhb[r * 136 + c] = bv;
    if (gr < NN) {
      hB[(size_t)gr * HD + c] = acc;
      hbB[(size_t)gr * HD + c] = bv;
      uiB[(size_t)gr * 384 + 256 + c] = bv;
    }
  }
  __syncthreads();
  pq_from_lhb(lhb, wpq0, PQ_all + (size_t)br * NN * 512, r0, tid >> 6, tid & 63);
}

// ---------------- edge phase: ui[n][:256] = sum_e relu(P[src_e] + Q[n] + b1) ------
// Half-wave owns a contiguous run of the node's edge list; 4 P-loads in flight.
__global__ __launch_bounds__(256) void k_edge(const u16* PQ, const int* starts,
                                              const int* srcs, const float* b1, u16* ui) {
  int br = blockIdx.z;
  int node = blockIdx.x * 4 + (threadIdx.x >> 6);
  int lane = threadIdx.x & 63;
  int half = lane >> 5;
  int c0 = (lane & 31) * 8;
  const u16* PQb = PQ + (size_t)br * NN * 512;
  const int* st = starts + br * (NN + 8);
  const int* sr = srcs + br * NE;
  u16x8 qr = *(const u16x8*)(PQb + (size_t)node * 512 + 256 + c0);
  float qv[8], acc[8];
#pragma unroll
  for (int j = 0; j < 8; j++) { qv[j] = b2f(qr[j]) + b1[c0 + j]; acc[j] = 0.f; }
  int e0 = st[node], e1 = st[node + 1];
  int mid = e0 + ((e1 - e0 + 1) >> 1);
  int e = half ? mid : e0;
  int ee = half ? e1 : mid;
  for (; e + 3 < ee; e += 4) {
    int s0 = sr[e], s1 = sr[e + 1], s2 = sr[e + 2], s3 = sr[e + 3];
    u16x8 p0 = *(const u16x8*)(PQb + (size_t)s0 * 512 + c0);
    u16x8 p1 = *(const u16x8*)(PQb + (size_t)s1 * 512 + c0);
    u16x8 p2 = *(const u16x8*)(PQb + (size_t)s2 * 512 + c0);
    u16x8 p3 = *(const u16x8*)(PQb + (size_t)s3 * 512 + c0);
#pragma unroll
    for (int j = 0; j < 8; j++) {
      float v0 = b2f(p0[j]) + qv[j];
      float v1 = b2f(p1[j]) + qv[j];
      float v2 = b2f(p2[j]) + qv[j];
      float v3 = b2f(p3[j]) + qv[j];
      acc[j] += (v0 > 0.f ? v0 : 0.f) + (v1 > 0.f ? v1 : 0.f)
              + (v2 > 0.f ? v2 : 0.f) + (v3 > 0.f ? v3 : 0.f);
    }
  }
  for (; e + 1 < ee; e += 2) {
    int s0 = sr[e], s1 = sr[e + 1];
    u16x8 p0 = *(const u16x8*)(PQb + (size_t)s0 * 512 + c0);
    u16x8 p1 = *(const u16x8*)(PQb + (size_t)s1 * 512 + c0);
#pragma unroll
    for (int j = 0; j < 8; j++) {
      float v0 = b2f(p0[j]) + qv[j];
      float v1 = b2f(p1[j]) + qv[j];
      acc[j] += (v0 > 0.f ? v0 : 0.f) + (v1 > 0.f ? v1 : 0.f);
    }
  }
  if (e < ee) {
    int s0 = sr[e];
    u16x8 p0 = *(const u16x8*)(PQb + (size_t)s0 * 512 + c0);
#pragma unroll
    for (int j = 0; j < 8; j++) {
      float v0 = b2f(p0[j]) + qv[j];
      acc[j] += (v0 > 0.f ? v0 : 0.f);
    }
  }
#pragma unroll
  for (int j = 0; j < 8; j++) acc[j] += __shfl_xor(acc[j], 32);
  if (half == 0) {
    u16x8 o;
#pragma unroll
    for (int j = 0; j < 8; j++) o[j] = f2b(acc[j]);
    *(u16x8*)(ui + (size_t)br * NN * 384 + (size_t)node * 384 + c0) = o;
  }
}

// ---------------- plain MFMA GEMM (bf16 store, no bias): Wc prep only ----------
struct GemmP {
  const u16* A;   size_t sA;
  int lda;
  const u16* Wt;  size_t sW;
  u16* outb;  size_t s_outb;
  int M, N, K, ldo;
};

__global__ __launch_bounds__(256) void k_gemm(GemmP p) {
  const int br = blockIdx.z;
  const int tid = threadIdx.x;
  const int lane = tid & 63, wave = tid >> 6;
  const int wm = (wave & 1) * 64, wn = (wave >> 1) * 64;
  const int q = lane >> 4, lr = lane & 15;
  const int m0 = blockIdx.x * 128, n0 = blockIdx.y * 128;
  __shared__ alignas(16) u16 lA[128 * LSTR];
  __shared__ alignas(16) u16 lB[128 * LSTR];

  f32x4 acc[4][4];
#pragma unroll
  for (int i = 0; i < 4; i++)
#pragma unroll
    for (int j = 0; j < 4; j++) acc[i][j] = (f32x4){0.f, 0.f, 0.f, 0.f};

  const u16* Abr = p.A + (size_t)br * p.sA;
  const u16* Wbr = p.Wt + (size_t)br * p.sW;

  for (int k0 = 0; k0 < p.K; k0 += 32) {
#pragma unroll
    for (int c = tid; c < 512; c += 256) {
      int r = c >> 2, kc = (c & 3) << 3;
      int gr = m0 + r;
      u16x8 v = {0, 0, 0, 0, 0, 0, 0, 0};
      if (gr < p.M) v = *(const u16x8*)(Abr + (size_t)gr * p.lda + k0 + kc);
      *(u16x8*)&lA[r * LSTR + kc] = v;
    }
#pragma unroll
    for (int c = tid; c < 512; c += 256) {
      int r = c >> 2, kc = (c & 3) << 3;
      *(u16x8*)&lB[r * LSTR + kc] = *(const u16x8*)(Wbr + (size_t)(n0 + r) * p.K + k0 + kc);
    }
    __syncthreads();
    bf16x8 af[4], bfr[4];
#pragma unroll
    for (int i = 0; i < 4; i++) af[i] = *(const bf16x8*)&lA[(wm + i * 16 + lr) * LSTR + q * 8];
#pragma unroll
    for (int i = 0; i < 4; i++) bfr[i] = *(const bf16x8*)&lB[(wn + i * 16 + lr) * LSTR + q * 8];
#pragma unroll
    for (int mi = 0; mi < 4; mi++)
#pragma unroll
      for (int ni = 0; ni < 4; ni++)
        acc[mi][ni] = __builtin_amdgcn_mfma_f32_16x16x32_bf16(af[mi], bfr[ni], acc[mi][ni], 0, 0, 0);
    __syncthreads();
  }

  u16* ob = p.outb + (size_t)br * p.s_outb;
#pragma unroll
  for (int mi = 0; mi < 4; mi++)
#pragma unroll
    for (int rg = 0; rg < 4; rg++) {
      int row = m0 + wm + mi * 16 + q * 4 + rg;
      if (row >= p.M) continue;
#pragma unroll
      for (int ni = 0; ni < 4; ni++) {
        int col = n0 + wn + ni * 16 + lr;
        ob[(size_t)row * p.ldo + col] = f2b(acc[mi][ni][rg]);
      }
    }
}

// ---------------- fused update MLP (M-tile 32), single-stage A, global B ----------
// Stage A strip once (1 barrier). P1: U1 = relu([S|h]@W1c + b1u + deg*c2), B from
// global. lU overlays lA. P2: h += lU@W2^T + b2. P3: PQ-next (mode 0) or readout.
__global__ __launch_bounds__(256, 4) void k_upd(
    const u16* ui_all, const u16* w1c, const float* b1u, const float* c2l,
    const int* deg_all, const u16* w2, const float* b2u,
    float* h_all, u16* hb_all, int mode,
    const u16* wpq_next, u16* PQ_all,
    const u16* wnode, const float* nb, const int* b0v, const int* b1v, float* g) {
  const int br = blockIdx.z;
  const int tid = threadIdx.x;
  const int lane = tid & 63, wave = tid >> 6;
  const int q = lane >> 4, lr = lane & 15;
  const int m0 = blockIdx.x * 32;

  __shared__ alignas(16) u16 lA[32 * 392];   // A strip [32][384], stride 392
  __shared__ alignas(16) u16 lhb[32 * 136];
  __shared__ int sbat[32];
  u16* lU = lA;  // overlay after phase1 (32*272 <= 32*392)

  const u16* ui = ui_all + (size_t)br * NN * 384;

  // ---- stage A strip: 1536 u16x8 chunks, 6 per thread ----
  for (int c = tid; c < 1536; c += 256) {
    int r = c / 48, kc = (c % 48) * 8;
    int gr = m0 + r;
    u16x8 v = {0, 0, 0, 0, 0, 0, 0, 0};
    if (gr < NN) v = *(const u16x8*)(ui + (size_t)gr * 384 + kc);
    *(u16x8*)&lA[r * 392 + kc] = v;
  }
  if (mode == 1 && tid < 32) {
    const int* batch = br ? b1v : b0v;
    int n = m0 + tid;
    sbat[tid] = (n < NN) ? batch[n] : -1;
  }
  __syncthreads();

  // ---- phase 1: af from lA, bfr direct from global w1c (L2-resident) ----
  const int wn = wave * 64;
  f32x4 acc[2][4];
#pragma unroll
  for (int i = 0; i < 2; i++)
#pragma unroll
    for (int j = 0; j < 4; j++) acc[i][j] = (f32x4){0.f, 0.f, 0.f, 0.f};

#pragma unroll
  for (int k0 = 0; k0 < 384; k0 += 32) {
    bf16x8 af[2], bfr[4];
#pragma unroll
    for (int i = 0; i < 2; i++)
      af[i] = *(const bf16x8*)&lA[(i * 16 + lr) * 392 + k0 + q * 8];
#pragma unroll
    for (int i = 0; i < 4; i++)
      bfr[i] = *(const bf16x8*)(w1c + (size_t)(wn + i * 16 + lr) * 384 + k0 + q * 8);
#pragma unroll
    for (int mi = 0; mi < 2; mi++)
#pragma unroll
      for (int ni = 0; ni < 4; ni++)
        acc[mi][ni] = __builtin_amdgcn_mfma_f32_16x16x32_bf16(af[mi], bfr[ni], acc[mi][ni], 0, 0, 0);
  }
  __syncthreads();  // all lA reads done before overlay

  // relu + bias + deg*c2 -> bf16 into lU[32][272] (overlays lA)
  const int* deg = deg_all + br * NN;
#pragma unroll
  for (int mi = 0; mi < 2; mi++)
#pragma unroll
    for (int rg = 0; rg < 4; rg++) {
      int row = mi * 16 + q * 4 + rg;
      int gr = m0 + row;
      float d = (gr < NN) ? (float)deg[gr] : 0.f;
#pragma unroll
      for (int ni = 0; ni < 4; ni++) {
        int col = wn + ni * 16 + lr;
        float v = acc[mi][ni][rg] + b1u[col] + d * c2l[col];
        if (v < 0.f) v = 0.f;
        lU[row * 272 + col] = f2b(v);
      }
    }
  __syncthreads();

  // ---- phase 2: af from lU, bfr from global w2 ----
  const int wn2 = wave * 32;
  f32x4 acc2[2][2];
#pragma unroll
  for (int i = 0; i < 2; i++)
#pragma unroll
    for (int j = 0; j < 2; j++) acc2[i][j] = (f32x4){0.f, 0.f, 0.f, 0.f};

#pragma unroll
  for (int k0 = 0; k0 < 256; k0 += 32) {
    bf16x8 af[2], bfr[2];
#pragma unroll
    for (int i = 0; i < 2; i++)
      af[i] = *(const bf16x8*)&lU[(i * 16 + lr) * 272 + k0 + q * 8];
#pragma unroll
    for (int i = 0; i < 2; i++)
      bfr[i] = *(const bf16x8*)(w2 + (size_t)(wn2 + i * 16 + lr) * 256 + k0 + q * 8);
#pragma unroll
    for (int mi = 0; mi < 2; mi++)
#pragma unroll
      for (int ni = 0; ni < 2; ni++)
        acc2[mi][ni] = __builtin_amdgcn_mfma_f32_16x16x32_bf16(af[mi], bfr[ni], acc2[mi][ni], 0, 0, 0);
  }

  // residual epilogue (+ stage bf16 h into lhb)
  float* h = h_all + (size_t)br * NN * 128;
  u16* hb = hb_all + (size_t)br * NN * 128;
  u16* uiw = (u16*)ui_all + (size_t)br * NN * 384;
#pragma unroll
  for (int mi = 0; mi < 2; mi++)
#pragma unroll
    for (int rg = 0; rg < 4; rg++) {
      int lrow = mi * 16 + q * 4 + rg;
      int grow = m0 + lrow;
#pragma unroll
      for (int ni = 0; ni < 2; ni++) {
        int col = wn2 + ni * 16 + lr;
        if (grow < NN) {
          size_t o = (size_t)grow * 128 + col;
          float nh = h[o] + acc2[mi][ni][rg] + b2u[col];
          u16 bv = f2b(nh);
          h[o] = nh;
          hb[o] = bv;
          uiw[(size_t)grow * 384 + 256 + col] = bv;
          lhb[lrow * 136 + col] = bv;
        } else {
          lhb[lrow * 136 + col] = 0;
        }
      }
    }
  __syncthreads();

  // ---- phase 3 ----
  if (mode == 0) {
    pq_from_lhb(lhb, wpq_next, PQ_all + (size_t)br * NN * 512, m0, wave, lane);
  } else {
    const int wg = wave * 32;
    f32x4 a3[2][4];  // ni 0-1 gate cols, 2-3 val cols
#pragma unroll
    for (int i = 0; i < 2; i++)
#pragma unroll
      for (int j = 0; j < 4; j++) a3[i][j] = (f32x4){0.f, 0.f, 0.f, 0.f};
#pragma unroll
    for (int k0 = 0; k0 < 128; k0 += 32) {
      bf16x8 af[2], bfr[4];
#pragma unroll
      for (int i = 0; i < 2; i++)
        af[i] = *(const bf16x8*)&lhb[(i * 16 + lr) * 136 + k0 + q * 8];
#pragma unroll
      for (int i = 0; i < 4; i++) {
        int nrow = (i < 2) ? (wg + i * 16 + lr) : (128 + wg + (i - 2) * 16 + lr);
        bfr[i] = *(const bf16x8*)(wnode + (size_t)nrow * 128 + k0 + q * 8);
      }
#pragma unroll
      for (int mi = 0; mi < 2; mi++)
#pragma unroll
        for (int ni = 0; ni < 4; ni++)
          a3[mi][ni] = __builtin_amdgcn_mfma_f32_16x16x32_bf16(af[mi], bfr[ni], a3[mi][ni], 0, 0, 0);
    }
    float* gb = g + (size_t)br * NG * 128;
    float racc[2] = {0.f, 0.f};
    int cur = -1;
#pragma unroll
    for (int mi = 0; mi < 2; mi++)
#pragma unroll
      for (int rg = 0; rg < 4; rg++) {
        int lrow = mi * 16 + q * 4 + rg;
        int bt = sbat[lrow];
        if (bt != cur) {
          if (cur >= 0) {
#pragma unroll
            for (int ni = 0; ni < 2; ni++)
              atomicAdd(gb + (size_t)cur * 128 + wg + ni * 16 + lr, racc[ni]);
          }
          cur = bt;
          racc[0] = 0.f; racc[1] = 0.f;
        }
        if (bt >= 0) {
#pragma unroll
          for (int ni = 0; ni < 2; ni++) {
            int gcol = wg + ni * 16 + lr;
            float gt = a3[mi][ni][rg] + nb[gcol];
            float vl = a3[mi][ni + 2][rg] + nb[128 + gcol];
            racc[ni] += vl / (1.f + __expf(-gt));
          }
        }
      }
    if (cur >= 0) {
#pragma unroll
      for (int ni = 0; ni < 2; ni++)
        atomicAdd(gb + (size_t)cur * 128 + wg + ni * 16 + lr, racc[ni]);
    }
  }
}

// ---------------- final graph GEMM ----------------
__global__ __launch_bounds__(128) void k_final(const float* g, const float* W,
                                               const float* b, float* out) {
  int br = blockIdx.z, gi = blockIdx.x, j = threadIdx.x;
  __shared__ float sg[128];
  sg[j] = g[(size_t)br * NG * 128 + (size_t)gi * 128 + j];
  __syncthreads();
  float acc = b[j];
#pragma unroll
  for (int k = 0; k < 128; k++) acc += sg[k] * W[k * 128 + j];
  out[(size_t)br * NG * 128 + (size_t)gi * 128 + j] = acc;
}

extern "C" void kernel_launch(void* const* d_in, const int* in_sizes, int n_in,
                              void* d_out, int out_size, void* d_ws, size_t ws_size,
                              hipStream_t stream) {
  const float* x1     = (const float*)d_in[0];
  const int*   ei1    = (const int*)d_in[1];
  const int*   bat1   = (const int*)d_in[2];
  const float* x2     = (const float*)d_in[3];
  const int*   ei2    = (const int*)d_in[4];
  const int*   bat2   = (const int*)d_in[5];
  const float* W_emb  = (const float*)d_in[6];
  const float* b_emb  = (const float*)d_in[7];
  const float* msg_W1 = (const float*)d_in[8];
  const float* msg_b1 = (const float*)d_in[9];
  const float* msg_W2 = (const float*)d_in[10];
  const float* msg_b2 = (const float*)d_in[11];
  const float* upd_W1 = (const float*)d_in[12];
  const float* upd_b1 = (const float*)d_in[13];
  const float* upd_W2 = (const float*)d_in[14];
  const float* upd_b2 = (const float*)d_in[15];
  const float* node_W = (const float*)d_in[16];
  const float* node_b = (const float*)d_in[17];
  const float* graph_W = (const float*)d_in[18];
  const float* graph_b = (const float*)d_in[19];
  float* out = (float*)d_out;

  char* ws = (char*)d_ws;
  u16* wt_pq   = (u16*)(ws + WT_PQ);
  u16* wt_m2r  = (u16*)(ws + WT_M2R);
  u16* wt_upd1 = (u16*)(ws + WT_UPD1);
  u16* wt_u1c  = (u16*)(ws + WT_U1C);
  u16* wt_upd2 = (u16*)(ws + WT_UPD2);
  u16* wt_node = (u16*)(ws + WT_NODE);
  float* c2    = (float*)(ws + OFF_C2);
  int* deg    = (int*)(ws + OFF_DEG);
  int* starts = (int*)(ws + OFF_ST);
  int* cursor = (int*)(ws + OFF_CUR);
  int* srcs   = (int*)(ws + OFF_SRC);
  float* h  = (float*)(ws + OFF_H);
  u16*   hb = (u16*)(ws + OFF_HB);
  u16*   PQ = (u16*)(ws + OFF_PQ);
  u16*   ui = (u16*)(ws + OFF_UI);
  float* g  = (float*)(ws + OFF_G);

  // ---- prep (weights + c2 + zero deg/g) ----
  k_prep<<<768, 256, 0, stream>>>(msg_W1, msg_W2, upd_W1, upd_W2, node_W, msg_b2,
                                  wt_pq, wt_m2r, wt_upd1, wt_u1c, wt_upd2, wt_node,
                                  c2, deg, g);
  // Wc = W2 @ W1u_top -> wt_u1c[:, :256] (z = layer)
  {
    GemmP pc{};
    pc.A = wt_upd1; pc.sA = 98304; pc.lda = 384;
    pc.Wt = wt_m2r; pc.sW = 65536;
    pc.outb = wt_u1c; pc.s_outb = 98304;
    pc.M = 256; pc.N = 256; pc.K = 256; pc.ldo = 384;
    k_gemm<<<dim3(2, 2, 2), 256, 0, stream>>>(pc);
  }
  k_deg<<<dim3(625, 1, 2), 256, 0, stream>>>(ei1, ei2, deg);
  k_scan<<<dim3(1, 1, 2), 256, 0, stream>>>(deg, starts, cursor);
  k_scatter<<<dim3(625, 1, 2), 256, 0, stream>>>(ei1, ei2, cursor, srcs);
  // embed + PQ(l=0)
  k_embed<<<dim3(313, 1, 2), 256, 0, stream>>>(x1, x2, W_emb, b_emb, h, hb, ui,
                                               wt_pq, PQ);

  for (int l = 0; l < 2; l++) {
    // ui[:, :256] = S[n] = sum_{e: tgt=n} relu(P[src_e] + Q[n] + b1)
    k_edge<<<dim3(2500, 1, 2), 256, 0, stream>>>(PQ, starts, srcs, msg_b1 + l * 256, ui);

    // fused: U1 = relu([S|h]@W1c+..); h += U1@W2+b2; then PQ(l+1) or readout
    k_upd<<<dim3(313, 1, 2), 256, 0, stream>>>(
        ui, wt_u1c + (size_t)l * 98304, upd_b1 + l * 256, c2 + l * 256,
        deg, wt_upd2 + (size_t)l * 32768, upd_b2 + l * 128, h, hb,
        (l == 0) ? 0 : 1,
        wt_pq + 65536, PQ,
        wt_node, node_b, bat1, bat2, g);
  }

  k_final<<<dim3(NG, 1, 2), 128, 0, stream>>>(g, graph_W, graph_b, out);
}

// Round 8
// 331.808 us; speedup vs baseline: 4.6812x; 1.0577x over previous
//
#include <hip/hip_runtime.h>

typedef unsigned short u16;
typedef __bf16 bf16x8 __attribute__((ext_vector_type(8)));
typedef float f32x4 __attribute__((ext_vector_type(4)));
typedef unsigned short u16x8 __attribute__((ext_vector_type(8)));

constexpr int NN  = 10000;   // nodes
constexpr int NE  = 160000;  // edges
constexpr int NG  = 32;      // graphs
constexpr int HD  = 128;     // hidden

// ---- workspace layout (bytes) ----
constexpr size_t WT_PQ   = 0;                  // [2][512][128] bf16 (msgW1 split/transposed)
constexpr size_t WT_U1C  = 917504;             // [2][256][384] bf16 (combined UPD1' weight)
constexpr size_t WT_UPD2 = 1310720;            // [2][128][256]
constexpr size_t WT_NODE = 1441792;            // [256][128]
constexpr size_t OFF_C2  = 1507328;            // f32 [2][256]
constexpr size_t OFF_DEG = 1509376;            // int [2][NN]
constexpr size_t OFF_ST  = 1589376;            // int [2][NN+8]
constexpr size_t OFF_CUR = 1669440;            // int [2][NN]
constexpr size_t OFF_SRC = 1749440;            // int [2][NE]
constexpr size_t OFF_H   = 3029440;            // f32 [2][NN][128]
constexpr size_t OFF_HB  = 13269440;           // bf16 [2][NN][128]
constexpr size_t OFF_PQ  = 18389440;           // bf16 [2][NN][512]
constexpr size_t OFF_UI  = 38869440;           // bf16 [2][NN][384]
constexpr size_t OFF_G   = 54229440;           // f32 [2][NG][128]
constexpr size_t OFF_XB  = 54262208;           // bf16 [2][NN][64]
constexpr size_t WT_EMB  = 56822208;           // [128][64] bf16 (W_emb transposed)

#define LSTR 40

__device__ inline u16 f2b(float f) {
  unsigned int u = __float_as_uint(f);
  unsigned int r = u + 0x7fffu + ((u >> 16) & 1u);
  return (u16)(r >> 16);
}
__device__ inline float b2f(u16 u) { return __uint_as_float(((unsigned int)u) << 16); }

// ---------------- weight prep (+ Wc, c2, xb cast, zero deg/g) ----------------
__global__ __launch_bounds__(256) void k_prep(
    const float* msgW1, const float* msgW2, const float* updW1,
    const float* updW2, const float* nodeW, const float* msgb2,
    const float* W_emb, const float* x1, const float* x2,
    u16* tpq, u16* tu1c, u16* t4, u16* t5, u16* temb, u16* xb,
    float* c2, int* deg, float* g) {
  int idx = blockIdx.x * 256 + threadIdx.x;
  if (idx < 131072) {
    // wt_pq: [l][n=512][k=128]; n<256 -> W1[k][n] (src half), n>=256 -> W1[128+k][n-256]
    int l = idx >> 16, r = idx & 65535, n = r >> 7, k = r & 127;
    int row = (n < 256) ? k : (128 + k);
    tpq[idx] = f2b(msgW1[l * 65536 + row * 256 + (n & 255)]);
  }
  if (idx < 65536) {   // u1c h-part: [l][n=256][256+k], k<128 <- updW1[l][256+k][n]
    int l = idx >> 15, r = idx & 32767, n = r >> 7, k = r & 127;
    tu1c[l * 98304 + n * 384 + 256 + k] = f2b(updW1[l * 98304 + (256 + k) * 256 + n]);
    // updW2: [l][k=256][n=128] -> [l][n=128][k=256]
    int n2 = (idx & 32767) >> 8, k2 = idx & 255;
    t4[idx] = f2b(updW2[(idx >> 15) * 32768 + (k2 << 7) + n2]);
  }
  if (idx < 32768) {   // nodeW: [k=128][n=256] -> [n=256][k=128]
    int n = idx >> 7, k = idx & 127;
    t5[idx] = f2b(nodeW[(k << 8) + n]);
  }
  if (idx < 512) {     // c2[l][n] = sum_c msg_b2[l][c] * updW1[l][c][n]
    int l = idx >> 8, n = idx & 255;
    const float* b2 = msgb2 + l * 256;
    const float* U1 = updW1 + l * 98304 + n;
    float a = 0.f;
    for (int c = 0; c < 256; c++) a += b2[c] * U1[c * 256];
    c2[idx] = a;
  }
  if (idx < 2 * NN) deg[idx] = 0;
  if (idx < 2 * NG * 128) g[idx] = 0.f;
  if (idx >= 131072 && idx < 262144) {
    // Wc = W2 @ W1u_top (fp32 accumulate): tu1c[l][n][k<256] = sum_c W2[k][c]*W1u[c][n]
    int j = idx - 131072;
    int l = j >> 16, r = j & 65535, k = r >> 8, n = r & 255;
    const float* w2p = msgW2 + l * 65536 + k * 256;
    const float* u1p = updW1 + l * 98304 + n;
    float a = 0.f;
    for (int c = 0; c < 256; c++) a += w2p[c] * u1p[c * 256];
    tu1c[l * 98304 + n * 384 + k] = f2b(a);
  }
  if (idx >= 262144 && idx < 270336) {
    // wt_emb: [n=128][k=64] <- W_emb[k][n]
    int j = idx - 262144;
    int n = j >> 6, k = j & 63;
    temb[j] = f2b(W_emb[(k << 7) + n]);
  }
  if (idx >= 270336 && idx < 1550336) {
    // xb cast: [2][NN][64] bf16
    int j = idx - 270336;
    int br = j >= NN * 64;
    int jj = br ? j - NN * 64 : j;
    const float* x = br ? x2 : x1;
    xb[(size_t)br * NN * 64 + jj] = f2b(x[jj]);
  }
}

// ---------------- counting sort of edges by tgt ----------------
__global__ __launch_bounds__(256) void k_deg(const int* ei0, const int* ei1, int* deg) {
  int br = blockIdx.z;
  int e = blockIdx.x * 256 + threadIdx.x;
  if (e >= NE) return;
  const int* tgt = br ? ei1 : ei0;
  atomicAdd(deg + br * NN + tgt[e], 1);
}

__global__ __launch_bounds__(256) void k_scan(const int* deg, int* starts, int* cursor) {
  int br = blockIdx.z;
  const int* d = deg + br * NN;
  int* st = starts + br * (NN + 8);
  int* cu = cursor + br * NN;
  __shared__ int part[257];
  int t = threadIdx.x;
  int c0 = t * 40;
  int s = 0;
  for (int i = 0; i < 40; i++) if (c0 + i < NN) s += d[c0 + i];
  part[t] = s;
  __syncthreads();
  if (t == 0) {
    int run = 0;
    for (int i = 0; i < 256; i++) { int v = part[i]; part[i] = run; run += v; }
    part[256] = run;
  }
  __syncthreads();
  int run = part[t];
  for (int i = 0; i < 40; i++) {
    int n = c0 + i;
    if (n < NN) { st[n] = run; cu[n] = run; run += d[n]; }
  }
  if (t == 255) st[NN] = part[256];
}

__global__ __launch_bounds__(256) void k_scatter(const int* ei0, const int* ei1,
                                                 int* cursor, int* srcs) {
  int br = blockIdx.z;
  int e = blockIdx.x * 256 + threadIdx.x;
  if (e >= NE) return;
  const int* ei = br ? ei1 : ei0;
  int t = ei[e], s = ei[NE + e];
  int pos = atomicAdd(cursor + br * NN + t, 1);
  srcs[br * NE + pos] = s;
}

// ---------------- shared phase: PQ strip from lhb (32x128 bf16, stride 136) -------
__device__ __forceinline__ void pq_from_lhb(
    const u16* lhb, const u16* wq, u16* PQ, int m0, int wave, int lane) {
  const int q = lane >> 4, lr = lane & 15;
  f32x4 a3[2][8];
#pragma unroll
  for (int i = 0; i < 2; i++)
#pragma unroll
    for (int j = 0; j < 8; j++) a3[i][j] = (f32x4){0.f, 0.f, 0.f, 0.f};
  bf16x8 bcur[8], bnxt[8];
#pragma unroll
  for (int i = 0; i < 8; i++)
    bcur[i] = *(const bf16x8*)(wq + (size_t)(wave * 128 + i * 16 + lr) * 128 + q * 8);
#pragma unroll
  for (int k0 = 0; k0 < 128; k0 += 32) {
    if (k0 + 32 < 128) {
#pragma unroll
      for (int i = 0; i < 8; i++)
        bnxt[i] = *(const bf16x8*)(wq + (size_t)(wave * 128 + i * 16 + lr) * 128 + k0 + 32 + q * 8);
    }
    bf16x8 af[2];
#pragma unroll
    for (int i = 0; i < 2; i++)
      af[i] = *(const bf16x8*)&lhb[(i * 16 + lr) * 136 + k0 + q * 8];
#pragma unroll
    for (int mi = 0; mi < 2; mi++)
#pragma unroll
      for (int ni = 0; ni < 8; ni++)
        a3[mi][ni] = __builtin_amdgcn_mfma_f32_16x16x32_bf16(af[mi], bcur[ni], a3[mi][ni], 0, 0, 0);
#pragma unroll
    for (int i = 0; i < 8; i++) bcur[i] = bnxt[i];
  }
#pragma unroll
  for (int mi = 0; mi < 2; mi++)
#pragma unroll
    for (int rg = 0; rg < 4; rg++) {
      int grow = m0 + mi * 16 + q * 4 + rg;
      if (grow >= NN) continue;
#pragma unroll
      for (int ni = 0; ni < 8; ni++) {
        int col = wave * 128 + ni * 16 + lr;
        PQ[(size_t)grow * 512 + col] = f2b(a3[mi][ni][rg]);
      }
    }
}

// ---------------- embedding via MFMA: h = xb @ W_emb^T + b; + PQ(l=0) ------------
__global__ __launch_bounds__(256) void k_embed(
    const u16* xb_all, const u16* wemb, const float* b,
    float* h, u16* h_bf, u16* ui, const u16* wpq0, u16* PQ_all) {
  const int br = blockIdx.z;
  const int tid = threadIdx.x;
  const int lane = tid & 63, wave = tid >> 6;
  const int q = lane >> 4, lr = lane & 15;
  const int m0 = blockIdx.x * 32;

  __shared__ alignas(16) u16 lx[32 * 72];
  __shared__ alignas(16) u16 lhb[32 * 136];

  const u16* xb = xb_all + (size_t)br * NN * 64;
  {
    int r = tid >> 3, kc = (tid & 7) * 8;
    int gr = m0 + r;
    u16x8 v = {0, 0, 0, 0, 0, 0, 0, 0};
    if (gr < NN) v = *(const u16x8*)(xb + (size_t)gr * 64 + kc);
    *(u16x8*)&lx[r * 72 + kc] = v;
  }
  __syncthreads();

  const int wn = wave * 32;
  f32x4 acc[2][2];
#pragma unroll
  for (int i = 0; i < 2; i++)
#pragma unroll
    for (int j = 0; j < 2; j++) acc[i][j] = (f32x4){0.f, 0.f, 0.f, 0.f};

#pragma unroll
  for (int k0 = 0; k0 < 64; k0 += 32) {
    bf16x8 af[2], bfr[2];
#pragma unroll
    for (int i = 0; i < 2; i++)
      af[i] = *(const bf16x8*)&lx[(i * 16 + lr) * 72 + k0 + q * 8];
#pragma unroll
    for (int i = 0; i < 2; i++)
      bfr[i] = *(const bf16x8*)(wemb + (size_t)(wn + i * 16 + lr) * 64 + k0 + q * 8);
#pragma unroll
    for (int mi = 0; mi < 2; mi++)
#pragma unroll
      for (int ni = 0; ni < 2; ni++)
        acc[mi][ni] = __builtin_amdgcn_mfma_f32_16x16x32_bf16(af[mi], bfr[ni], acc[mi][ni], 0, 0, 0);
  }

  float* hB = h + (size_t)br * NN * HD;
  u16* hbB = h_bf + (size_t)br * NN * HD;
  u16* uiB = ui + (size_t)br * NN * 384;
#pragma unroll
  for (int mi = 0; mi < 2; mi++)
#pragma unroll
    for (int rg = 0; rg < 4; rg++) {
      int lrow = mi * 16 + q * 4 + rg;
      int gr = m0 + lrow;
#pragma unroll
      for (int ni = 0; ni < 2; ni++) {
        int col = wn + ni * 16 + lr;
        if (gr < NN) {
          float nh = acc[mi][ni][rg] + b[col];
          u16 bv = f2b(nh);
          hB[(size_t)gr * HD + col] = nh;
          hbB[(size_t)gr * HD + col] = bv;
          uiB[(size_t)gr * 384 + 256 + col] = bv;
          lhb[lrow * 136 + col] = bv;
        } else {
          lhb[lrow * 136 + col] = 0;
        }
      }
    }
  __syncthreads();
  pq_from_lhb(lhb, wpq0, PQ_all + (size_t)br * NN * 512, m0, wave, lane);
}

// ---------------- edge phase: ui[n][:256] = sum_e relu(P[src_e] + Q[n] + b1) ------
__global__ __launch_bounds__(256) void k_edge(const u16* PQ, const int* starts,
                                              const int* srcs, const float* b1, u16* ui) {
  int br = blockIdx.z;
  int node = blockIdx.x * 4 + (threadIdx.x >> 6);
  int lane = threadIdx.x & 63;
  int half = lane >> 5;
  int c0 = (lane & 31) * 8;
  const u16* PQb = PQ + (size_t)br * NN * 512;
  const int* st = starts + br * (NN + 8);
  const int* sr = srcs + br * NE;
  u16x8 qr = *(const u16x8*)(PQb + (size_t)node * 512 + 256 + c0);
  float qv[8], acc[8];
#pragma unroll
  for (int j = 0; j < 8; j++) { qv[j] = b2f(qr[j]) + b1[c0 + j]; acc[j] = 0.f; }
  int e0 = st[node], e1 = st[node + 1];
  int mid = e0 + ((e1 - e0 + 1) >> 1);
  int e = half ? mid : e0;
  int ee = half ? e1 : mid;
  for (; e + 3 < ee; e += 4) {
    int s0 = sr[e], s1 = sr[e + 1], s2 = sr[e + 2], s3 = sr[e + 3];
    u16x8 p0 = *(const u16x8*)(PQb + (size_t)s0 * 512 + c0);
    u16x8 p1 = *(const u16x8*)(PQb + (size_t)s1 * 512 + c0);
    u16x8 p2 = *(const u16x8*)(PQb + (size_t)s2 * 512 + c0);
    u16x8 p3 = *(const u16x8*)(PQb + (size_t)s3 * 512 + c0);
#pragma unroll
    for (int j = 0; j < 8; j++) {
      float v0 = b2f(p0[j]) + qv[j];
      float v1 = b2f(p1[j]) + qv[j];
      float v2 = b2f(p2[j]) + qv[j];
      float v3 = b2f(p3[j]) + qv[j];
      acc[j] += (v0 > 0.f ? v0 : 0.f) + (v1 > 0.f ? v1 : 0.f)
              + (v2 > 0.f ? v2 : 0.f) + (v3 > 0.f ? v3 : 0.f);
    }
  }
  for (; e + 1 < ee; e += 2) {
    int s0 = sr[e], s1 = sr[e + 1];
    u16x8 p0 = *(const u16x8*)(PQb + (size_t)s0 * 512 + c0);
    u16x8 p1 = *(const u16x8*)(PQb + (size_t)s1 * 512 + c0);
#pragma unroll
    for (int j = 0; j < 8; j++) {
      float v0 = b2f(p0[j]) + qv[j];
      float v1 = b2f(p1[j]) + qv[j];
      acc[j] += (v0 > 0.f ? v0 : 0.f) + (v1 > 0.f ? v1 : 0.f);
    }
  }
  if (e < ee) {
    int s0 = sr[e];
    u16x8 p0 = *(const u16x8*)(PQb + (size_t)s0 * 512 + c0);
#pragma unroll
    for (int j = 0; j < 8; j++) {
      float v0 = b2f(p0[j]) + qv[j];
      acc[j] += (v0 > 0.f ? v0 : 0.f);
    }
  }
#pragma unroll
  for (int j = 0; j < 8; j++) acc[j] += __shfl_xor(acc[j], 32);
  if (half == 0) {
    u16x8 o;
#pragma unroll
    for (int j = 0; j < 8; j++) o[j] = f2b(acc[j]);
    *(u16x8*)(ui + (size_t)br * NN * 384 + (size_t)node * 384 + c0) = o;
  }
}

// ---------------- fused update MLP (M-tile 32), single-stage A, global B ----------
__global__ __launch_bounds__(256, 4) void k_upd(
    const u16* ui_all, const u16* w1c, const float* b1u, const float* c2l,
    const int* deg_all, const u16* w2, const float* b2u,
    float* h_all, u16* hb_all, int mode,
    const u16* wpq_next, u16* PQ_all,
    const u16* wnode, const float* nb, const int* b0v, const int* b1v, float* g) {
  const int br = blockIdx.z;
  const int tid = threadIdx.x;
  const int lane = tid & 63, wave = tid >> 6;
  const int q = lane >> 4, lr = lane & 15;
  const int m0 = blockIdx.x * 32;

  __shared__ alignas(16) u16 lA[32 * 392];   // A strip [32][384], stride 392
  __shared__ alignas(16) u16 lhb[32 * 136];
  __shared__ int sbat[32];
  u16* lU = lA;  // overlay after phase1 (32*272 <= 32*392)

  const u16* ui = ui_all + (size_t)br * NN * 384;

  // ---- stage A strip ----
  for (int c = tid; c < 1536; c += 256) {
    int r = c / 48, kc = (c % 48) * 8;
    int gr = m0 + r;
    u16x8 v = {0, 0, 0, 0, 0, 0, 0, 0};
    if (gr < NN) v = *(const u16x8*)(ui + (size_t)gr * 384 + kc);
    *(u16x8*)&lA[r * 392 + kc] = v;
  }
  if (mode == 1 && tid < 32) {
    const int* batch = br ? b1v : b0v;
    int n = m0 + tid;
    sbat[tid] = (n < NN) ? batch[n] : -1;
  }
  __syncthreads();

  // ---- phase 1: af from lA, bfr double-buffered from global w1c ----
  const int wn = wave * 64;
  f32x4 acc[2][4];
#pragma unroll
  for (int i = 0; i < 2; i++)
#pragma unroll
    for (int j = 0; j < 4; j++) acc[i][j] = (f32x4){0.f, 0.f, 0.f, 0.f};

  bf16x8 bcur[4], bnxt[4];
#pragma unroll
  for (int i = 0; i < 4; i++)
    bcur[i] = *(const bf16x8*)(w1c + (size_t)(wn + i * 16 + lr) * 384 + q * 8);
#pragma unroll
  for (int k0 = 0; k0 < 384; k0 += 32) {
    if (k0 + 32 < 384) {
#pragma unroll
      for (int i = 0; i < 4; i++)
        bnxt[i] = *(const bf16x8*)(w1c + (size_t)(wn + i * 16 + lr) * 384 + k0 + 32 + q * 8);
    }
    bf16x8 af[2];
#pragma unroll
    for (int i = 0; i < 2; i++)
      af[i] = *(const bf16x8*)&lA[(i * 16 + lr) * 392 + k0 + q * 8];
#pragma unroll
    for (int mi = 0; mi < 2; mi++)
#pragma unroll
      for (int ni = 0; ni < 4; ni++)
        acc[mi][ni] = __builtin_amdgcn_mfma_f32_16x16x32_bf16(af[mi], bcur[ni], acc[mi][ni], 0, 0, 0);
#pragma unroll
    for (int i = 0; i < 4; i++) bcur[i] = bnxt[i];
  }
  __syncthreads();  // all lA reads done before overlay

  // relu + bias + deg*c2 -> bf16 into lU[32][272]
  const int* deg = deg_all + br * NN;
#pragma unroll
  for (int mi = 0; mi < 2; mi++)
#pragma unroll
    for (int rg = 0; rg < 4; rg++) {
      int row = mi * 16 + q * 4 + rg;
      int gr = m0 + row;
      float d = (gr < NN) ? (float)deg[gr] : 0.f;
#pragma unroll
      for (int ni = 0; ni < 4; ni++) {
        int col = wn + ni * 16 + lr;
        float v = acc[mi][ni][rg] + b1u[col] + d * c2l[col];
        if (v < 0.f) v = 0.f;
        lU[row * 272 + col] = f2b(v);
      }
    }
  __syncthreads();

  // ---- phase 2: af from lU, bfr double-buffered from global w2 ----
  const int wn2 = wave * 32;
  f32x4 acc2[2][2];
#pragma unroll
  for (int i = 0; i < 2; i++)
#pragma unroll
    for (int j = 0; j < 2; j++) acc2[i][j] = (f32x4){0.f, 0.f, 0.f, 0.f};

  bf16x8 b2c[2], b2n[2];
#pragma unroll
  for (int i = 0; i < 2; i++)
    b2c[i] = *(const bf16x8*)(w2 + (size_t)(wn2 + i * 16 + lr) * 256 + q * 8);
#pragma unroll
  for (int k0 = 0; k0 < 256; k0 += 32) {
    if (k0 + 32 < 256) {
#pragma unroll
      for (int i = 0; i < 2; i++)
        b2n[i] = *(const bf16x8*)(w2 + (size_t)(wn2 + i * 16 + lr) * 256 + k0 + 32 + q * 8);
    }
    bf16x8 af[2];
#pragma unroll
    for (int i = 0; i < 2; i++)
      af[i] = *(const bf16x8*)&lU[(i * 16 + lr) * 272 + k0 + q * 8];
#pragma unroll
    for (int mi = 0; mi < 2; mi++)
#pragma unroll
      for (int ni = 0; ni < 2; ni++)
        acc2[mi][ni] = __builtin_amdgcn_mfma_f32_16x16x32_bf16(af[mi], b2c[ni], acc2[mi][ni], 0, 0, 0);
#pragma unroll
    for (int i = 0; i < 2; i++) b2c[i] = b2n[i];
  }

  // residual epilogue (+ stage bf16 h into lhb)
  float* h = h_all + (size_t)br * NN * 128;
  u16* hb = hb_all + (size_t)br * NN * 128;
  u16* uiw = (u16*)ui_all + (size_t)br * NN * 384;
#pragma unroll
  for (int mi = 0; mi < 2; mi++)
#pragma unroll
    for (int rg = 0; rg < 4; rg++) {
      int lrow = mi * 16 + q * 4 + rg;
      int grow = m0 + lrow;
#pragma unroll
      for (int ni = 0; ni < 2; ni++) {
        int col = wn2 + ni * 16 + lr;
        if (grow < NN) {
          size_t o = (size_t)grow * 128 + col;
          float nh = h[o] + acc2[mi][ni][rg] + b2u[col];
          u16 bv = f2b(nh);
          h[o] = nh;
          hb[o] = bv;
          uiw[(size_t)grow * 384 + 256 + col] = bv;
          lhb[lrow * 136 + col] = bv;
        } else {
          lhb[lrow * 136 + col] = 0;
        }
      }
    }
  __syncthreads();

  // ---- phase 3 ----
  if (mode == 0) {
    pq_from_lhb(lhb, wpq_next, PQ_all + (size_t)br * NN * 512, m0, wave, lane);
  } else {
    const int wg = wave * 32;
    f32x4 a3[2][4];  // ni 0-1 gate cols, 2-3 val cols
#pragma unroll
    for (int i = 0; i < 2; i++)
#pragma unroll
      for (int j = 0; j < 4; j++) a3[i][j] = (f32x4){0.f, 0.f, 0.f, 0.f};
#pragma unroll
    for (int k0 = 0; k0 < 128; k0 += 32) {
      bf16x8 af[2], bfr[4];
#pragma unroll
      for (int i = 0; i < 2; i++)
        af[i] = *(const bf16x8*)&lhb[(i * 16 + lr) * 136 + k0 + q * 8];
#pragma unroll
      for (int i = 0; i < 4; i++) {
        int nrow = (i < 2) ? (wg + i * 16 + lr) : (128 + wg + (i - 2) * 16 + lr);
        bfr[i] = *(const bf16x8*)(wnode + (size_t)nrow * 128 + k0 + q * 8);
      }
#pragma unroll
      for (int mi = 0; mi < 2; mi++)
#pragma unroll
        for (int ni = 0; ni < 4; ni++)
          a3[mi][ni] = __builtin_amdgcn_mfma_f32_16x16x32_bf16(af[mi], bfr[ni], a3[mi][ni], 0, 0, 0);
    }
    float* gb = g + (size_t)br * NG * 128;
    float racc[2] = {0.f, 0.f};
    int cur = -1;
#pragma unroll
    for (int mi = 0; mi < 2; mi++)
#pragma unroll
      for (int rg = 0; rg < 4; rg++) {
        int lrow = mi * 16 + q * 4 + rg;
        int bt = sbat[lrow];
        if (bt != cur) {
          if (cur >= 0) {
#pragma unroll
            for (int ni = 0; ni < 2; ni++)
              atomicAdd(gb + (size_t)cur * 128 + wg + ni * 16 + lr, racc[ni]);
          }
          cur = bt;
          racc[0] = 0.f; racc[1] = 0.f;
        }
        if (bt >= 0) {
#pragma unroll
          for (int ni = 0; ni < 2; ni++) {
            int gcol = wg + ni * 16 + lr;
            float gt = a3[mi][ni][rg] + nb[gcol];
            float vl = a3[mi][ni + 2][rg] + nb[128 + gcol];
            racc[ni] += vl / (1.f + __expf(-gt));
          }
        }
      }
    if (cur >= 0) {
#pragma unroll
      for (int ni = 0; ni < 2; ni++)
        atomicAdd(gb + (size_t)cur * 128 + wg + ni * 16 + lr, racc[ni]);
    }
  }
}

// ---------------- final graph GEMM ----------------
__global__ __launch_bounds__(128) void k_final(const float* g, const float* W,
                                               const float* b, float* out) {
  int br = blockIdx.z, gi = blockIdx.x, j = threadIdx.x;
  __shared__ float sg[128];
  sg[j] = g[(size_t)br * NG * 128 + (size_t)gi * 128 + j];
  __syncthreads();
  float acc = b[j];
#pragma unroll
  for (int k = 0; k < 128; k++) acc += sg[k] * W[k * 128 + j];
  out[(size_t)br * NG * 128 + (size_t)gi * 128 + j] = acc;
}

extern "C" void kernel_launch(void* const* d_in, const int* in_sizes, int n_in,
                              void* d_out, int out_size, void* d_ws, size_t ws_size,
                              hipStream_t stream) {
  const float* x1     = (const float*)d_in[0];
  const int*   ei1    = (const int*)d_in[1];
  const int*   bat1   = (const int*)d_in[2];
  const float* x2     = (const float*)d_in[3];
  const int*   ei2    = (const int*)d_in[4];
  const int*   bat2   = (const int*)d_in[5];
  const float* W_emb  = (const float*)d_in[6];
  const float* b_emb  = (const float*)d_in[7];
  const float* msg_W1 = (const float*)d_in[8];
  const float* msg_b1 = (const float*)d_in[9];
  const float* msg_W2 = (const float*)d_in[10];
  const float* msg_b2 = (const float*)d_in[11];
  const float* upd_W1 = (const float*)d_in[12];
  const float* upd_b1 = (const float*)d_in[13];
  const float* upd_W2 = (const float*)d_in[14];
  const float* upd_b2 = (const float*)d_in[15];
  const float* node_W = (const float*)d_in[16];
  const float* node_b = (const float*)d_in[17];
  const float* graph_W = (const float*)d_in[18];
  const float* graph_b = (const float*)d_in[19];
  float* out = (float*)d_out;

  char* ws = (char*)d_ws;
  u16* wt_pq   = (u16*)(ws + WT_PQ);
  u16* wt_u1c  = (u16*)(ws + WT_U1C);
  u16* wt_upd2 = (u16*)(ws + WT_UPD2);
  u16* wt_node = (u16*)(ws + WT_NODE);
  u16* wt_emb  = (u16*)(ws + WT_EMB);
  u16* xb      = (u16*)(ws + OFF_XB);
  float* c2    = (float*)(ws + OFF_C2);
  int* deg    = (int*)(ws + OFF_DEG);
  int* starts = (int*)(ws + OFF_ST);
  int* cursor = (int*)(ws + OFF_CUR);
  int* srcs   = (int*)(ws + OFF_SRC);
  float* h  = (float*)(ws + OFF_H);
  u16*   hb = (u16*)(ws + OFF_HB);
  u16*   PQ = (u16*)(ws + OFF_PQ);
  u16*   ui = (u16*)(ws + OFF_UI);
  float* g  = (float*)(ws + OFF_G);

  // ---- prep (weights + Wc + c2 + xb + zero deg/g) ----
  k_prep<<<6057, 256, 0, stream>>>(msg_W1, msg_W2, upd_W1, upd_W2, node_W, msg_b2,
                                   W_emb, x1, x2,
                                   wt_pq, wt_u1c, wt_upd2, wt_node, wt_emb, xb,
                                   c2, deg, g);
  k_deg<<<dim3(625, 1, 2), 256, 0, stream>>>(ei1, ei2, deg);
  k_scan<<<dim3(1, 1, 2), 256, 0, stream>>>(deg, starts, cursor);
  k_scatter<<<dim3(625, 1, 2), 256, 0, stream>>>(ei1, ei2, cursor, srcs);
  // embed (MFMA) + PQ(l=0)
  k_embed<<<dim3(313, 1, 2), 256, 0, stream>>>(xb, wt_emb, b_emb, h, hb, ui,
                                               wt_pq, PQ);

  for (int l = 0; l < 2; l++) {
    // ui[:, :256] = S[n] = sum_{e: tgt=n} relu(P[src_e] + Q[n] + b1)
    k_edge<<<dim3(2500, 1, 2), 256, 0, stream>>>(PQ, starts, srcs, msg_b1 + l * 256, ui);

    // fused: U1 = relu([S|h]@W1c+..); h += U1@W2+b2; then PQ(l+1) or readout
    k_upd<<<dim3(313, 1, 2), 256, 0, stream>>>(
        ui, wt_u1c + (size_t)l * 98304, upd_b1 + l * 256, c2 + l * 256,
        deg, wt_upd2 + (size_t)l * 32768, upd_b2 + l * 128, h, hb,
        (l == 0) ? 0 : 1,
        wt_pq + 65536, PQ,
        wt_node, node_b, bat1, bat2, g);
  }

  k_final<<<dim3(NG, 1, 2), 128, 0, stream>>>(g, graph_W, graph_b, out);
}